// Round 16
// baseline (249.028 us; speedup 1.0000x reference)
//
#include <hip/hip_runtime.h>

#define NN 32768
#define GEPS 1e-6f

__device__ __forceinline__ float wredsum(float v){
  v += __shfl_xor(v, 32); v += __shfl_xor(v, 16); v += __shfl_xor(v, 8);
  v += __shfl_xor(v, 4);  v += __shfl_xor(v, 2);  v += __shfl_xor(v, 1);
  return v;
}
// sum across lanes sharing lane&7 (eighth class): flip point bits 3,4,5
__device__ __forceinline__ float eredsum(float v){
  v += __shfl_xor(v, 8); v += __shfl_xor(v, 16); v += __shfl_xor(v, 32);
  return v;
}
// combine the 8 eighth-lanes of one point (bits 0-2)
__device__ __forceinline__ float ecomb(float v){
  v += __shfl_xor(v, 1); v += __shfl_xor(v, 2); v += __shfl_xor(v, 4);
  return v;
}

// ---------------- F0: weight transposes / concats ----------------------------------
__global__ void __launch_bounds__(256) f0_prep(
    const float* __restrict__ w_mlp1, const float* __restrict__ b_mlp1,
    const float* __restrict__ w_sc,   const float* __restrict__ b_sc,
    const float* __restrict__ w_pool1,const float* __restrict__ w_pool2,
    float* __restrict__ WallT, float* __restrict__ ball,
    float* __restrict__ wp1T,  float* __restrict__ wp2T)
{
  const int t0 = blockIdx.x*256 + threadIdx.x;
  const int stride = gridDim.x*256;
  for (int u=t0; u<72*160; u+=stride){
    int i = u/160, o = u - i*160;
    WallT[u] = (o < 128) ? w_sc[o*72+i] : w_mlp1[(o-128)*72+i];
  }
  for (int u=t0; u<160; u+=stride)
    ball[u] = (u < 128) ? b_sc[u] : b_mlp1[u-128];
  for (int u=t0; u<64*32; u+=stride){ int c=u>>5, o=u&31; wp1T[u] = w_pool1[o*64+c]; }
  for (int u=t0; u<64*64; u+=stride){ int c=u>>6, o=u&63; wp2T[u] = w_pool2[o*64+c]; }
}

// ---------------- K0: all-LDS inner loop; 128 pts/block, 2 pts/thread ---------------
__global__ void __launch_bounds__(256,2) k0_mlp1_scstats(
    const float* __restrict__ feat, const float* __restrict__ WallT,
    const float* __restrict__ ball,
    float* __restrict__ X1, float* __restrict__ scS, float* __restrict__ scQ)
{
  __shared__ float xl[72][128];
  __shared__ float wl[72*32];
  __shared__ float ssl[128], sql[128];
  const int tid = threadIdx.x, lane = tid & 63;
  const int wid = __builtin_amdgcn_readfirstlane(tid >> 6);
  const int b   = __builtin_amdgcn_readfirstlane((int)blockIdx.x >> 8);
  const int n0  = ((int)blockIdx.x & 255) << 7;
  const int p0  = lane*2;

  for (int u=tid; u<72*128; u+=256){
    int c = u>>7, j = u&127;
    xl[c][j] = feat[(size_t)(b*72+c)*NN + n0 + j];
  }

#pragma unroll 1
  for (int pass=0; pass<5; ++pass){
    __syncthreads();
    for (int u=tid; u<2304; u+=256){
      int i = u>>5, c = u&31;
      wl[u] = WallT[i*160 + pass*32 + c];
    }
    __syncthreads();

    const int oc = pass*32 + wid*8;
    float a0[8], a1[8];
#pragma unroll
    for (int q=0;q<8;q++){ float bv = ball[oc+q]; a0[q]=bv; a1[q]=bv; }

    const float* wbase = wl + wid*8;
#pragma unroll
    for (int i=0;i<72;i++){
      const float2 x2 = *(const float2*)&xl[i][p0];
      const float4 w0 = *(const float4*)(wbase + i*32);
      const float4 w1 = *(const float4*)(wbase + i*32 + 4);
      a0[0]=fmaf(w0.x,x2.x,a0[0]); a1[0]=fmaf(w0.x,x2.y,a1[0]);
      a0[1]=fmaf(w0.y,x2.x,a0[1]); a1[1]=fmaf(w0.y,x2.y,a1[1]);
      a0[2]=fmaf(w0.z,x2.x,a0[2]); a1[2]=fmaf(w0.z,x2.y,a1[2]);
      a0[3]=fmaf(w0.w,x2.x,a0[3]); a1[3]=fmaf(w0.w,x2.y,a1[3]);
      a0[4]=fmaf(w1.x,x2.x,a0[4]); a1[4]=fmaf(w1.x,x2.y,a1[4]);
      a0[5]=fmaf(w1.y,x2.x,a0[5]); a1[5]=fmaf(w1.y,x2.y,a1[5]);
      a0[6]=fmaf(w1.z,x2.x,a0[6]); a1[6]=fmaf(w1.z,x2.y,a1[6]);
      a0[7]=fmaf(w1.w,x2.x,a0[7]); a1[7]=fmaf(w1.w,x2.y,a1[7]);
    }

    if (pass < 4){
#pragma unroll
      for (int q=0;q<8;q++){
        float s  = wredsum(a0[q]+a1[q]);
        float s2 = wredsum(a0[q]*a0[q] + a1[q]*a1[q]);
        if (lane==0){ ssl[oc+q] = s; sql[oc+q] = s2; }
      }
    } else {
      __syncthreads();
      float* xst = &xl[0][0];      // overlay [32][130]
#pragma unroll
      for (int q=0;q<8;q++){
        float v0 = a0[q], v1 = a1[q];
        v0 = v0 > 0.f ? v0 : 0.2f*v0;
        v1 = v1 > 0.f ? v1 : 0.2f*v1;
        float2 t; t.x=v0; t.y=v1;
        *(float2*)&xst[(wid*8+q)*130 + p0] = t;
      }
      __syncthreads();
      float* xb = X1 + ((size_t)b*NN + n0)*32;
#pragma unroll
      for (int r=0;r<4;r++){
        int u = tid + r*256;
        int p = u>>3, c0 = (u&7)*4;
        float4 o;
        o.x = xst[(c0+0)*130+p]; o.y = xst[(c0+1)*130+p];
        o.z = xst[(c0+2)*130+p]; o.w = xst[(c0+3)*130+p];
        *(float4*)(xb + (size_t)p*32 + c0) = o;
      }
    }
  }

  if (tid < 128){
    atomicAdd(&scS[b*128+tid], ssl[tid]);
    atomicAdd(&scQ[b*128+tid], sql[tid]);
  }
}

// ---------------- K1: v10 moments, 4 threads per point (k-quarters) -----------------
__global__ void __launch_bounds__(256) k1_vmom(
    const float* __restrict__ coords, const int* __restrict__ idx,
    const float* __restrict__ dist, float* __restrict__ vm)
{
  __shared__ float red[4*65];
  const int tid = threadIdx.x, lane = tid & 63, wid = tid >> 6;
  const int gn = blockIdx.x*256 + tid;
  const int pt = gn >> 2, h = gn & 3;
  const int b = pt >> 15, n = pt & (NN-1);
  const size_t pb = (size_t)b*NN + n;
  const float c0 = coords[pb*3+0], c1 = coords[pb*3+1], c2 = coords[pb*3+2];

  int ja[4]; float da[4];
  {
    int4 j4 = *(const int4*)(idx + pb*16 + h*4);
    float4 d4 = *(const float4*)(dist + pb*16 + h*4);
    ja[0]=j4.x; ja[1]=j4.y; ja[2]=j4.z; ja[3]=j4.w;
    da[0]=d4.x; da[1]=d4.y; da[2]=d4.z; da[3]=d4.w;
  }

  float aS[10], aM[55];
#pragma unroll
  for (int i=0;i<10;i++) aS[i]=0.f;
#pragma unroll
  for (int i=0;i<55;i++) aM[i]=0.f;

#pragma unroll
  for (int k=0;k<4;k++){
    const float* nb = coords + ((size_t)b*NN + ja[k])*3;
    const float n0v=nb[0], n1v=nb[1], n2v=nb[2];
    const float v[10] = {c0,c1,c2,n0v,n1v,n2v,c0-n0v,c1-n1v,c2-n2v,da[k]};
#pragma unroll
    for (int i=0;i<10;i++){
      aS[i] += v[i];
#pragma unroll
      for (int j=i;j<10;j++)
        aM[i*10 - (i*(i-1))/2 + (j-i)] += v[i]*v[j];
    }
  }

#pragma unroll
  for (int i=0;i<10;i++){ float s = wredsum(aS[i]); if (lane==0) red[wid*65+i] = s; }
#pragma unroll
  for (int i=0;i<55;i++){ float s = wredsum(aM[i]); if (lane==0) red[wid*65+10+i] = s; }
  __syncthreads();
  if (tid < 65){
    float s = red[tid] + red[65+tid] + red[130+tid] + red[195+tid];
    const int bb = blockIdx.x >> 9;   // 64 pts/block
    atomicAdd(&vm[bb*65+tid], s);
  }
}

// ---------------- F1: fold GN into LSE conv weights --------------------------------
__global__ void f1_fold(
    const float* __restrict__ w_lse1, const float* __restrict__ b_lse1,
    const float* __restrict__ g_lse1, const float* __restrict__ bt_lse1,
    const float* __restrict__ w_lse2, const float* __restrict__ b_lse2,
    const float* __restrict__ g_lse2, const float* __restrict__ bt_lse2,
    const float* __restrict__ vm,
    float* __restrict__ w1p, float* __restrict__ w2p)
{
  const int tid = threadIdx.x; // 128
  const int half = tid >> 6;
  const int u = tid & 63, b = u >> 5, c = u & 31;
  const float* W  = half ? w_lse2  : w_lse1;
  const float* Bv = half ? b_lse2  : b_lse1;
  const float* G  = half ? g_lse2  : g_lse1;
  const float* Bt = half ? bt_lse2 : bt_lse1;
  float wr[10];
#pragma unroll
  for (int i=0;i<10;i++) wr[i] = W[c*10+i];
  const float* S = vm + b*65;
  const float* M = vm + b*65 + 10;
  float P = 0.f;
#pragma unroll
  for (int i=0;i<10;i++) P = fmaf(wr[i], S[i], P);
  float Q = 0.f;
#pragma unroll
  for (int i=0;i<10;i++){
#pragma unroll
    for (int j=i;j<10;j++){
      float m = M[i*10 - (i*(i-1))/2 + (j-i)];
      float t = wr[i]*wr[j]*m;
      Q += (i==j) ? t : 2.f*t;
    }
  }
  const float invNK = 1.f/((float)NN*16.f);
  const float bc = Bv[c];
  float mean = P*invNK + bc;
  float ey2  = (Q + 2.f*bc*P)*invNK + bc*bc;
  float mu = 0.5f*(mean + __shfl_xor(mean,1));
  float e2 = 0.5f*(ey2  + __shfl_xor(ey2, 1));
  float var = e2 - mu*mu;
  float rstd = rsqrtf(var + GEPS);
  float a = G[c]*rstd, d = Bt[c] - mu*a;
  float* out = (half ? w2p : w1p) + (b*32+c)*12;
#pragma unroll
  for (int i=0;i<10;i++) out[i] = wr[i]*a;
  out[10] = bc*a + d;
  out[11] = 0.f;
}

// ---------------- K2: LSE1+pool1; 8 thr/pt; 32 pts/block; LDS pool weights ---------
__global__ void __launch_bounds__(256,6) k2_lse1_pool1(
    const float* __restrict__ coords, const int* __restrict__ idx,
    const float* __restrict__ dist, const float* __restrict__ X1,
    const float* __restrict__ w1p, const float* __restrict__ wp1T,
    const float* __restrict__ b_pool1,
    float* __restrict__ Y1, float* __restrict__ p1S, float* __restrict__ p1Q)
{
  __shared__ float mfl[32*66];
  __shared__ float wlds[64*32];
  __shared__ float sl[32], ql[32];
  const int tid = threadIdx.x, lane = tid & 63;
  const int e = tid & 7;       // eighth
  const int pl = tid >> 3;     // point-local 0..31
  if (tid < 32){ sl[tid]=0.f; ql[tid]=0.f; }
  for (int u=tid; u<2048; u+=256) wlds[u] = wp1T[u];
  __syncthreads();
  const int b = __builtin_amdgcn_readfirstlane((int)blockIdx.x & 1);
  const int n = (((int)blockIdx.x >> 1) << 5) + pl;
  const size_t pb = (size_t)b*NN + n;
  float* mf = &mfl[pl*66];
  const float s16 = 0.0625f;

  // Phase A: ch-split gather — eighth e reads channels e*4..e*4+4 of all 16 nbrs
  {
    int ja[16];
    const int4* ip = (const int4*)(idx + pb*16);
#pragma unroll
    for (int k4=0;k4<4;k4++){
      int4 j4 = ip[k4];
      ja[k4*4+0]=j4.x; ja[k4*4+1]=j4.y; ja[k4*4+2]=j4.z; ja[k4*4+3]=j4.w;
    }
    float af0=0.f, af1=0.f, af2=0.f, af3=0.f;
    const float* xb = X1 + (size_t)b*NN*32 + e*4;
#pragma unroll 4
    for (int k=0;k<16;k++){
      float4 g = *(const float4*)(xb + (size_t)ja[k]*32);
      af0+=g.x; af1+=g.y; af2+=g.z; af3+=g.w;
    }
    mf[32+e*4+0]=af0*s16; mf[32+e*4+1]=af1*s16;
    mf[32+e*4+2]=af2*s16; mf[32+e*4+3]=af3*s16;
  }

  // Phase B: k-split enc — eighth e owns 2 neighbors; channel-chunked (8 at a time)
  {
    int2 j2 = *(const int2*)(idx + pb*16 + e*2);
    float2 d2 = *(const float2*)(dist + pb*16 + e*2);
    const float* nb0 = coords + ((size_t)b*NN + j2.x)*3;
    const float* nb1 = coords + ((size_t)b*NN + j2.y)*3;
    const float nx0=nb0[0], ny0=nb0[1], nz0=nb0[2];
    const float nx1=nb1[0], ny1=nb1[1], nz1=nb1[2];
    const float c0=coords[pb*3], c1=coords[pb*3+1], c2=coords[pb*3+2];
    const float* wrow = w1p + (size_t)(b*32)*12;
#pragma unroll 1
    for (int cc=0;cc<4;cc++){
      float ptc[8];
#pragma unroll
      for (int q=0;q<8;q++){
        const float4* r4 = (const float4*)(wrow + (cc*8+q)*12);
        float4 ra=r4[0], rb=r4[1], rc=r4[2];
        const float t0=ra.x+rb.z, t1=ra.y+rb.w, t2=ra.z+rc.x;
        const float u0=ra.w-rb.z, u1=rb.x-rb.w, u2=rb.y-rc.x;
        const float wd=rc.y;
        float cb = rc.z;
        cb = fmaf(t0,c0,cb); cb = fmaf(t1,c1,cb); cb = fmaf(t2,c2,cb);
        float s0 = cb, s1 = cb;
        s0 = fmaf(u0,nx0,s0); s0 = fmaf(u1,ny0,s0); s0 = fmaf(u2,nz0,s0);
        s0 = fmaf(wd,d2.x,s0);
        s1 = fmaf(u0,nx1,s1); s1 = fmaf(u1,ny1,s1); s1 = fmaf(u2,nz1,s1);
        s1 = fmaf(wd,d2.y,s1);
        ptc[q] = fmaxf(s0,0.f) + fmaxf(s1,0.f);
      }
#pragma unroll
      for (int q=0;q<8;q++) ptc[q] = ecomb(ptc[q]);
      if ((e>>1)==cc){
        float v0 = (e&1) ? ptc[4] : ptc[0];
        float v1 = (e&1) ? ptc[5] : ptc[1];
        float v2 = (e&1) ? ptc[6] : ptc[2];
        float v3 = (e&1) ? ptc[7] : ptc[3];
        mf[e*4+0]=v0*s16; mf[e*4+1]=v1*s16;
        mf[e*4+2]=v2*s16; mf[e*4+3]=v3*s16;
      }
    }
  }
  __syncthreads();

  // pool1: outputs e*4 .. e*4+4 over 64 inputs (weights from LDS)
  const int o0 = e*4;
  float yac[4];
  {
    const float4 b0 = *(const float4*)(b_pool1 + o0);
    yac[0]=b0.x; yac[1]=b0.y; yac[2]=b0.z; yac[3]=b0.w;
  }
#pragma unroll 4
  for (int c=0;c<64;c++){
    const float mc = mf[c];
    const float4 w0 = *(const float4*)(wlds + c*32 + o0);
    yac[0]=fmaf(w0.x,mc,yac[0]); yac[1]=fmaf(w0.y,mc,yac[1]);
    yac[2]=fmaf(w0.z,mc,yac[2]); yac[3]=fmaf(w0.w,mc,yac[3]);
  }
  {
    float4 r0; r0.x=yac[0]; r0.y=yac[1]; r0.z=yac[2]; r0.w=yac[3];
    *(float4*)(Y1 + pb*32 + o0) = r0;
  }
#pragma unroll
  for (int q=0;q<4;q++){
    float s  = eredsum(yac[q]);
    float s2 = eredsum(yac[q]*yac[q]);
    if (lane < 8){ atomicAdd(&sl[o0+q], s); atomicAdd(&ql[o0+q], s2); }
  }
  __syncthreads();
  if (tid<32){ atomicAdd(&p1S[b*32+tid], sl[tid]); atomicAdd(&p1Q[b*32+tid], ql[tid]); }
}

// ---------------- K4: LSE2+pool2; GN-on-gather fused; LDS pool weights --------------
__global__ void __launch_bounds__(256,6) k4_lse2_pool2(
    const float* __restrict__ coords, const int* __restrict__ idx,
    const float* __restrict__ dist, const float* __restrict__ Y1,
    const float* __restrict__ w2p, const float* __restrict__ wp2T,
    const float* __restrict__ b_pool2,
    const float* __restrict__ p1S, const float* __restrict__ p1Q,
    const float* __restrict__ g_p1, const float* __restrict__ bt_p1,
    float* __restrict__ Y2T, float* __restrict__ p2S, float* __restrict__ p2Q)
{
  __shared__ float mfl[32*66];     // also holds transposed store stage [64][33]
  __shared__ float wlds[64*64];
  __shared__ float sl[64], ql[64];
  __shared__ float al[32], dl[32];
  const int tid = threadIdx.x, lane = tid & 63;
  const int e = tid & 7;
  const int pl = tid >> 3;
  const int b = __builtin_amdgcn_readfirstlane((int)blockIdx.x & 1);
  if (tid < 64){ sl[tid]=0.f; ql[tid]=0.f; }
  if (tid >= 64 && tid < 96){
    const int c = tid - 64;
    float s = p1S[b*32+c], q = p1Q[b*32+c];
    s += __shfl_xor(s,1); q += __shfl_xor(q,1);
    const float inv = 1.f/(2.f*(float)NN);
    float mu = s*inv, e2 = q*inv, var = e2-mu*mu;
    float rstd = rsqrtf(var + GEPS);
    float a = g_p1[c]*rstd;
    al[c] = a; dl[c] = bt_p1[c] - mu*a;
  }
  for (int u=tid; u<4096; u+=256) wlds[u] = wp2T[u];
  __syncthreads();
  const int n0g = (((int)blockIdx.x >> 1) << 5);
  const int n = n0g + pl;
  const size_t pb = (size_t)b*NN + n;
  float* mf = &mfl[pl*66];
  const float s16 = 0.0625f;

  // Phase A: ch-split gather with fused pool1-GN+ReLU
  {
    const float a0g=al[e*4+0], a1g=al[e*4+1], a2g=al[e*4+2], a3g=al[e*4+3];
    const float d0g=dl[e*4+0], d1g=dl[e*4+1], d2g=dl[e*4+2], d3g=dl[e*4+3];
    int ja[16];
    const int4* ip = (const int4*)(idx + pb*16);
#pragma unroll
    for (int k4=0;k4<4;k4++){
      int4 j4 = ip[k4];
      ja[k4*4+0]=j4.x; ja[k4*4+1]=j4.y; ja[k4*4+2]=j4.z; ja[k4*4+3]=j4.w;
    }
    float af0=0.f, af1=0.f, af2=0.f, af3=0.f;
    const float* yb = Y1 + (size_t)b*NN*32 + e*4;
#pragma unroll 4
    for (int k=0;k<16;k++){
      float4 g = *(const float4*)(yb + (size_t)ja[k]*32);
      af0 += fmaxf(fmaf(g.x, a0g, d0g), 0.f);
      af1 += fmaxf(fmaf(g.y, a1g, d1g), 0.f);
      af2 += fmaxf(fmaf(g.z, a2g, d2g), 0.f);
      af3 += fmaxf(fmaf(g.w, a3g, d3g), 0.f);
    }
    mf[32+e*4+0]=af0*s16; mf[32+e*4+1]=af1*s16;
    mf[32+e*4+2]=af2*s16; mf[32+e*4+3]=af3*s16;
  }

  // Phase B: k-split enc
  {
    int2 j2 = *(const int2*)(idx + pb*16 + e*2);
    float2 d2 = *(const float2*)(dist + pb*16 + e*2);
    const float* nb0 = coords + ((size_t)b*NN + j2.x)*3;
    const float* nb1 = coords + ((size_t)b*NN + j2.y)*3;
    const float nx0=nb0[0], ny0=nb0[1], nz0=nb0[2];
    const float nx1=nb1[0], ny1=nb1[1], nz1=nb1[2];
    const float c0=coords[pb*3], c1=coords[pb*3+1], c2=coords[pb*3+2];
    const float* wrow = w2p + (size_t)(b*32)*12;
#pragma unroll 1
    for (int cc=0;cc<4;cc++){
      float ptc[8];
#pragma unroll
      for (int q=0;q<8;q++){
        const float4* r4 = (const float4*)(wrow + (cc*8+q)*12);
        float4 ra=r4[0], rb=r4[1], rc=r4[2];
        const float t0=ra.x+rb.z, t1=ra.y+rb.w, t2=ra.z+rc.x;
        const float u0=ra.w-rb.z, u1=rb.x-rb.w, u2=rb.y-rc.x;
        const float wd=rc.y;
        float cb = rc.z;
        cb = fmaf(t0,c0,cb); cb = fmaf(t1,c1,cb); cb = fmaf(t2,c2,cb);
        float s0 = cb, s1 = cb;
        s0 = fmaf(u0,nx0,s0); s0 = fmaf(u1,ny0,s0); s0 = fmaf(u2,nz0,s0);
        s0 = fmaf(wd,d2.x,s0);
        s1 = fmaf(u0,nx1,s1); s1 = fmaf(u1,ny1,s1); s1 = fmaf(u2,nz1,s1);
        s1 = fmaf(wd,d2.y,s1);
        ptc[q] = fmaxf(s0,0.f) + fmaxf(s1,0.f);
      }
#pragma unroll
      for (int q=0;q<8;q++) ptc[q] = ecomb(ptc[q]);
      if ((e>>1)==cc){
        float v0 = (e&1) ? ptc[4] : ptc[0];
        float v1 = (e&1) ? ptc[5] : ptc[1];
        float v2 = (e&1) ? ptc[6] : ptc[2];
        float v3 = (e&1) ? ptc[7] : ptc[3];
        mf[e*4+0]=v0*s16; mf[e*4+1]=v1*s16;
        mf[e*4+2]=v2*s16; mf[e*4+3]=v3*s16;
      }
    }
  }
  __syncthreads();

  // pool2: outputs e*8 .. e*8+8 over 64 inputs (weights from LDS)
  const int o0 = e*8;
  float yac[8];
  {
    const float4 b0 = *(const float4*)(b_pool2 + o0);
    const float4 b1 = *(const float4*)(b_pool2 + o0 + 4);
    yac[0]=b0.x; yac[1]=b0.y; yac[2]=b0.z; yac[3]=b0.w;
    yac[4]=b1.x; yac[5]=b1.y; yac[6]=b1.z; yac[7]=b1.w;
  }
#pragma unroll 4
  for (int c=0;c<64;c++){
    const float mc = mf[c];
    const float4 w0 = *(const float4*)(wlds + c*64 + o0);
    const float4 w1 = *(const float4*)(wlds + c*64 + o0 + 4);
    yac[0]=fmaf(w0.x,mc,yac[0]); yac[1]=fmaf(w0.y,mc,yac[1]);
    yac[2]=fmaf(w0.z,mc,yac[2]); yac[3]=fmaf(w0.w,mc,yac[3]);
    yac[4]=fmaf(w1.x,mc,yac[4]); yac[5]=fmaf(w1.y,mc,yac[5]);
    yac[6]=fmaf(w1.z,mc,yac[6]); yac[7]=fmaf(w1.w,mc,yac[7]);
  }
  // stats first (before overwriting mfl)
#pragma unroll
  for (int q=0;q<8;q++){
    float s  = eredsum(yac[q]);
    float s2 = eredsum(yac[q]*yac[q]);
    if (lane < 8){ atomicAdd(&sl[o0+q], s); atomicAdd(&ql[o0+q], s2); }
  }
  __syncthreads();   // all mf reads + stats done
  // stage transposed: lds[ch][pt], stride 33 (64*33=2112 = 32*66)
  float* ldsT = &mfl[0];
#pragma unroll
  for (int o=0;o<8;o++) ldsT[(o0+o)*33 + pl] = yac[o];
  __syncthreads();
  // coalesced channel-major store: 64 ch x 32 pts
#pragma unroll
  for (int r=0;r<8;r++){
    int u = tid + r*256;
    int ch = u >> 5, p = u & 31;
    Y2T[((size_t)(b*64+ch))*NN + n0g + p] = ldsT[ch*33 + p];
  }
  if (tid<64){ atomicAdd(&p2S[b*64+tid], sl[tid]); atomicAdd(&p2Q[b*64+tid], ql[tid]); }
}

// ---------------- F3a: per-batch GN affines (sc + pool2) ----------------------------
__global__ void f3a_affines(
    const float* __restrict__ scS, const float* __restrict__ scQ,
    const float* __restrict__ g_sc, const float* __restrict__ bt_sc,
    const float* __restrict__ b_sc, const float* __restrict__ b_mlp2,
    const float* __restrict__ p2S, const float* __restrict__ p2Q,
    const float* __restrict__ g_p2, const float* __restrict__ bt_p2,
    float* __restrict__ ascT, float* __restrict__ cstF,
    float* __restrict__ a2F, float* __restrict__ d2F)
{
  const int tid = threadIdx.x; // 384
  if (tid < 256){
    const int b = tid >> 7, c = tid & 127;
    float s = scS[b*128+c], q = scQ[b*128+c];
    s += __shfl_xor(s,1); q += __shfl_xor(q,1);
    s += __shfl_xor(s,2); q += __shfl_xor(q,2);
    s += __shfl_xor(s,4); q += __shfl_xor(q,4);
    const float inv = 1.f/(8.f*(float)NN);
    float mu = s*inv, e2 = q*inv, var = e2-mu*mu;
    float rstd = rsqrtf(var + GEPS);
    float a = g_sc[c]*rstd;
    ascT[tid] = a;
    cstF[tid] = b_mlp2[c] + a*b_sc[c] + (bt_sc[c] - mu*a);
  } else {
    const int t = tid - 256;
    const int b = t >> 6, c = t & 63;
    float s = p2S[b*64+c], q = p2Q[b*64+c];
    s += __shfl_xor(s,1); q += __shfl_xor(q,1);
    s += __shfl_xor(s,2); q += __shfl_xor(q,2);
    const float inv = 1.f/(4.f*(float)NN);
    float mu = s*inv, e2 = q*inv, var = e2-mu*mu;
    float rstd = rsqrtf(var + GEPS);
    float a = g_p2[c]*rstd;
    a2F[t] = a; d2F[t] = bt_p2[c] - mu*a;
  }
}

// ---------------- F3b: Wcomb[b] = [ w_mlp2^T (64x128) ; w_sc^T * asc[b] (72x128) ] --
__global__ void __launch_bounds__(256) f3b_wcomb(
    const float* __restrict__ w_mlp2, const float* __restrict__ w_sc,
    const float* __restrict__ ascT, float* __restrict__ Wcomb)
{
  const int t0 = blockIdx.x*256 + threadIdx.x;
  const int stride = gridDim.x*256;
  for (int u=t0; u<2*136*128; u+=stride){
    int bb = u / 17408;
    int rr = u - bb*17408;
    int i = rr >> 7, o = rr & 127;
    Wcomb[u] = (i < 64) ? w_mlp2[o*64+i]
                        : w_sc[o*72 + (i-64)] * ascT[bb*128+o];
  }
}

// ---------------- K6: outer-product reg tile; bank-conflict-free w layout ----------
// grid [b:2][tile:256] = 512; LDS xl[34][128] + wl[34][160] (10-float chunk stride)
__global__ void __launch_bounds__(256,2) k6_final(
    const float* __restrict__ feat, const float* __restrict__ Y2T,
    const float* __restrict__ Wcomb, const float* __restrict__ cstF,
    const float* __restrict__ a2F, const float* __restrict__ d2F,
    float* __restrict__ out)
{
  __shared__ float xl[34*128];
  __shared__ float wl[34*160];
  const int tid = threadIdx.x;
  const int tc = tid & 15;      // channel group: 8 ch
  const int tp = tid >> 4;      // point group: 8 pts
  const int b  = __builtin_amdgcn_readfirstlane((int)blockIdx.x >> 8);
  const int n0 = ((int)blockIdx.x & 255) << 7;

  float acc[8][8];   // [pt][ch]
#pragma unroll
  for (int q=0;q<8;q++){
    float bv = cstF[b*128 + tc*8 + q];
#pragma unroll
    for (int p=0;p<8;p++) acc[p][q] = bv;
  }

  const float* Wb = Wcomb + b*17408;
#pragma unroll 1
  for (int kk=0; kk<4; ++kk){
    __syncthreads();
    for (int u=tid; u<34*128; u+=256){
      int row = u>>7, j = u&127;
      int r = kk*34 + row;
      float v;
      if (r < 64){
        float y = Y2T[(size_t)(b*64+r)*NN + n0 + j];
        v = fmaxf(fmaf(y, a2F[b*64+r], d2F[b*64+r]), 0.f);
      } else {
        v = feat[(size_t)(b*72 + (r-64))*NN + n0 + j];
      }
      xl[u] = v;
    }
    for (int u=tid; u<34*128; u+=256){
      int row = u>>7, c = u&127;
      wl[row*160 + (c>>3)*10 + (c&7)] = Wb[(size_t)(kk*34+row)*128 + c];
    }
    __syncthreads();

#pragma unroll 2
    for (int i=0;i<34;i++){
      const float4 xa = *(const float4*)&xl[i*128 + tp*8];
      const float4 xb = *(const float4*)&xl[i*128 + tp*8 + 4];
      const float4 wa = *(const float4*)&wl[i*160 + tc*10];
      const float4 wb = *(const float4*)&wl[i*160 + tc*10 + 4];
      const float xs[8] = {xa.x,xa.y,xa.z,xa.w,xb.x,xb.y,xb.z,xb.w};
      const float wv[8] = {wa.x,wa.y,wa.z,wa.w,wb.x,wb.y,wb.z,wb.w};
#pragma unroll
      for (int p=0;p<8;p++)
#pragma unroll
        for (int q=0;q<8;q++)
          acc[p][q] = fmaf(wv[q], xs[p], acc[p][q]);
    }
  }

#pragma unroll
  for (int q=0;q<8;q++){
    const int ch = b*128 + tc*8 + q;
    float4 r0, r1;
    float v;
    v = acc[0][q]; r0.x = v>0.f? v : 0.01f*v;
    v = acc[1][q]; r0.y = v>0.f? v : 0.01f*v;
    v = acc[2][q]; r0.z = v>0.f? v : 0.01f*v;
    v = acc[3][q]; r0.w = v>0.f? v : 0.01f*v;
    v = acc[4][q]; r1.x = v>0.f? v : 0.01f*v;
    v = acc[5][q]; r1.y = v>0.f? v : 0.01f*v;
    v = acc[6][q]; r1.z = v>0.f? v : 0.01f*v;
    v = acc[7][q]; r1.w = v>0.f? v : 0.01f*v;
    float* ob = out + (size_t)ch*NN + n0 + tp*8;
    *(float4*)(ob)     = r0;
    *(float4*)(ob + 4) = r1;
  }
}

extern "C" void kernel_launch(void* const* d_in, const int* in_sizes, int n_in,
                              void* d_out, int out_size, void* d_ws, size_t ws_size,
                              hipStream_t stream) {
  (void)in_sizes; (void)n_in; (void)out_size; (void)ws_size;
  const float* coords  = (const float*)d_in[0];
  const float* feats   = (const float*)d_in[1];
  const int*   idx     = (const int*)  d_in[2];
  const float* dist    = (const float*)d_in[3];
  const float* w_mlp1  = (const float*)d_in[4];
  const float* b_mlp1  = (const float*)d_in[5];
  const float* w_lse1  = (const float*)d_in[6];
  const float* b_lse1  = (const float*)d_in[7];
  const float* g_lse1  = (const float*)d_in[8];
  const float* bt_lse1 = (const float*)d_in[9];
  const float* w_pool1 = (const float*)d_in[10];
  const float* b_pool1 = (const float*)d_in[11];
  const float* g_pool1 = (const float*)d_in[12];
  const float* bt_pool1= (const float*)d_in[13];
  const float* w_lse2  = (const float*)d_in[14];
  const float* b_lse2  = (const float*)d_in[15];
  const float* g_lse2  = (const float*)d_in[16];
  const float* bt_lse2 = (const float*)d_in[17];
  const float* w_pool2 = (const float*)d_in[18];
  const float* b_pool2 = (const float*)d_in[19];
  const float* g_pool2 = (const float*)d_in[20];
  const float* bt_pool2= (const float*)d_in[21];
  const float* w_mlp2  = (const float*)d_in[22];
  const float* b_mlp2  = (const float*)d_in[23];
  const float* w_sc    = (const float*)d_in[24];
  const float* b_sc    = (const float*)d_in[25];
  const float* g_sc    = (const float*)d_in[26];
  const float* bt_sc   = (const float*)d_in[27];

  float* ws   = (float*)d_ws;
  float* scS  = ws;            // 256
  float* scQ  = ws + 256;      // 256
  float* vm   = ws + 512;      // 130
  float* p1S  = ws + 704;      // 64
  float* p1Q  = ws + 768;      // 64
  float* p2S  = ws + 832;      // 128
  float* p2Q  = ws + 960;      // 128  (stats end 1088)
  float* w1p  = ws + 1280;     // 768
  float* w2p  = ws + 2048;     // 768
  float* wp1T = ws + 2816;     // 2048
  float* wp2T = ws + 4864;     // 4096 -> 8960
  float* ball = ws + 8960;     // 160 -> 9120
  float* cstF = ws + 9120;     // 256 -> 9376
  float* a2F  = ws + 9376;     // 128 -> 9504
  float* d2F  = ws + 9504;     // 128 -> 9632
  float* ascT = ws + 9632;     // 256 -> 9888
  float* WallT= ws + 9984;     // 11520 -> 21504
  float* Wcomb= ws + 21504;    // 34816 -> 56320
  float* X1   = ws + 57344;    // 2*NN*32
  float* Y1   = X1 + (size_t)2*NN*32;
  float* Y2T  = Y1 + (size_t)2*NN*32;

  hipMemsetAsync(d_ws, 0, 1088*sizeof(float), stream);

  f0_prep<<<32,256,0,stream>>>(w_mlp1,b_mlp1,w_sc,b_sc,w_pool1,w_pool2,
                               WallT,ball,wp1T,wp2T);
  k0_mlp1_scstats<<<512,256,0,stream>>>(feats, WallT, ball, X1, scS, scQ);
  k1_vmom<<<1024,256,0,stream>>>(coords, idx, dist, vm);
  f1_fold<<<1,128,0,stream>>>(w_lse1,b_lse1,g_lse1,bt_lse1,
                              w_lse2,b_lse2,g_lse2,bt_lse2,
                              vm, w1p, w2p);
  k2_lse1_pool1<<<2048,256,0,stream>>>(coords, idx, dist, X1, w1p, wp1T, b_pool1,
                                       Y1, p1S, p1Q);
  k4_lse2_pool2<<<2048,256,0,stream>>>(coords, idx, dist, Y1, w2p, wp2T, b_pool2,
                                       p1S, p1Q, g_pool1, bt_pool1,
                                       Y2T, p2S, p2Q);
  f3a_affines<<<1,384,0,stream>>>(scS,scQ,g_sc,bt_sc,b_sc,b_mlp2,
                                  p2S,p2Q,g_pool2,bt_pool2, ascT,cstF,a2F,d2F);
  f3b_wcomb<<<64,256,0,stream>>>(w_mlp2, w_sc, ascT, Wcomb);
  k6_final<<<512,256,0,stream>>>(feats, Y2T, Wcomb, cstF, a2F, d2F, (float*)d_out);
}

// Round 17
// 240.725 us; speedup vs baseline: 1.0345x; 1.0345x over previous
//
#include <hip/hip_runtime.h>

#define NN 32768
#define GEPS 1e-6f

__device__ __forceinline__ float wredsum(float v){
  v += __shfl_xor(v, 32); v += __shfl_xor(v, 16); v += __shfl_xor(v, 8);
  v += __shfl_xor(v, 4);  v += __shfl_xor(v, 2);  v += __shfl_xor(v, 1);
  return v;
}
// sum across lanes sharing lane&7 (eighth class): flip point bits 3,4,5
__device__ __forceinline__ float eredsum(float v){
  v += __shfl_xor(v, 8); v += __shfl_xor(v, 16); v += __shfl_xor(v, 32);
  return v;
}
// combine the 8 eighth-lanes of one point (bits 0-2)
__device__ __forceinline__ float ecomb(float v){
  v += __shfl_xor(v, 1); v += __shfl_xor(v, 2); v += __shfl_xor(v, 4);
  return v;
}

// ---------------- F0: weight transposes / concats ----------------------------------
__global__ void __launch_bounds__(256) f0_prep(
    const float* __restrict__ w_mlp1, const float* __restrict__ b_mlp1,
    const float* __restrict__ w_sc,   const float* __restrict__ b_sc,
    const float* __restrict__ w_pool1,const float* __restrict__ w_pool2,
    float* __restrict__ WallT, float* __restrict__ ball,
    float* __restrict__ wp1T,  float* __restrict__ wp2T)
{
  const int t0 = blockIdx.x*256 + threadIdx.x;
  const int stride = gridDim.x*256;
  for (int u=t0; u<72*160; u+=stride){
    int i = u/160, o = u - i*160;
    WallT[u] = (o < 128) ? w_sc[o*72+i] : w_mlp1[(o-128)*72+i];
  }
  for (int u=t0; u<160; u+=stride)
    ball[u] = (u < 128) ? b_sc[u] : b_mlp1[u-128];
  for (int u=t0; u<64*32; u+=stride){ int c=u>>5, o=u&31; wp1T[u] = w_pool1[o*64+c]; }
  for (int u=t0; u<64*64; u+=stride){ int c=u>>6, o=u&63; wp2T[u] = w_pool2[o*64+c]; }
}

// ---------------- K0: all-LDS inner loop; 128 pts/block, 2 pts/thread ---------------
__global__ void __launch_bounds__(256,2) k0_mlp1_scstats(
    const float* __restrict__ feat, const float* __restrict__ WallT,
    const float* __restrict__ ball,
    float* __restrict__ X1, float* __restrict__ scS, float* __restrict__ scQ)
{
  __shared__ float xl[72][128];
  __shared__ float wl[72*32];
  __shared__ float ssl[128], sql[128];
  const int tid = threadIdx.x, lane = tid & 63;
  const int wid = __builtin_amdgcn_readfirstlane(tid >> 6);
  const int b   = __builtin_amdgcn_readfirstlane((int)blockIdx.x >> 8);
  const int n0  = ((int)blockIdx.x & 255) << 7;
  const int p0  = lane*2;

  for (int u=tid; u<72*128; u+=256){
    int c = u>>7, j = u&127;
    xl[c][j] = feat[(size_t)(b*72+c)*NN + n0 + j];
  }

#pragma unroll 1
  for (int pass=0; pass<5; ++pass){
    __syncthreads();
    for (int u=tid; u<2304; u+=256){
      int i = u>>5, c = u&31;
      wl[u] = WallT[i*160 + pass*32 + c];
    }
    __syncthreads();

    const int oc = pass*32 + wid*8;
    float a0[8], a1[8];
#pragma unroll
    for (int q=0;q<8;q++){ float bv = ball[oc+q]; a0[q]=bv; a1[q]=bv; }

    const float* wbase = wl + wid*8;
#pragma unroll
    for (int i=0;i<72;i++){
      const float2 x2 = *(const float2*)&xl[i][p0];
      const float4 w0 = *(const float4*)(wbase + i*32);
      const float4 w1 = *(const float4*)(wbase + i*32 + 4);
      a0[0]=fmaf(w0.x,x2.x,a0[0]); a1[0]=fmaf(w0.x,x2.y,a1[0]);
      a0[1]=fmaf(w0.y,x2.x,a0[1]); a1[1]=fmaf(w0.y,x2.y,a1[1]);
      a0[2]=fmaf(w0.z,x2.x,a0[2]); a1[2]=fmaf(w0.z,x2.y,a1[2]);
      a0[3]=fmaf(w0.w,x2.x,a0[3]); a1[3]=fmaf(w0.w,x2.y,a1[3]);
      a0[4]=fmaf(w1.x,x2.x,a0[4]); a1[4]=fmaf(w1.x,x2.y,a1[4]);
      a0[5]=fmaf(w1.y,x2.x,a0[5]); a1[5]=fmaf(w1.y,x2.y,a1[5]);
      a0[6]=fmaf(w1.z,x2.x,a0[6]); a1[6]=fmaf(w1.z,x2.y,a1[6]);
      a0[7]=fmaf(w1.w,x2.x,a0[7]); a1[7]=fmaf(w1.w,x2.y,a1[7]);
    }

    if (pass < 4){
#pragma unroll
      for (int q=0;q<8;q++){
        float s  = wredsum(a0[q]+a1[q]);
        float s2 = wredsum(a0[q]*a0[q] + a1[q]*a1[q]);
        if (lane==0){ ssl[oc+q] = s; sql[oc+q] = s2; }
      }
    } else {
      __syncthreads();
      float* xst = &xl[0][0];      // overlay [32][130]
#pragma unroll
      for (int q=0;q<8;q++){
        float v0 = a0[q], v1 = a1[q];
        v0 = v0 > 0.f ? v0 : 0.2f*v0;
        v1 = v1 > 0.f ? v1 : 0.2f*v1;
        float2 t; t.x=v0; t.y=v1;
        *(float2*)&xst[(wid*8+q)*130 + p0] = t;
      }
      __syncthreads();
      float* xb = X1 + ((size_t)b*NN + n0)*32;
#pragma unroll
      for (int r=0;r<4;r++){
        int u = tid + r*256;
        int p = u>>3, c0 = (u&7)*4;
        float4 o;
        o.x = xst[(c0+0)*130+p]; o.y = xst[(c0+1)*130+p];
        o.z = xst[(c0+2)*130+p]; o.w = xst[(c0+3)*130+p];
        *(float4*)(xb + (size_t)p*32 + c0) = o;
      }
    }
  }

  if (tid < 128){
    atomicAdd(&scS[b*128+tid], ssl[tid]);
    atomicAdd(&scQ[b*128+tid], sql[tid]);
  }
}

// ---------------- K1: v10 moments, 4 threads per point (k-quarters) -----------------
__global__ void __launch_bounds__(256) k1_vmom(
    const float* __restrict__ coords, const int* __restrict__ idx,
    const float* __restrict__ dist, float* __restrict__ vm)
{
  __shared__ float red[4*65];
  const int tid = threadIdx.x, lane = tid & 63, wid = tid >> 6;
  const int gn = blockIdx.x*256 + tid;
  const int pt = gn >> 2, h = gn & 3;
  const int b = pt >> 15, n = pt & (NN-1);
  const size_t pb = (size_t)b*NN + n;
  const float c0 = coords[pb*3+0], c1 = coords[pb*3+1], c2 = coords[pb*3+2];

  int ja[4]; float da[4];
  {
    int4 j4 = *(const int4*)(idx + pb*16 + h*4);
    float4 d4 = *(const float4*)(dist + pb*16 + h*4);
    ja[0]=j4.x; ja[1]=j4.y; ja[2]=j4.z; ja[3]=j4.w;
    da[0]=d4.x; da[1]=d4.y; da[2]=d4.z; da[3]=d4.w;
  }

  float aS[10], aM[55];
#pragma unroll
  for (int i=0;i<10;i++) aS[i]=0.f;
#pragma unroll
  for (int i=0;i<55;i++) aM[i]=0.f;

#pragma unroll
  for (int k=0;k<4;k++){
    const float* nb = coords + ((size_t)b*NN + ja[k])*3;
    const float n0v=nb[0], n1v=nb[1], n2v=nb[2];
    const float v[10] = {c0,c1,c2,n0v,n1v,n2v,c0-n0v,c1-n1v,c2-n2v,da[k]};
#pragma unroll
    for (int i=0;i<10;i++){
      aS[i] += v[i];
#pragma unroll
      for (int j=i;j<10;j++)
        aM[i*10 - (i*(i-1))/2 + (j-i)] += v[i]*v[j];
    }
  }

#pragma unroll
  for (int i=0;i<10;i++){ float s = wredsum(aS[i]); if (lane==0) red[wid*65+i] = s; }
#pragma unroll
  for (int i=0;i<55;i++){ float s = wredsum(aM[i]); if (lane==0) red[wid*65+10+i] = s; }
  __syncthreads();
  if (tid < 65){
    float s = red[tid] + red[65+tid] + red[130+tid] + red[195+tid];
    const int bb = blockIdx.x >> 9;   // 64 pts/block
    atomicAdd(&vm[bb*65+tid], s);
  }
}

// ---------------- F1: fold GN into LSE conv weights --------------------------------
__global__ void f1_fold(
    const float* __restrict__ w_lse1, const float* __restrict__ b_lse1,
    const float* __restrict__ g_lse1, const float* __restrict__ bt_lse1,
    const float* __restrict__ w_lse2, const float* __restrict__ b_lse2,
    const float* __restrict__ g_lse2, const float* __restrict__ bt_lse2,
    const float* __restrict__ vm,
    float* __restrict__ w1p, float* __restrict__ w2p)
{
  const int tid = threadIdx.x; // 128
  const int half = tid >> 6;
  const int u = tid & 63, b = u >> 5, c = u & 31;
  const float* W  = half ? w_lse2  : w_lse1;
  const float* Bv = half ? b_lse2  : b_lse1;
  const float* G  = half ? g_lse2  : g_lse1;
  const float* Bt = half ? bt_lse2 : bt_lse1;
  float wr[10];
#pragma unroll
  for (int i=0;i<10;i++) wr[i] = W[c*10+i];
  const float* S = vm + b*65;
  const float* M = vm + b*65 + 10;
  float P = 0.f;
#pragma unroll
  for (int i=0;i<10;i++) P = fmaf(wr[i], S[i], P);
  float Q = 0.f;
#pragma unroll
  for (int i=0;i<10;i++){
#pragma unroll
    for (int j=i;j<10;j++){
      float m = M[i*10 - (i*(i-1))/2 + (j-i)];
      float t = wr[i]*wr[j]*m;
      Q += (i==j) ? t : 2.f*t;
    }
  }
  const float invNK = 1.f/((float)NN*16.f);
  const float bc = Bv[c];
  float mean = P*invNK + bc;
  float ey2  = (Q + 2.f*bc*P)*invNK + bc*bc;
  float mu = 0.5f*(mean + __shfl_xor(mean,1));
  float e2 = 0.5f*(ey2  + __shfl_xor(ey2, 1));
  float var = e2 - mu*mu;
  float rstd = rsqrtf(var + GEPS);
  float a = G[c]*rstd, d = Bt[c] - mu*a;
  float* out = (half ? w2p : w1p) + (b*32+c)*12;
#pragma unroll
  for (int i=0;i<10;i++) out[i] = wr[i]*a;
  out[10] = bc*a + d;
  out[11] = 0.f;
}

// ---------------- K2: LSE1+pool1; 8 thr/pt; 32 pts/block; LDS pool weights ---------
__global__ void __launch_bounds__(256,6) k2_lse1_pool1(
    const float* __restrict__ coords, const int* __restrict__ idx,
    const float* __restrict__ dist, const float* __restrict__ X1,
    const float* __restrict__ w1p, const float* __restrict__ wp1T,
    const float* __restrict__ b_pool1,
    float* __restrict__ Y1, float* __restrict__ p1S, float* __restrict__ p1Q)
{
  __shared__ float mfl[32*66];
  __shared__ float wlds[64*32];
  __shared__ float sl[32], ql[32];
  const int tid = threadIdx.x, lane = tid & 63;
  const int e = tid & 7;       // eighth
  const int pl = tid >> 3;     // point-local 0..31
  if (tid < 32){ sl[tid]=0.f; ql[tid]=0.f; }
  for (int u=tid; u<2048; u+=256) wlds[u] = wp1T[u];
  __syncthreads();
  const int b = __builtin_amdgcn_readfirstlane((int)blockIdx.x & 1);
  const int n = (((int)blockIdx.x >> 1) << 5) + pl;
  const size_t pb = (size_t)b*NN + n;
  float* mf = &mfl[pl*66];
  const float s16 = 0.0625f;

  // Phase A: ch-split gather — eighth e reads channels e*4..e*4+4 of all 16 nbrs
  {
    int ja[16];
    const int4* ip = (const int4*)(idx + pb*16);
#pragma unroll
    for (int k4=0;k4<4;k4++){
      int4 j4 = ip[k4];
      ja[k4*4+0]=j4.x; ja[k4*4+1]=j4.y; ja[k4*4+2]=j4.z; ja[k4*4+3]=j4.w;
    }
    float af0=0.f, af1=0.f, af2=0.f, af3=0.f;
    const float* xb = X1 + (size_t)b*NN*32 + e*4;
#pragma unroll 4
    for (int k=0;k<16;k++){
      float4 g = *(const float4*)(xb + (size_t)ja[k]*32);
      af0+=g.x; af1+=g.y; af2+=g.z; af3+=g.w;
    }
    mf[32+e*4+0]=af0*s16; mf[32+e*4+1]=af1*s16;
    mf[32+e*4+2]=af2*s16; mf[32+e*4+3]=af3*s16;
  }

  // Phase B: k-split enc — eighth e owns 2 neighbors; channel-chunked (8 at a time)
  {
    int2 j2 = *(const int2*)(idx + pb*16 + e*2);
    float2 d2 = *(const float2*)(dist + pb*16 + e*2);
    const float* nb0 = coords + ((size_t)b*NN + j2.x)*3;
    const float* nb1 = coords + ((size_t)b*NN + j2.y)*3;
    const float nx0=nb0[0], ny0=nb0[1], nz0=nb0[2];
    const float nx1=nb1[0], ny1=nb1[1], nz1=nb1[2];
    const float c0=coords[pb*3], c1=coords[pb*3+1], c2=coords[pb*3+2];
    const float* wrow = w1p + (size_t)(b*32)*12;
#pragma unroll 1
    for (int cc=0;cc<4;cc++){
      float ptc[8];
#pragma unroll
      for (int q=0;q<8;q++){
        const float4* r4 = (const float4*)(wrow + (cc*8+q)*12);
        float4 ra=r4[0], rb=r4[1], rc=r4[2];
        const float t0=ra.x+rb.z, t1=ra.y+rb.w, t2=ra.z+rc.x;
        const float u0=ra.w-rb.z, u1=rb.x-rb.w, u2=rb.y-rc.x;
        const float wd=rc.y;
        float cb = rc.z;
        cb = fmaf(t0,c0,cb); cb = fmaf(t1,c1,cb); cb = fmaf(t2,c2,cb);
        float s0 = cb, s1 = cb;
        s0 = fmaf(u0,nx0,s0); s0 = fmaf(u1,ny0,s0); s0 = fmaf(u2,nz0,s0);
        s0 = fmaf(wd,d2.x,s0);
        s1 = fmaf(u0,nx1,s1); s1 = fmaf(u1,ny1,s1); s1 = fmaf(u2,nz1,s1);
        s1 = fmaf(wd,d2.y,s1);
        ptc[q] = fmaxf(s0,0.f) + fmaxf(s1,0.f);
      }
#pragma unroll
      for (int q=0;q<8;q++) ptc[q] = ecomb(ptc[q]);
      if ((e>>1)==cc){
        float v0 = (e&1) ? ptc[4] : ptc[0];
        float v1 = (e&1) ? ptc[5] : ptc[1];
        float v2 = (e&1) ? ptc[6] : ptc[2];
        float v3 = (e&1) ? ptc[7] : ptc[3];
        mf[e*4+0]=v0*s16; mf[e*4+1]=v1*s16;
        mf[e*4+2]=v2*s16; mf[e*4+3]=v3*s16;
      }
    }
  }
  __syncthreads();

  // pool1: outputs e*4 .. e*4+4 over 64 inputs (weights from LDS)
  const int o0 = e*4;
  float yac[4];
  {
    const float4 b0 = *(const float4*)(b_pool1 + o0);
    yac[0]=b0.x; yac[1]=b0.y; yac[2]=b0.z; yac[3]=b0.w;
  }
#pragma unroll 4
  for (int c=0;c<64;c++){
    const float mc = mf[c];
    const float4 w0 = *(const float4*)(wlds + c*32 + o0);
    yac[0]=fmaf(w0.x,mc,yac[0]); yac[1]=fmaf(w0.y,mc,yac[1]);
    yac[2]=fmaf(w0.z,mc,yac[2]); yac[3]=fmaf(w0.w,mc,yac[3]);
  }
  {
    float4 r0; r0.x=yac[0]; r0.y=yac[1]; r0.z=yac[2]; r0.w=yac[3];
    *(float4*)(Y1 + pb*32 + o0) = r0;
  }
#pragma unroll
  for (int q=0;q<4;q++){
    float s  = eredsum(yac[q]);
    float s2 = eredsum(yac[q]*yac[q]);
    if (lane < 8){ atomicAdd(&sl[o0+q], s); atomicAdd(&ql[o0+q], s2); }
  }
  __syncthreads();
  if (tid<32){ atomicAdd(&p1S[b*32+tid], sl[tid]); atomicAdd(&p1Q[b*32+tid], ql[tid]); }
}

// ---------------- K4: LSE2+pool2; GN-on-gather fused; LDS pool weights --------------
__global__ void __launch_bounds__(256,6) k4_lse2_pool2(
    const float* __restrict__ coords, const int* __restrict__ idx,
    const float* __restrict__ dist, const float* __restrict__ Y1,
    const float* __restrict__ w2p, const float* __restrict__ wp2T,
    const float* __restrict__ b_pool2,
    const float* __restrict__ p1S, const float* __restrict__ p1Q,
    const float* __restrict__ g_p1, const float* __restrict__ bt_p1,
    float* __restrict__ Y2T, float* __restrict__ p2S, float* __restrict__ p2Q)
{
  __shared__ float mfl[32*66];     // also holds transposed store stage [64][33]
  __shared__ float wlds[64*64];
  __shared__ float sl[64], ql[64];
  __shared__ float al[32], dl[32];
  const int tid = threadIdx.x, lane = tid & 63;
  const int e = tid & 7;
  const int pl = tid >> 3;
  const int b = __builtin_amdgcn_readfirstlane((int)blockIdx.x & 1);
  if (tid < 64){ sl[tid]=0.f; ql[tid]=0.f; }
  if (tid >= 64 && tid < 96){
    const int c = tid - 64;
    float s = p1S[b*32+c], q = p1Q[b*32+c];
    s += __shfl_xor(s,1); q += __shfl_xor(q,1);
    const float inv = 1.f/(2.f*(float)NN);
    float mu = s*inv, e2 = q*inv, var = e2-mu*mu;
    float rstd = rsqrtf(var + GEPS);
    float a = g_p1[c]*rstd;
    al[c] = a; dl[c] = bt_p1[c] - mu*a;
  }
  for (int u=tid; u<4096; u+=256) wlds[u] = wp2T[u];
  __syncthreads();
  const int n0g = (((int)blockIdx.x >> 1) << 5);
  const int n = n0g + pl;
  const size_t pb = (size_t)b*NN + n;
  float* mf = &mfl[pl*66];
  const float s16 = 0.0625f;

  // Phase A: ch-split gather with fused pool1-GN+ReLU
  {
    const float a0g=al[e*4+0], a1g=al[e*4+1], a2g=al[e*4+2], a3g=al[e*4+3];
    const float d0g=dl[e*4+0], d1g=dl[e*4+1], d2g=dl[e*4+2], d3g=dl[e*4+3];
    int ja[16];
    const int4* ip = (const int4*)(idx + pb*16);
#pragma unroll
    for (int k4=0;k4<4;k4++){
      int4 j4 = ip[k4];
      ja[k4*4+0]=j4.x; ja[k4*4+1]=j4.y; ja[k4*4+2]=j4.z; ja[k4*4+3]=j4.w;
    }
    float af0=0.f, af1=0.f, af2=0.f, af3=0.f;
    const float* yb = Y1 + (size_t)b*NN*32 + e*4;
#pragma unroll 4
    for (int k=0;k<16;k++){
      float4 g = *(const float4*)(yb + (size_t)ja[k]*32);
      af0 += fmaxf(fmaf(g.x, a0g, d0g), 0.f);
      af1 += fmaxf(fmaf(g.y, a1g, d1g), 0.f);
      af2 += fmaxf(fmaf(g.z, a2g, d2g), 0.f);
      af3 += fmaxf(fmaf(g.w, a3g, d3g), 0.f);
    }
    mf[32+e*4+0]=af0*s16; mf[32+e*4+1]=af1*s16;
    mf[32+e*4+2]=af2*s16; mf[32+e*4+3]=af3*s16;
  }

  // Phase B: k-split enc
  {
    int2 j2 = *(const int2*)(idx + pb*16 + e*2);
    float2 d2 = *(const float2*)(dist + pb*16 + e*2);
    const float* nb0 = coords + ((size_t)b*NN + j2.x)*3;
    const float* nb1 = coords + ((size_t)b*NN + j2.y)*3;
    const float nx0=nb0[0], ny0=nb0[1], nz0=nb0[2];
    const float nx1=nb1[0], ny1=nb1[1], nz1=nb1[2];
    const float c0=coords[pb*3], c1=coords[pb*3+1], c2=coords[pb*3+2];
    const float* wrow = w2p + (size_t)(b*32)*12;
#pragma unroll 1
    for (int cc=0;cc<4;cc++){
      float ptc[8];
#pragma unroll
      for (int q=0;q<8;q++){
        const float4* r4 = (const float4*)(wrow + (cc*8+q)*12);
        float4 ra=r4[0], rb=r4[1], rc=r4[2];
        const float t0=ra.x+rb.z, t1=ra.y+rb.w, t2=ra.z+rc.x;
        const float u0=ra.w-rb.z, u1=rb.x-rb.w, u2=rb.y-rc.x;
        const float wd=rc.y;
        float cb = rc.z;
        cb = fmaf(t0,c0,cb); cb = fmaf(t1,c1,cb); cb = fmaf(t2,c2,cb);
        float s0 = cb, s1 = cb;
        s0 = fmaf(u0,nx0,s0); s0 = fmaf(u1,ny0,s0); s0 = fmaf(u2,nz0,s0);
        s0 = fmaf(wd,d2.x,s0);
        s1 = fmaf(u0,nx1,s1); s1 = fmaf(u1,ny1,s1); s1 = fmaf(u2,nz1,s1);
        s1 = fmaf(wd,d2.y,s1);
        ptc[q] = fmaxf(s0,0.f) + fmaxf(s1,0.f);
      }
#pragma unroll
      for (int q=0;q<8;q++) ptc[q] = ecomb(ptc[q]);
      if ((e>>1)==cc){
        float v0 = (e&1) ? ptc[4] : ptc[0];
        float v1 = (e&1) ? ptc[5] : ptc[1];
        float v2 = (e&1) ? ptc[6] : ptc[2];
        float v3 = (e&1) ? ptc[7] : ptc[3];
        mf[e*4+0]=v0*s16; mf[e*4+1]=v1*s16;
        mf[e*4+2]=v2*s16; mf[e*4+3]=v3*s16;
      }
    }
  }
  __syncthreads();

  // pool2: outputs e*8 .. e*8+8 over 64 inputs (weights from LDS)
  const int o0 = e*8;
  float yac[8];
  {
    const float4 b0 = *(const float4*)(b_pool2 + o0);
    const float4 b1 = *(const float4*)(b_pool2 + o0 + 4);
    yac[0]=b0.x; yac[1]=b0.y; yac[2]=b0.z; yac[3]=b0.w;
    yac[4]=b1.x; yac[5]=b1.y; yac[6]=b1.z; yac[7]=b1.w;
  }
#pragma unroll 4
  for (int c=0;c<64;c++){
    const float mc = mf[c];
    const float4 w0 = *(const float4*)(wlds + c*64 + o0);
    const float4 w1 = *(const float4*)(wlds + c*64 + o0 + 4);
    yac[0]=fmaf(w0.x,mc,yac[0]); yac[1]=fmaf(w0.y,mc,yac[1]);
    yac[2]=fmaf(w0.z,mc,yac[2]); yac[3]=fmaf(w0.w,mc,yac[3]);
    yac[4]=fmaf(w1.x,mc,yac[4]); yac[5]=fmaf(w1.y,mc,yac[5]);
    yac[6]=fmaf(w1.z,mc,yac[6]); yac[7]=fmaf(w1.w,mc,yac[7]);
  }
  // stats first (before overwriting mfl)
#pragma unroll
  for (int q=0;q<8;q++){
    float s  = eredsum(yac[q]);
    float s2 = eredsum(yac[q]*yac[q]);
    if (lane < 8){ atomicAdd(&sl[o0+q], s); atomicAdd(&ql[o0+q], s2); }
  }
  __syncthreads();   // all mf reads + stats done
  // stage transposed: lds[ch][pt], stride 33 (64*33=2112 = 32*66)
  float* ldsT = &mfl[0];
#pragma unroll
  for (int o=0;o<8;o++) ldsT[(o0+o)*33 + pl] = yac[o];
  __syncthreads();
  // coalesced channel-major store: 64 ch x 32 pts
#pragma unroll
  for (int r=0;r<8;r++){
    int u = tid + r*256;
    int ch = u >> 5, p = u & 31;
    Y2T[((size_t)(b*64+ch))*NN + n0g + p] = ldsT[ch*33 + p];
  }
  if (tid<64){ atomicAdd(&p2S[b*64+tid], sl[tid]); atomicAdd(&p2Q[b*64+tid], ql[tid]); }
}

// ---------------- F3a: per-batch GN affines (sc + pool2) ----------------------------
__global__ void f3a_affines(
    const float* __restrict__ scS, const float* __restrict__ scQ,
    const float* __restrict__ g_sc, const float* __restrict__ bt_sc,
    const float* __restrict__ b_sc, const float* __restrict__ b_mlp2,
    const float* __restrict__ p2S, const float* __restrict__ p2Q,
    const float* __restrict__ g_p2, const float* __restrict__ bt_p2,
    float* __restrict__ ascT, float* __restrict__ cstF,
    float* __restrict__ a2F, float* __restrict__ d2F)
{
  const int tid = threadIdx.x; // 384
  if (tid < 256){
    const int b = tid >> 7, c = tid & 127;
    float s = scS[b*128+c], q = scQ[b*128+c];
    s += __shfl_xor(s,1); q += __shfl_xor(q,1);
    s += __shfl_xor(s,2); q += __shfl_xor(q,2);
    s += __shfl_xor(s,4); q += __shfl_xor(q,4);
    const float inv = 1.f/(8.f*(float)NN);
    float mu = s*inv, e2 = q*inv, var = e2-mu*mu;
    float rstd = rsqrtf(var + GEPS);
    float a = g_sc[c]*rstd;
    ascT[tid] = a;
    cstF[tid] = b_mlp2[c] + a*b_sc[c] + (bt_sc[c] - mu*a);
  } else {
    const int t = tid - 256;
    const int b = t >> 6, c = t & 63;
    float s = p2S[b*64+c], q = p2Q[b*64+c];
    s += __shfl_xor(s,1); q += __shfl_xor(q,1);
    s += __shfl_xor(s,2); q += __shfl_xor(q,2);
    const float inv = 1.f/(4.f*(float)NN);
    float mu = s*inv, e2 = q*inv, var = e2-mu*mu;
    float rstd = rsqrtf(var + GEPS);
    float a = g_p2[c]*rstd;
    a2F[t] = a; d2F[t] = bt_p2[c] - mu*a;
  }
}

// ---------------- F3b: Wcomb[b] = [ w_mlp2^T (64x128) ; w_sc^T * asc[b] (72x128) ] --
__global__ void __launch_bounds__(256) f3b_wcomb(
    const float* __restrict__ w_mlp2, const float* __restrict__ w_sc,
    const float* __restrict__ ascT, float* __restrict__ Wcomb)
{
  const int t0 = blockIdx.x*256 + threadIdx.x;
  const int stride = gridDim.x*256;
  for (int u=t0; u<2*136*128; u+=stride){
    int bb = u / 17408;
    int rr = u - bb*17408;
    int i = rr >> 7, o = rr & 127;
    Wcomb[u] = (i < 64) ? w_mlp2[o*64+i]
                        : w_sc[o*72 + (i-64)] * ascT[bb*128+o];
  }
}

// ---------------- K6: outer-product reg tile; 64 pts x 128 ch; 4x8/thread ----------
// grid [b:2][tile:512] = 1024; LDS xl[34][64] + wl[34][160] = 30464 B; 4 K-chunks
__global__ void __launch_bounds__(256,4) k6_final(
    const float* __restrict__ feat, const float* __restrict__ Y2T,
    const float* __restrict__ Wcomb, const float* __restrict__ cstF,
    const float* __restrict__ a2F, const float* __restrict__ d2F,
    float* __restrict__ out)
{
  __shared__ float xl[34*64];
  __shared__ float wl[34*160];
  const int tid = threadIdx.x;
  const int tc = tid & 15;      // channel group: 8 ch
  const int tp = tid >> 4;      // point group: 4 pts
  const int b  = __builtin_amdgcn_readfirstlane((int)blockIdx.x >> 9);
  const int n0 = ((int)blockIdx.x & 511) << 6;

  float acc[4][8];   // [pt][ch]
#pragma unroll
  for (int q=0;q<8;q++){
    float bv = cstF[b*128 + tc*8 + q];
#pragma unroll
    for (int p=0;p<4;p++) acc[p][q] = bv;
  }

  const float* Wb = Wcomb + b*17408;
#pragma unroll 1
  for (int kk=0; kk<4; ++kk){
    __syncthreads();
    for (int u=tid; u<34*64; u+=256){
      int row = u>>6, j = u&63;
      int r = kk*34 + row;
      float v;
      if (r < 64){
        float y = Y2T[(size_t)(b*64+r)*NN + n0 + j];
        v = fmaxf(fmaf(y, a2F[b*64+r], d2F[b*64+r]), 0.f);
      } else {
        v = feat[(size_t)(b*72 + (r-64))*NN + n0 + j];
      }
      xl[u] = v;
    }
    for (int u=tid; u<34*128; u+=256){
      int row = u>>7, c = u&127;
      wl[row*160 + (c>>3)*10 + (c&7)] = Wb[(size_t)(kk*34+row)*128 + c];
    }
    __syncthreads();

#pragma unroll 2
    for (int i=0;i<34;i++){
      const float4 xa = *(const float4*)&xl[i*64 + tp*4];
      const float4 wa = *(const float4*)&wl[i*160 + tc*10];
      const float4 wb = *(const float4*)&wl[i*160 + tc*10 + 4];
      const float xs[4] = {xa.x,xa.y,xa.z,xa.w};
      const float wv[8] = {wa.x,wa.y,wa.z,wa.w,wb.x,wb.y,wb.z,wb.w};
#pragma unroll
      for (int p=0;p<4;p++)
#pragma unroll
        for (int q=0;q<8;q++)
          acc[p][q] = fmaf(wv[q], xs[p], acc[p][q]);
    }
  }

#pragma unroll
  for (int q=0;q<8;q++){
    const int ch = b*128 + tc*8 + q;
    float4 r0;
    float v;
    v = acc[0][q]; r0.x = v>0.f? v : 0.01f*v;
    v = acc[1][q]; r0.y = v>0.f? v : 0.01f*v;
    v = acc[2][q]; r0.z = v>0.f? v : 0.01f*v;
    v = acc[3][q]; r0.w = v>0.f? v : 0.01f*v;
    *(float4*)(out + (size_t)ch*NN + n0 + tp*4) = r0;
  }
}

extern "C" void kernel_launch(void* const* d_in, const int* in_sizes, int n_in,
                              void* d_out, int out_size, void* d_ws, size_t ws_size,
                              hipStream_t stream) {
  (void)in_sizes; (void)n_in; (void)out_size; (void)ws_size;
  const float* coords  = (const float*)d_in[0];
  const float* feats   = (const float*)d_in[1];
  const int*   idx     = (const int*)  d_in[2];
  const float* dist    = (const float*)d_in[3];
  const float* w_mlp1  = (const float*)d_in[4];
  const float* b_mlp1  = (const float*)d_in[5];
  const float* w_lse1  = (const float*)d_in[6];
  const float* b_lse1  = (const float*)d_in[7];
  const float* g_lse1  = (const float*)d_in[8];
  const float* bt_lse1 = (const float*)d_in[9];
  const float* w_pool1 = (const float*)d_in[10];
  const float* b_pool1 = (const float*)d_in[11];
  const float* g_pool1 = (const float*)d_in[12];
  const float* bt_pool1= (const float*)d_in[13];
  const float* w_lse2  = (const float*)d_in[14];
  const float* b_lse2  = (const float*)d_in[15];
  const float* g_lse2  = (const float*)d_in[16];
  const float* bt_lse2 = (const float*)d_in[17];
  const float* w_pool2 = (const float*)d_in[18];
  const float* b_pool2 = (const float*)d_in[19];
  const float* g_pool2 = (const float*)d_in[20];
  const float* bt_pool2= (const float*)d_in[21];
  const float* w_mlp2  = (const float*)d_in[22];
  const float* b_mlp2  = (const float*)d_in[23];
  const float* w_sc    = (const float*)d_in[24];
  const float* b_sc    = (const float*)d_in[25];
  const float* g_sc    = (const float*)d_in[26];
  const float* bt_sc   = (const float*)d_in[27];

  float* ws   = (float*)d_ws;
  float* scS  = ws;            // 256
  float* scQ  = ws + 256;      // 256
  float* vm   = ws + 512;      // 130
  float* p1S  = ws + 704;      // 64
  float* p1Q  = ws + 768;      // 64
  float* p2S  = ws + 832;      // 128
  float* p2Q  = ws + 960;      // 128  (stats end 1088)
  float* w1p  = ws + 1280;     // 768
  float* w2p  = ws + 2048;     // 768
  float* wp1T = ws + 2816;     // 2048
  float* wp2T = ws + 4864;     // 4096 -> 8960
  float* ball = ws + 8960;     // 160 -> 9120
  float* cstF = ws + 9120;     // 256 -> 9376
  float* a2F  = ws + 9376;     // 128 -> 9504
  float* d2F  = ws + 9504;     // 128 -> 9632
  float* ascT = ws + 9632;     // 256 -> 9888
  float* WallT= ws + 9984;     // 11520 -> 21504
  float* Wcomb= ws + 21504;    // 34816 -> 56320
  float* X1   = ws + 57344;    // 2*NN*32
  float* Y1   = X1 + (size_t)2*NN*32;
  float* Y2T  = Y1 + (size_t)2*NN*32;

  hipMemsetAsync(d_ws, 0, 1088*sizeof(float), stream);

  f0_prep<<<32,256,0,stream>>>(w_mlp1,b_mlp1,w_sc,b_sc,w_pool1,w_pool2,
                               WallT,ball,wp1T,wp2T);
  k0_mlp1_scstats<<<512,256,0,stream>>>(feats, WallT, ball, X1, scS, scQ);
  k1_vmom<<<1024,256,0,stream>>>(coords, idx, dist, vm);
  f1_fold<<<1,128,0,stream>>>(w_lse1,b_lse1,g_lse1,bt_lse1,
                              w_lse2,b_lse2,g_lse2,bt_lse2,
                              vm, w1p, w2p);
  k2_lse1_pool1<<<2048,256,0,stream>>>(coords, idx, dist, X1, w1p, wp1T, b_pool1,
                                       Y1, p1S, p1Q);
  k4_lse2_pool2<<<2048,256,0,stream>>>(coords, idx, dist, Y1, w2p, wp2T, b_pool2,
                                       p1S, p1Q, g_pool1, bt_pool1,
                                       Y2T, p2S, p2Q);
  f3a_affines<<<1,384,0,stream>>>(scS,scQ,g_sc,bt_sc,b_sc,b_mlp2,
                                  p2S,p2Q,g_pool2,bt_pool2, ascT,cstF,a2F,d2F);
  f3b_wcomb<<<64,256,0,stream>>>(w_mlp2, w_sc, ascT, Wcomb);
  k6_final<<<1024,256,0,stream>>>(feats, Y2T, Wcomb, cstF, a2F, d2F, (float*)d_out);
}

// Round 18
// 236.148 us; speedup vs baseline: 1.0545x; 1.0194x over previous
//
#include <hip/hip_runtime.h>
#include <hip/hip_fp16.h>

#define NN 32768
#define GEPS 1e-6f

__device__ __forceinline__ float wredsum(float v){
  v += __shfl_xor(v, 32); v += __shfl_xor(v, 16); v += __shfl_xor(v, 8);
  v += __shfl_xor(v, 4);  v += __shfl_xor(v, 2);  v += __shfl_xor(v, 1);
  return v;
}
__device__ __forceinline__ float eredsum(float v){
  v += __shfl_xor(v, 8); v += __shfl_xor(v, 16); v += __shfl_xor(v, 32);
  return v;
}
__device__ __forceinline__ float ecomb(float v){
  v += __shfl_xor(v, 1); v += __shfl_xor(v, 2); v += __shfl_xor(v, 4);
  return v;
}

// ---------------- F0: weight transposes / concats ----------------------------------
__global__ void __launch_bounds__(256) f0_prep(
    const float* __restrict__ w_mlp1, const float* __restrict__ b_mlp1,
    const float* __restrict__ w_sc,   const float* __restrict__ b_sc,
    const float* __restrict__ w_pool1,const float* __restrict__ w_pool2,
    float* __restrict__ WallT, float* __restrict__ ball,
    float* __restrict__ wp1T,  float* __restrict__ wp2T)
{
  const int t0 = blockIdx.x*256 + threadIdx.x;
  const int stride = gridDim.x*256;
  for (int u=t0; u<72*160; u+=stride){
    int i = u/160, o = u - i*160;
    WallT[u] = (o < 128) ? w_sc[o*72+i] : w_mlp1[(o-128)*72+i];
  }
  for (int u=t0; u<160; u+=stride)
    ball[u] = (u < 128) ? b_sc[u] : b_mlp1[u-128];
  for (int u=t0; u<64*32; u+=stride){ int c=u>>5, o=u&31; wp1T[u] = w_pool1[o*64+c]; }
  for (int u=t0; u<64*64; u+=stride){ int c=u>>6, o=u&63; wp2T[u] = w_pool2[o*64+c]; }
}

// ---------------- K0: all-LDS inner loop; 128 pts/block; X1 stored fp16 -------------
__global__ void __launch_bounds__(256,2) k0_mlp1_scstats(
    const float* __restrict__ feat, const float* __restrict__ WallT,
    const float* __restrict__ ball,
    __half* __restrict__ X1, float* __restrict__ scS, float* __restrict__ scQ)
{
  __shared__ float xl[72][128];
  __shared__ float wl[72*32];
  __shared__ float ssl[128], sql[128];
  const int tid = threadIdx.x, lane = tid & 63;
  const int wid = __builtin_amdgcn_readfirstlane(tid >> 6);
  const int b   = __builtin_amdgcn_readfirstlane((int)blockIdx.x >> 8);
  const int n0  = ((int)blockIdx.x & 255) << 7;
  const int p0  = lane*2;

  for (int u=tid; u<72*128; u+=256){
    int c = u>>7, j = u&127;
    xl[c][j] = feat[(size_t)(b*72+c)*NN + n0 + j];
  }

#pragma unroll 1
  for (int pass=0; pass<5; ++pass){
    __syncthreads();
    for (int u=tid; u<2304; u+=256){
      int i = u>>5, c = u&31;
      wl[u] = WallT[i*160 + pass*32 + c];
    }
    __syncthreads();

    const int oc = pass*32 + wid*8;
    float a0[8], a1[8];
#pragma unroll
    for (int q=0;q<8;q++){ float bv = ball[oc+q]; a0[q]=bv; a1[q]=bv; }

    const float* wbase = wl + wid*8;
#pragma unroll
    for (int i=0;i<72;i++){
      const float2 x2 = *(const float2*)&xl[i][p0];
      const float4 w0 = *(const float4*)(wbase + i*32);
      const float4 w1 = *(const float4*)(wbase + i*32 + 4);
      a0[0]=fmaf(w0.x,x2.x,a0[0]); a1[0]=fmaf(w0.x,x2.y,a1[0]);
      a0[1]=fmaf(w0.y,x2.x,a0[1]); a1[1]=fmaf(w0.y,x2.y,a1[1]);
      a0[2]=fmaf(w0.z,x2.x,a0[2]); a1[2]=fmaf(w0.z,x2.y,a1[2]);
      a0[3]=fmaf(w0.w,x2.x,a0[3]); a1[3]=fmaf(w0.w,x2.y,a1[3]);
      a0[4]=fmaf(w1.x,x2.x,a0[4]); a1[4]=fmaf(w1.x,x2.y,a1[4]);
      a0[5]=fmaf(w1.y,x2.x,a0[5]); a1[5]=fmaf(w1.y,x2.y,a1[5]);
      a0[6]=fmaf(w1.z,x2.x,a0[6]); a1[6]=fmaf(w1.z,x2.y,a1[6]);
      a0[7]=fmaf(w1.w,x2.x,a0[7]); a1[7]=fmaf(w1.w,x2.y,a1[7]);
    }

    if (pass < 4){
#pragma unroll
      for (int q=0;q<8;q++){
        float s  = wredsum(a0[q]+a1[q]);
        float s2 = wredsum(a0[q]*a0[q] + a1[q]*a1[q]);
        if (lane==0){ ssl[oc+q] = s; sql[oc+q] = s2; }
      }
    } else {
      __syncthreads();
      float* xst = &xl[0][0];      // overlay [32][130]
#pragma unroll
      for (int q=0;q<8;q++){
        float v0 = a0[q], v1 = a1[q];
        v0 = v0 > 0.f ? v0 : 0.2f*v0;
        v1 = v1 > 0.f ? v1 : 0.2f*v1;
        float2 t; t.x=v0; t.y=v1;
        *(float2*)&xst[(wid*8+q)*130 + p0] = t;
      }
      __syncthreads();
      __half* xb = X1 + ((size_t)b*NN + n0)*32;
#pragma unroll
      for (int r=0;r<2;r++){
        int u = tid + r*256;           // 512 total: 128 pts x 4 octets
        int p = u>>2, co = (u&3)*8;
        __half2 h[4];
        h[0] = __floats2half2_rn(xst[(co+0)*130+p], xst[(co+1)*130+p]);
        h[1] = __floats2half2_rn(xst[(co+2)*130+p], xst[(co+3)*130+p]);
        h[2] = __floats2half2_rn(xst[(co+4)*130+p], xst[(co+5)*130+p]);
        h[3] = __floats2half2_rn(xst[(co+6)*130+p], xst[(co+7)*130+p]);
        *(uint4*)(xb + (size_t)p*32 + co) = *(uint4*)h;
      }
    }
  }

  if (tid < 128){
    atomicAdd(&scS[b*128+tid], ssl[tid]);
    atomicAdd(&scQ[b*128+tid], sql[tid]);
  }
}

// ---------------- K1: v10 moments, 4 threads per point (k-quarters) -----------------
__global__ void __launch_bounds__(256) k1_vmom(
    const float* __restrict__ coords, const int* __restrict__ idx,
    const float* __restrict__ dist, float* __restrict__ vm)
{
  __shared__ float red[4*65];
  const int tid = threadIdx.x, lane = tid & 63, wid = tid >> 6;
  const int gn = blockIdx.x*256 + tid;
  const int pt = gn >> 2, h = gn & 3;
  const int b = pt >> 15, n = pt & (NN-1);
  const size_t pb = (size_t)b*NN + n;
  const float c0 = coords[pb*3+0], c1 = coords[pb*3+1], c2 = coords[pb*3+2];

  int ja[4]; float da[4];
  {
    int4 j4 = *(const int4*)(idx + pb*16 + h*4);
    float4 d4 = *(const float4*)(dist + pb*16 + h*4);
    ja[0]=j4.x; ja[1]=j4.y; ja[2]=j4.z; ja[3]=j4.w;
    da[0]=d4.x; da[1]=d4.y; da[2]=d4.z; da[3]=d4.w;
  }

  float aS[10], aM[55];
#pragma unroll
  for (int i=0;i<10;i++) aS[i]=0.f;
#pragma unroll
  for (int i=0;i<55;i++) aM[i]=0.f;

#pragma unroll
  for (int k=0;k<4;k++){
    const float* nb = coords + ((size_t)b*NN + ja[k])*3;
    const float n0v=nb[0], n1v=nb[1], n2v=nb[2];
    const float v[10] = {c0,c1,c2,n0v,n1v,n2v,c0-n0v,c1-n1v,c2-n2v,da[k]};
#pragma unroll
    for (int i=0;i<10;i++){
      aS[i] += v[i];
#pragma unroll
      for (int j=i;j<10;j++)
        aM[i*10 - (i*(i-1))/2 + (j-i)] += v[i]*v[j];
    }
  }

#pragma unroll
  for (int i=0;i<10;i++){ float s = wredsum(aS[i]); if (lane==0) red[wid*65+i] = s; }
#pragma unroll
  for (int i=0;i<55;i++){ float s = wredsum(aM[i]); if (lane==0) red[wid*65+10+i] = s; }
  __syncthreads();
  if (tid < 65){
    float s = red[tid] + red[65+tid] + red[130+tid] + red[195+tid];
    const int bb = blockIdx.x >> 9;
    atomicAdd(&vm[bb*65+tid], s);
  }
}

// ---------------- F1: fold GN into LSE conv weights --------------------------------
__global__ void f1_fold(
    const float* __restrict__ w_lse1, const float* __restrict__ b_lse1,
    const float* __restrict__ g_lse1, const float* __restrict__ bt_lse1,
    const float* __restrict__ w_lse2, const float* __restrict__ b_lse2,
    const float* __restrict__ g_lse2, const float* __restrict__ bt_lse2,
    const float* __restrict__ vm,
    float* __restrict__ w1p, float* __restrict__ w2p)
{
  const int tid = threadIdx.x; // 128
  const int half = tid >> 6;
  const int u = tid & 63, b = u >> 5, c = u & 31;
  const float* W  = half ? w_lse2  : w_lse1;
  const float* Bv = half ? b_lse2  : b_lse1;
  const float* G  = half ? g_lse2  : g_lse1;
  const float* Bt = half ? bt_lse2 : bt_lse1;
  float wr[10];
#pragma unroll
  for (int i=0;i<10;i++) wr[i] = W[c*10+i];
  const float* S = vm + b*65;
  const float* M = vm + b*65 + 10;
  float P = 0.f;
#pragma unroll
  for (int i=0;i<10;i++) P = fmaf(wr[i], S[i], P);
  float Q = 0.f;
#pragma unroll
  for (int i=0;i<10;i++){
#pragma unroll
    for (int j=i;j<10;j++){
      float m = M[i*10 - (i*(i-1))/2 + (j-i)];
      float t = wr[i]*wr[j]*m;
      Q += (i==j) ? t : 2.f*t;
    }
  }
  const float invNK = 1.f/((float)NN*16.f);
  const float bc = Bv[c];
  float mean = P*invNK + bc;
  float ey2  = (Q + 2.f*bc*P)*invNK + bc*bc;
  float mu = 0.5f*(mean + __shfl_xor(mean,1));
  float e2 = 0.5f*(ey2  + __shfl_xor(ey2, 1));
  float var = e2 - mu*mu;
  float rstd = rsqrtf(var + GEPS);
  float a = G[c]*rstd, d = Bt[c] - mu*a;
  float* out = (half ? w2p : w1p) + (b*32+c)*12;
#pragma unroll
  for (int i=0;i<10;i++) out[i] = wr[i]*a;
  out[10] = bc*a + d;
  out[11] = 0.f;
}

// ---------------- K2: LSE1+pool1; fp16 gather; LDS pool weights --------------------
__global__ void __launch_bounds__(256,6) k2_lse1_pool1(
    const float* __restrict__ coords, const int* __restrict__ idx,
    const float* __restrict__ dist, const __half* __restrict__ X1,
    const float* __restrict__ w1p, const float* __restrict__ wp1T,
    const float* __restrict__ b_pool1,
    __half* __restrict__ Y1, float* __restrict__ p1S, float* __restrict__ p1Q)
{
  __shared__ float mfl[32*66];
  __shared__ float wlds[64*32];
  __shared__ float sl[32], ql[32];
  const int tid = threadIdx.x, lane = tid & 63;
  const int e = tid & 7;
  const int pl = tid >> 3;
  if (tid < 32){ sl[tid]=0.f; ql[tid]=0.f; }
  for (int u=tid; u<2048; u+=256) wlds[u] = wp1T[u];
  __syncthreads();
  const int b = __builtin_amdgcn_readfirstlane((int)blockIdx.x & 1);
  const int n = (((int)blockIdx.x >> 1) << 5) + pl;
  const size_t pb = (size_t)b*NN + n;
  float* mf = &mfl[pl*66];
  const float s16 = 0.0625f;

  // Phase A: ch-split gather (fp16) — eighth e reads channels e*4..e*4+4
  {
    int ja[16];
    const int4* ip = (const int4*)(idx + pb*16);
#pragma unroll
    for (int k4=0;k4<4;k4++){
      int4 j4 = ip[k4];
      ja[k4*4+0]=j4.x; ja[k4*4+1]=j4.y; ja[k4*4+2]=j4.z; ja[k4*4+3]=j4.w;
    }
    float af0=0.f, af1=0.f, af2=0.f, af3=0.f;
    const __half* xb = X1 + (size_t)b*NN*32 + e*4;
#pragma unroll 4
    for (int k=0;k<16;k++){
      uint2 v = *(const uint2*)(xb + (size_t)ja[k]*32);
      __half2 h0 = *(__half2*)&v.x, h1 = *(__half2*)&v.y;
      float2 f0 = __half22float2(h0), f1 = __half22float2(h1);
      af0+=f0.x; af1+=f0.y; af2+=f1.x; af3+=f1.y;
    }
    mf[32+e*4+0]=af0*s16; mf[32+e*4+1]=af1*s16;
    mf[32+e*4+2]=af2*s16; mf[32+e*4+3]=af3*s16;
  }

  // Phase B: k-split enc
  {
    int2 j2 = *(const int2*)(idx + pb*16 + e*2);
    float2 d2 = *(const float2*)(dist + pb*16 + e*2);
    const float* nb0 = coords + ((size_t)b*NN + j2.x)*3;
    const float* nb1 = coords + ((size_t)b*NN + j2.y)*3;
    const float nx0=nb0[0], ny0=nb0[1], nz0=nb0[2];
    const float nx1=nb1[0], ny1=nb1[1], nz1=nb1[2];
    const float c0=coords[pb*3], c1=coords[pb*3+1], c2=coords[pb*3+2];
    const float* wrow = w1p + (size_t)(b*32)*12;
#pragma unroll 1
    for (int cc=0;cc<4;cc++){
      float ptc[8];
#pragma unroll
      for (int q=0;q<8;q++){
        const float4* r4 = (const float4*)(wrow + (cc*8+q)*12);
        float4 ra=r4[0], rb=r4[1], rc=r4[2];
        const float t0=ra.x+rb.z, t1=ra.y+rb.w, t2=ra.z+rc.x;
        const float u0=ra.w-rb.z, u1=rb.x-rb.w, u2=rb.y-rc.x;
        const float wd=rc.y;
        float cb = rc.z;
        cb = fmaf(t0,c0,cb); cb = fmaf(t1,c1,cb); cb = fmaf(t2,c2,cb);
        float s0 = cb, s1 = cb;
        s0 = fmaf(u0,nx0,s0); s0 = fmaf(u1,ny0,s0); s0 = fmaf(u2,nz0,s0);
        s0 = fmaf(wd,d2.x,s0);
        s1 = fmaf(u0,nx1,s1); s1 = fmaf(u1,ny1,s1); s1 = fmaf(u2,nz1,s1);
        s1 = fmaf(wd,d2.y,s1);
        ptc[q] = fmaxf(s0,0.f) + fmaxf(s1,0.f);
      }
#pragma unroll
      for (int q=0;q<8;q++) ptc[q] = ecomb(ptc[q]);
      if ((e>>1)==cc){
        float v0 = (e&1) ? ptc[4] : ptc[0];
        float v1 = (e&1) ? ptc[5] : ptc[1];
        float v2 = (e&1) ? ptc[6] : ptc[2];
        float v3 = (e&1) ? ptc[7] : ptc[3];
        mf[e*4+0]=v0*s16; mf[e*4+1]=v1*s16;
        mf[e*4+2]=v2*s16; mf[e*4+3]=v3*s16;
      }
    }
  }
  __syncthreads();

  // pool1: outputs e*4 .. e*4+4 over 64 inputs (weights from LDS)
  const int o0 = e*4;
  float yac[4];
  {
    const float4 b0 = *(const float4*)(b_pool1 + o0);
    yac[0]=b0.x; yac[1]=b0.y; yac[2]=b0.z; yac[3]=b0.w;
  }
#pragma unroll 4
  for (int c=0;c<64;c++){
    const float mc = mf[c];
    const float4 w0 = *(const float4*)(wlds + c*32 + o0);
    yac[0]=fmaf(w0.x,mc,yac[0]); yac[1]=fmaf(w0.y,mc,yac[1]);
    yac[2]=fmaf(w0.z,mc,yac[2]); yac[3]=fmaf(w0.w,mc,yac[3]);
  }
  {
    __half2 h[2];
    h[0] = __floats2half2_rn(yac[0], yac[1]);
    h[1] = __floats2half2_rn(yac[2], yac[3]);
    *(uint2*)(Y1 + pb*32 + o0) = *(uint2*)h;
  }
#pragma unroll
  for (int q=0;q<4;q++){
    float s  = eredsum(yac[q]);
    float s2 = eredsum(yac[q]*yac[q]);
    if (lane < 8){ atomicAdd(&sl[o0+q], s); atomicAdd(&ql[o0+q], s2); }
  }
  __syncthreads();
  if (tid<32){ atomicAdd(&p1S[b*32+tid], sl[tid]); atomicAdd(&p1Q[b*32+tid], ql[tid]); }
}

// ---------------- K4: LSE2+pool2; fp16 gather + fused GN; LDS pool weights ----------
__global__ void __launch_bounds__(256,6) k4_lse2_pool2(
    const float* __restrict__ coords, const int* __restrict__ idx,
    const float* __restrict__ dist, const __half* __restrict__ Y1,
    const float* __restrict__ w2p, const float* __restrict__ wp2T,
    const float* __restrict__ b_pool2,
    const float* __restrict__ p1S, const float* __restrict__ p1Q,
    const float* __restrict__ g_p1, const float* __restrict__ bt_p1,
    float* __restrict__ Y2T, float* __restrict__ p2S, float* __restrict__ p2Q)
{
  __shared__ float mfl[32*66];
  __shared__ float wlds[64*64];
  __shared__ float sl[64], ql[64];
  __shared__ float al[32], dl[32];
  const int tid = threadIdx.x, lane = tid & 63;
  const int e = tid & 7;
  const int pl = tid >> 3;
  const int b = __builtin_amdgcn_readfirstlane((int)blockIdx.x & 1);
  if (tid < 64){ sl[tid]=0.f; ql[tid]=0.f; }
  if (tid >= 64 && tid < 96){
    const int c = tid - 64;
    float s = p1S[b*32+c], q = p1Q[b*32+c];
    s += __shfl_xor(s,1); q += __shfl_xor(q,1);
    const float inv = 1.f/(2.f*(float)NN);
    float mu = s*inv, e2 = q*inv, var = e2-mu*mu;
    float rstd = rsqrtf(var + GEPS);
    float a = g_p1[c]*rstd;
    al[c] = a; dl[c] = bt_p1[c] - mu*a;
  }
  for (int u=tid; u<4096; u+=256) wlds[u] = wp2T[u];
  __syncthreads();
  const int n0g = (((int)blockIdx.x >> 1) << 5);
  const int n = n0g + pl;
  const size_t pb = (size_t)b*NN + n;
  float* mf = &mfl[pl*66];
  const float s16 = 0.0625f;

  // Phase A: fp16 gather with fused pool1-GN+ReLU
  {
    const float a0g=al[e*4+0], a1g=al[e*4+1], a2g=al[e*4+2], a3g=al[e*4+3];
    const float d0g=dl[e*4+0], d1g=dl[e*4+1], d2g=dl[e*4+2], d3g=dl[e*4+3];
    int ja[16];
    const int4* ip = (const int4*)(idx + pb*16);
#pragma unroll
    for (int k4=0;k4<4;k4++){
      int4 j4 = ip[k4];
      ja[k4*4+0]=j4.x; ja[k4*4+1]=j4.y; ja[k4*4+2]=j4.z; ja[k4*4+3]=j4.w;
    }
    float af0=0.f, af1=0.f, af2=0.f, af3=0.f;
    const __half* yb = Y1 + (size_t)b*NN*32 + e*4;
#pragma unroll 4
    for (int k=0;k<16;k++){
      uint2 v = *(const uint2*)(yb + (size_t)ja[k]*32);
      __half2 h0 = *(__half2*)&v.x, h1 = *(__half2*)&v.y;
      float2 f0 = __half22float2(h0), f1 = __half22float2(h1);
      af0 += fmaxf(fmaf(f0.x, a0g, d0g), 0.f);
      af1 += fmaxf(fmaf(f0.y, a1g, d1g), 0.f);
      af2 += fmaxf(fmaf(f1.x, a2g, d2g), 0.f);
      af3 += fmaxf(fmaf(f1.y, a3g, d3g), 0.f);
    }
    mf[32+e*4+0]=af0*s16; mf[32+e*4+1]=af1*s16;
    mf[32+e*4+2]=af2*s16; mf[32+e*4+3]=af3*s16;
  }

  // Phase B: k-split enc
  {
    int2 j2 = *(const int2*)(idx + pb*16 + e*2);
    float2 d2 = *(const float2*)(dist + pb*16 + e*2);
    const float* nb0 = coords + ((size_t)b*NN + j2.x)*3;
    const float* nb1 = coords + ((size_t)b*NN + j2.y)*3;
    const float nx0=nb0[0], ny0=nb0[1], nz0=nb0[2];
    const float nx1=nb1[0], ny1=nb1[1], nz1=nb1[2];
    const float c0=coords[pb*3], c1=coords[pb*3+1], c2=coords[pb*3+2];
    const float* wrow = w2p + (size_t)(b*32)*12;
#pragma unroll 1
    for (int cc=0;cc<4;cc++){
      float ptc[8];
#pragma unroll
      for (int q=0;q<8;q++){
        const float4* r4 = (const float4*)(wrow + (cc*8+q)*12);
        float4 ra=r4[0], rb=r4[1], rc=r4[2];
        const float t0=ra.x+rb.z, t1=ra.y+rb.w, t2=ra.z+rc.x;
        const float u0=ra.w-rb.z, u1=rb.x-rb.w, u2=rb.y-rc.x;
        const float wd=rc.y;
        float cb = rc.z;
        cb = fmaf(t0,c0,cb); cb = fmaf(t1,c1,cb); cb = fmaf(t2,c2,cb);
        float s0 = cb, s1 = cb;
        s0 = fmaf(u0,nx0,s0); s0 = fmaf(u1,ny0,s0); s0 = fmaf(u2,nz0,s0);
        s0 = fmaf(wd,d2.x,s0);
        s1 = fmaf(u0,nx1,s1); s1 = fmaf(u1,ny1,s1); s1 = fmaf(u2,nz1,s1);
        s1 = fmaf(wd,d2.y,s1);
        ptc[q] = fmaxf(s0,0.f) + fmaxf(s1,0.f);
      }
#pragma unroll
      for (int q=0;q<8;q++) ptc[q] = ecomb(ptc[q]);
      if ((e>>1)==cc){
        float v0 = (e&1) ? ptc[4] : ptc[0];
        float v1 = (e&1) ? ptc[5] : ptc[1];
        float v2 = (e&1) ? ptc[6] : ptc[2];
        float v3 = (e&1) ? ptc[7] : ptc[3];
        mf[e*4+0]=v0*s16; mf[e*4+1]=v1*s16;
        mf[e*4+2]=v2*s16; mf[e*4+3]=v3*s16;
      }
    }
  }
  __syncthreads();

  // pool2: outputs e*8 .. e*8+8 over 64 inputs (weights from LDS)
  const int o0 = e*8;
  float yac[8];
  {
    const float4 b0 = *(const float4*)(b_pool2 + o0);
    const float4 b1 = *(const float4*)(b_pool2 + o0 + 4);
    yac[0]=b0.x; yac[1]=b0.y; yac[2]=b0.z; yac[3]=b0.w;
    yac[4]=b1.x; yac[5]=b1.y; yac[6]=b1.z; yac[7]=b1.w;
  }
#pragma unroll 4
  for (int c=0;c<64;c++){
    const float mc = mf[c];
    const float4 w0 = *(const float4*)(wlds + c*64 + o0);
    const float4 w1 = *(const float4*)(wlds + c*64 + o0 + 4);
    yac[0]=fmaf(w0.x,mc,yac[0]); yac[1]=fmaf(w0.y,mc,yac[1]);
    yac[2]=fmaf(w0.z,mc,yac[2]); yac[3]=fmaf(w0.w,mc,yac[3]);
    yac[4]=fmaf(w1.x,mc,yac[4]); yac[5]=fmaf(w1.y,mc,yac[5]);
    yac[6]=fmaf(w1.z,mc,yac[6]); yac[7]=fmaf(w1.w,mc,yac[7]);
  }
#pragma unroll
  for (int q=0;q<8;q++){
    float s  = eredsum(yac[q]);
    float s2 = eredsum(yac[q]*yac[q]);
    if (lane < 8){ atomicAdd(&sl[o0+q], s); atomicAdd(&ql[o0+q], s2); }
  }
  __syncthreads();
  float* ldsT = &mfl[0];
#pragma unroll
  for (int o=0;o<8;o++) ldsT[(o0+o)*33 + pl] = yac[o];
  __syncthreads();
#pragma unroll
  for (int r=0;r<8;r++){
    int u = tid + r*256;
    int ch = u >> 5, p = u & 31;
    Y2T[((size_t)(b*64+ch))*NN + n0g + p] = ldsT[ch*33 + p];
  }
  if (tid<64){ atomicAdd(&p2S[b*64+tid], sl[tid]); atomicAdd(&p2Q[b*64+tid], ql[tid]); }
}

// ---------------- F3a: per-batch GN affines (sc + pool2) ----------------------------
__global__ void f3a_affines(
    const float* __restrict__ scS, const float* __restrict__ scQ,
    const float* __restrict__ g_sc, const float* __restrict__ bt_sc,
    const float* __restrict__ b_sc, const float* __restrict__ b_mlp2,
    const float* __restrict__ p2S, const float* __restrict__ p2Q,
    const float* __restrict__ g_p2, const float* __restrict__ bt_p2,
    float* __restrict__ ascT, float* __restrict__ cstF,
    float* __restrict__ a2F, float* __restrict__ d2F)
{
  const int tid = threadIdx.x; // 384
  if (tid < 256){
    const int b = tid >> 7, c = tid & 127;
    float s = scS[b*128+c], q = scQ[b*128+c];
    s += __shfl_xor(s,1); q += __shfl_xor(q,1);
    s += __shfl_xor(s,2); q += __shfl_xor(q,2);
    s += __shfl_xor(s,4); q += __shfl_xor(q,4);
    const float inv = 1.f/(8.f*(float)NN);
    float mu = s*inv, e2 = q*inv, var = e2-mu*mu;
    float rstd = rsqrtf(var + GEPS);
    float a = g_sc[c]*rstd;
    ascT[tid] = a;
    cstF[tid] = b_mlp2[c] + a*b_sc[c] + (bt_sc[c] - mu*a);
  } else {
    const int t = tid - 256;
    const int b = t >> 6, c = t & 63;
    float s = p2S[b*64+c], q = p2Q[b*64+c];
    s += __shfl_xor(s,1); q += __shfl_xor(q,1);
    s += __shfl_xor(s,2); q += __shfl_xor(q,2);
    const float inv = 1.f/(4.f*(float)NN);
    float mu = s*inv, e2 = q*inv, var = e2-mu*mu;
    float rstd = rsqrtf(var + GEPS);
    float a = g_p2[c]*rstd;
    a2F[t] = a; d2F[t] = bt_p2[c] - mu*a;
  }
}

// ---------------- F3b: Wcomb[b] = [ w_mlp2^T (64x128) ; w_sc^T * asc[b] (72x128) ] --
__global__ void __launch_bounds__(256) f3b_wcomb(
    const float* __restrict__ w_mlp2, const float* __restrict__ w_sc,
    const float* __restrict__ ascT, float* __restrict__ Wcomb)
{
  const int t0 = blockIdx.x*256 + threadIdx.x;
  const int stride = gridDim.x*256;
  for (int u=t0; u<2*136*128; u+=stride){
    int bb = u / 17408;
    int rr = u - bb*17408;
    int i = rr >> 7, o = rr & 127;
    Wcomb[u] = (i < 64) ? w_mlp2[o*64+i]
                        : w_sc[o*72 + (i-64)] * ascT[bb*128+o];
  }
}

// ---------------- K6: outer-product reg tile; 64 pts x 128 ch; 4x8/thread ----------
__global__ void __launch_bounds__(256,4) k6_final(
    const float* __restrict__ feat, const float* __restrict__ Y2T,
    const float* __restrict__ Wcomb, const float* __restrict__ cstF,
    const float* __restrict__ a2F, const float* __restrict__ d2F,
    float* __restrict__ out)
{
  __shared__ float xl[34*64];
  __shared__ float wl[34*160];
  const int tid = threadIdx.x;
  const int tc = tid & 15;
  const int tp = tid >> 4;
  const int b  = __builtin_amdgcn_readfirstlane((int)blockIdx.x >> 9);
  const int n0 = ((int)blockIdx.x & 511) << 6;

  float acc[4][8];
#pragma unroll
  for (int q=0;q<8;q++){
    float bv = cstF[b*128 + tc*8 + q];
#pragma unroll
    for (int p=0;p<4;p++) acc[p][q] = bv;
  }

  const float* Wb = Wcomb + b*17408;
#pragma unroll 1
  for (int kk=0; kk<4; ++kk){
    __syncthreads();
    for (int u=tid; u<34*64; u+=256){
      int row = u>>6, j = u&63;
      int r = kk*34 + row;
      float v;
      if (r < 64){
        float y = Y2T[(size_t)(b*64+r)*NN + n0 + j];
        v = fmaxf(fmaf(y, a2F[b*64+r], d2F[b*64+r]), 0.f);
      } else {
        v = feat[(size_t)(b*72 + (r-64))*NN + n0 + j];
      }
      xl[u] = v;
    }
    for (int u=tid; u<34*128; u+=256){
      int row = u>>7, c = u&127;
      wl[row*160 + (c>>3)*10 + (c&7)] = Wb[(size_t)(kk*34+row)*128 + c];
    }
    __syncthreads();

#pragma unroll 2
    for (int i=0;i<34;i++){
      const float4 xa = *(const float4*)&xl[i*64 + tp*4];
      const float4 wa = *(const float4*)&wl[i*160 + tc*10];
      const float4 wb = *(const float4*)&wl[i*160 + tc*10 + 4];
      const float xs[4] = {xa.x,xa.y,xa.z,xa.w};
      const float wv[8] = {wa.x,wa.y,wa.z,wa.w,wb.x,wb.y,wb.z,wb.w};
#pragma unroll
      for (int p=0;p<4;p++)
#pragma unroll
        for (int q=0;q<8;q++)
          acc[p][q] = fmaf(wv[q], xs[p], acc[p][q]);
    }
  }

#pragma unroll
  for (int q=0;q<8;q++){
    const int ch = b*128 + tc*8 + q;
    float4 r0;
    float v;
    v = acc[0][q]; r0.x = v>0.f? v : 0.01f*v;
    v = acc[1][q]; r0.y = v>0.f? v : 0.01f*v;
    v = acc[2][q]; r0.z = v>0.f? v : 0.01f*v;
    v = acc[3][q]; r0.w = v>0.f? v : 0.01f*v;
    *(float4*)(out + (size_t)ch*NN + n0 + tp*4) = r0;
  }
}

extern "C" void kernel_launch(void* const* d_in, const int* in_sizes, int n_in,
                              void* d_out, int out_size, void* d_ws, size_t ws_size,
                              hipStream_t stream) {
  (void)in_sizes; (void)n_in; (void)out_size; (void)ws_size;
  const float* coords  = (const float*)d_in[0];
  const float* feats   = (const float*)d_in[1];
  const int*   idx     = (const int*)  d_in[2];
  const float* dist    = (const float*)d_in[3];
  const float* w_mlp1  = (const float*)d_in[4];
  const float* b_mlp1  = (const float*)d_in[5];
  const float* w_lse1  = (const float*)d_in[6];
  const float* b_lse1  = (const float*)d_in[7];
  const float* g_lse1  = (const float*)d_in[8];
  const float* bt_lse1 = (const float*)d_in[9];
  const float* w_pool1 = (const float*)d_in[10];
  const float* b_pool1 = (const float*)d_in[11];
  const float* g_pool1 = (const float*)d_in[12];
  const float* bt_pool1= (const float*)d_in[13];
  const float* w_lse2  = (const float*)d_in[14];
  const float* b_lse2  = (const float*)d_in[15];
  const float* g_lse2  = (const float*)d_in[16];
  const float* bt_lse2 = (const float*)d_in[17];
  const float* w_pool2 = (const float*)d_in[18];
  const float* b_pool2 = (const float*)d_in[19];
  const float* g_pool2 = (const float*)d_in[20];
  const float* bt_pool2= (const float*)d_in[21];
  const float* w_mlp2  = (const float*)d_in[22];
  const float* b_mlp2  = (const float*)d_in[23];
  const float* w_sc    = (const float*)d_in[24];
  const float* b_sc    = (const float*)d_in[25];
  const float* g_sc    = (const float*)d_in[26];
  const float* bt_sc   = (const float*)d_in[27];

  float* ws   = (float*)d_ws;
  float* scS  = ws;            // 256
  float* scQ  = ws + 256;      // 256
  float* vm   = ws + 512;      // 130
  float* p1S  = ws + 704;      // 64
  float* p1Q  = ws + 768;      // 64
  float* p2S  = ws + 832;      // 128
  float* p2Q  = ws + 960;      // 128
  float* w1p  = ws + 1280;     // 768
  float* w2p  = ws + 2048;     // 768
  float* wp1T = ws + 2816;     // 2048
  float* wp2T = ws + 4864;     // 4096 -> 8960
  float* ball = ws + 8960;     // 160 -> 9120
  float* cstF = ws + 9120;     // 256 -> 9376
  float* a2F  = ws + 9376;     // 128 -> 9504
  float* d2F  = ws + 9504;     // 128 -> 9632
  float* ascT = ws + 9632;     // 256 -> 9888
  float* WallT= ws + 9984;     // 11520 -> 21504
  float* Wcomb= ws + 21504;    // 34816 -> 56320
  __half* X1  = (__half*)(ws + 57344);            // 2*NN*32 halves (fits in 1M floats)
  __half* Y1  = (__half*)(ws + 57344 + (size_t)NN*32);   // next half-region
  float* Y2T  = ws + 57344 + (size_t)2*NN*32;     // fp32 region after both half arrays

  hipMemsetAsync(d_ws, 0, 1088*sizeof(float), stream);

  f0_prep<<<32,256,0,stream>>>(w_mlp1,b_mlp1,w_sc,b_sc,w_pool1,w_pool2,
                               WallT,ball,wp1T,wp2T);
  k0_mlp1_scstats<<<512,256,0,stream>>>(feats, WallT, ball, X1, scS, scQ);
  k1_vmom<<<1024,256,0,stream>>>(coords, idx, dist, vm);
  f1_fold<<<1,128,0,stream>>>(w_lse1,b_lse1,g_lse1,bt_lse1,
                              w_lse2,b_lse2,g_lse2,bt_lse2,
                              vm, w1p, w2p);
  k2_lse1_pool1<<<2048,256,0,stream>>>(coords, idx, dist, X1, w1p, wp1T, b_pool1,
                                       Y1, p1S, p1Q);
  k4_lse2_pool2<<<2048,256,0,stream>>>(coords, idx, dist, Y1, w2p, wp2T, b_pool2,
                                       p1S, p1Q, g_pool1, bt_pool1,
                                       Y2T, p2S, p2Q);
  f3a_affines<<<1,384,0,stream>>>(scS,scQ,g_sc,bt_sc,b_sc,b_mlp2,
                                  p2S,p2Q,g_pool2,bt_pool2, ascT,cstF,a2F,d2F);
  f3b_wcomb<<<64,256,0,stream>>>(w_mlp2, w_sc, ascT, Wcomb);
  k6_final<<<1024,256,0,stream>>>(feats, Y2T, Wcomb, cstF, a2F, d2F, (float*)d_out);
}

// Round 20
// 235.430 us; speedup vs baseline: 1.0578x; 1.0031x over previous
//
#include <hip/hip_runtime.h>
#include <hip/hip_fp16.h>

#define NN 32768
#define GEPS 1e-6f

__device__ __forceinline__ float wredsum(float v){
  v += __shfl_xor(v, 32); v += __shfl_xor(v, 16); v += __shfl_xor(v, 8);
  v += __shfl_xor(v, 4);  v += __shfl_xor(v, 2);  v += __shfl_xor(v, 1);
  return v;
}
__device__ __forceinline__ float eredsum(float v){
  v += __shfl_xor(v, 8); v += __shfl_xor(v, 16); v += __shfl_xor(v, 32);
  return v;
}
__device__ __forceinline__ float ecomb(float v){
  v += __shfl_xor(v, 1); v += __shfl_xor(v, 2); v += __shfl_xor(v, 4);
  return v;
}
// sum across 32 lanes of a half-wave (masks < 32 stay within the half)
__device__ __forceinline__ float hredsum(float v){
  v += __shfl_xor(v, 16); v += __shfl_xor(v, 8);
  v += __shfl_xor(v, 4);  v += __shfl_xor(v, 2);  v += __shfl_xor(v, 1);
  return v;
}

// ---------------- F0: weight transposes / concats ----------------------------------
__global__ void __launch_bounds__(256) f0_prep(
    const float* __restrict__ w_mlp1, const float* __restrict__ b_mlp1,
    const float* __restrict__ w_sc,   const float* __restrict__ b_sc,
    const float* __restrict__ w_pool1,const float* __restrict__ w_pool2,
    float* __restrict__ WallT, float* __restrict__ ball,
    float* __restrict__ wp1T,  float* __restrict__ wp2T)
{
  const int t0 = blockIdx.x*256 + threadIdx.x;
  const int stride = gridDim.x*256;
  for (int u=t0; u<72*160; u+=stride){
    int i = u/160, o = u - i*160;
    WallT[u] = (o < 128) ? w_sc[o*72+i] : w_mlp1[(o-128)*72+i];
  }
  for (int u=t0; u<160; u+=stride)
    ball[u] = (u < 128) ? b_sc[u] : b_mlp1[u-128];
  for (int u=t0; u<64*32; u+=stride){ int c=u>>5, o=u&31; wp1T[u] = w_pool1[o*64+c]; }
  for (int u=t0; u<64*64; u+=stride){ int c=u>>6, o=u&63; wp2T[u] = w_pool2[o*64+c]; }
}

// ---------------- K0: 64 pts/block; fp16 x in LDS; 3 passes {64,64,32} ch ----------
// grid [b:2][tile:512] = 1024; thread (p2 = tid&31: pt pair, g8 = tid>>5: 8-ch group)
__global__ void __launch_bounds__(256,4) k0_mlp1_scstats(
    const float* __restrict__ feat, const float* __restrict__ WallT,
    const float* __restrict__ ball,
    __half* __restrict__ X1, float* __restrict__ scS, float* __restrict__ scQ)
{
  __shared__ __half2 xl2[72*32];     // 9216 B
  __shared__ float wl[72*64];        // 18432 B
  __shared__ float ssl[128], sql[128];
  const int tid = threadIdx.x;
  const int p2 = tid & 31;
  const int g8 = tid >> 5;           // NOT wave-uniform: must stay per-lane
  const int b  = __builtin_amdgcn_readfirstlane((int)blockIdx.x >> 9);
  const int n0 = ((int)blockIdx.x & 511) << 6;

  // stage x as fp16 pairs
  for (int u=tid; u<72*32; u+=256){
    int i = u>>5, pp = u&31;
    float2 f = *(const float2*)(feat + (size_t)(b*72+i)*NN + n0 + pp*2);
    xl2[u] = __floats2half2_rn(f.x, f.y);
  }

#pragma unroll 1
  for (int pass=0; pass<3; ++pass){
    const int cb  = pass*64;
    __syncthreads();                           // xl ready / wl safe
    if (pass==2){
      for (int u=tid; u<72*32; u+=256){
        int i = u>>5, c = u&31;
        wl[i*64 + c] = WallT[i*160 + 128 + c];
      }
    } else {
      for (int u=tid; u<72*64; u+=256){
        int i = u>>6, c = u&63;
        wl[i*64 + c] = WallT[i*160 + cb + c];
      }
    }
    __syncthreads();

    if (pass==2 && g8 >= 4){ continue; }       // only 32 mlp1 channels

    const int oc = g8*8;
    float a0[8], a1[8];
#pragma unroll
    for (int q=0;q<8;q++){
      float bv = ball[cb + oc + q];
      a0[q]=bv; a1[q]=bv;
    }

    const float* wbase = wl + oc;
#pragma unroll
    for (int i=0;i<72;i++){
      const float2 x2 = __half22float2(xl2[i*32 + p2]);
      const float4 w0 = *(const float4*)(wbase + i*64);
      const float4 w1 = *(const float4*)(wbase + i*64 + 4);
      a0[0]=fmaf(w0.x,x2.x,a0[0]); a1[0]=fmaf(w0.x,x2.y,a1[0]);
      a0[1]=fmaf(w0.y,x2.x,a0[1]); a1[1]=fmaf(w0.y,x2.y,a1[1]);
      a0[2]=fmaf(w0.z,x2.x,a0[2]); a1[2]=fmaf(w0.z,x2.y,a1[2]);
      a0[3]=fmaf(w0.w,x2.x,a0[3]); a1[3]=fmaf(w0.w,x2.y,a1[3]);
      a0[4]=fmaf(w1.x,x2.x,a0[4]); a1[4]=fmaf(w1.x,x2.y,a1[4]);
      a0[5]=fmaf(w1.y,x2.x,a0[5]); a1[5]=fmaf(w1.y,x2.y,a1[5]);
      a0[6]=fmaf(w1.z,x2.x,a0[6]); a1[6]=fmaf(w1.z,x2.y,a1[6]);
      a0[7]=fmaf(w1.w,x2.x,a0[7]); a1[7]=fmaf(w1.w,x2.y,a1[7]);
    }

    if (pass < 2){
#pragma unroll
      for (int q=0;q<8;q++){
        float s  = hredsum(a0[q]+a1[q]);
        float s2 = hredsum(a0[q]*a0[q] + a1[q]*a1[q]);
        if (p2==0){ ssl[cb+oc+q] = s; sql[cb+oc+q] = s2; }
      }
    } else {
      __half2 h0[4], h1[4];
#pragma unroll
      for (int q=0;q<4;q++){
        float v00 = a0[q*2],   v01 = a0[q*2+1];
        float v10 = a1[q*2],   v11 = a1[q*2+1];
        v00 = v00>0.f? v00 : 0.2f*v00;  v01 = v01>0.f? v01 : 0.2f*v01;
        v10 = v10>0.f? v10 : 0.2f*v10;  v11 = v11>0.f? v11 : 0.2f*v11;
        h0[q] = __floats2half2_rn(v00, v01);
        h1[q] = __floats2half2_rn(v10, v11);
      }
      __half* xb = X1 + ((size_t)b*NN + n0 + p2*2)*32 + g8*8;
      *(uint4*)(xb)      = *(uint4*)h0;
      *(uint4*)(xb + 32) = *(uint4*)h1;
    }
  }

  __syncthreads();
  if (tid < 128){
    atomicAdd(&scS[b*128+tid], ssl[tid]);
    atomicAdd(&scQ[b*128+tid], sql[tid]);
  }
}

// ---------------- K1: v10 moments, 4 threads per point (k-quarters) -----------------
__global__ void __launch_bounds__(256) k1_vmom(
    const float* __restrict__ coords, const int* __restrict__ idx,
    const float* __restrict__ dist, float* __restrict__ vm)
{
  __shared__ float red[4*65];
  const int tid = threadIdx.x, lane = tid & 63, wid = tid >> 6;
  const int gn = blockIdx.x*256 + tid;
  const int pt = gn >> 2, h = gn & 3;
  const int b = pt >> 15, n = pt & (NN-1);
  const size_t pb = (size_t)b*NN + n;
  const float c0 = coords[pb*3+0], c1 = coords[pb*3+1], c2 = coords[pb*3+2];

  int ja[4]; float da[4];
  {
    int4 j4 = *(const int4*)(idx + pb*16 + h*4);
    float4 d4 = *(const float4*)(dist + pb*16 + h*4);
    ja[0]=j4.x; ja[1]=j4.y; ja[2]=j4.z; ja[3]=j4.w;
    da[0]=d4.x; da[1]=d4.y; da[2]=d4.z; da[3]=d4.w;
  }

  float aS[10], aM[55];
#pragma unroll
  for (int i=0;i<10;i++) aS[i]=0.f;
#pragma unroll
  for (int i=0;i<55;i++) aM[i]=0.f;

#pragma unroll
  for (int k=0;k<4;k++){
    const float* nb = coords + ((size_t)b*NN + ja[k])*3;
    const float n0v=nb[0], n1v=nb[1], n2v=nb[2];
    const float v[10] = {c0,c1,c2,n0v,n1v,n2v,c0-n0v,c1-n1v,c2-n2v,da[k]};
#pragma unroll
    for (int i=0;i<10;i++){
      aS[i] += v[i];
#pragma unroll
      for (int j=i;j<10;j++)
        aM[i*10 - (i*(i-1))/2 + (j-i)] += v[i]*v[j];
    }
  }

#pragma unroll
  for (int i=0;i<10;i++){ float s = wredsum(aS[i]); if (lane==0) red[wid*65+i] = s; }
#pragma unroll
  for (int i=0;i<55;i++){ float s = wredsum(aM[i]); if (lane==0) red[wid*65+10+i] = s; }
  __syncthreads();
  if (tid < 65){
    float s = red[tid] + red[65+tid] + red[130+tid] + red[195+tid];
    const int bb = blockIdx.x >> 9;
    atomicAdd(&vm[bb*65+tid], s);
  }
}

// ---------------- F1: fold GN into LSE conv weights --------------------------------
__global__ void f1_fold(
    const float* __restrict__ w_lse1, const float* __restrict__ b_lse1,
    const float* __restrict__ g_lse1, const float* __restrict__ bt_lse1,
    const float* __restrict__ w_lse2, const float* __restrict__ b_lse2,
    const float* __restrict__ g_lse2, const float* __restrict__ bt_lse2,
    const float* __restrict__ vm,
    float* __restrict__ w1p, float* __restrict__ w2p)
{
  const int tid = threadIdx.x; // 128
  const int half = tid >> 6;
  const int u = tid & 63, b = u >> 5, c = u & 31;
  const float* W  = half ? w_lse2  : w_lse1;
  const float* Bv = half ? b_lse2  : b_lse1;
  const float* G  = half ? g_lse2  : g_lse1;
  const float* Bt = half ? bt_lse2 : bt_lse1;
  float wr[10];
#pragma unroll
  for (int i=0;i<10;i++) wr[i] = W[c*10+i];
  const float* S = vm + b*65;
  const float* M = vm + b*65 + 10;
  float P = 0.f;
#pragma unroll
  for (int i=0;i<10;i++) P = fmaf(wr[i], S[i], P);
  float Q = 0.f;
#pragma unroll
  for (int i=0;i<10;i++){
#pragma unroll
    for (int j=i;j<10;j++){
      float m = M[i*10 - (i*(i-1))/2 + (j-i)];
      float t = wr[i]*wr[j]*m;
      Q += (i==j) ? t : 2.f*t;
    }
  }
  const float invNK = 1.f/((float)NN*16.f);
  const float bc = Bv[c];
  float mean = P*invNK + bc;
  float ey2  = (Q + 2.f*bc*P)*invNK + bc*bc;
  float mu = 0.5f*(mean + __shfl_xor(mean,1));
  float e2 = 0.5f*(ey2  + __shfl_xor(ey2, 1));
  float var = e2 - mu*mu;
  float rstd = rsqrtf(var + GEPS);
  float a = G[c]*rstd, d = Bt[c] - mu*a;
  float* out = (half ? w2p : w1p) + (b*32+c)*12;
#pragma unroll
  for (int i=0;i<10;i++) out[i] = wr[i]*a;
  out[10] = bc*a + d;
  out[11] = 0.f;
}

// ---------------- K2: LSE1+pool1; fp16 gather; LDS pool weights --------------------
__global__ void __launch_bounds__(256,6) k2_lse1_pool1(
    const float* __restrict__ coords, const int* __restrict__ idx,
    const float* __restrict__ dist, const __half* __restrict__ X1,
    const float* __restrict__ w1p, const float* __restrict__ wp1T,
    const float* __restrict__ b_pool1,
    __half* __restrict__ Y1, float* __restrict__ p1S, float* __restrict__ p1Q)
{
  __shared__ float mfl[32*66];
  __shared__ float wlds[64*32];
  __shared__ float sl[32], ql[32];
  const int tid = threadIdx.x, lane = tid & 63;
  const int e = tid & 7;
  const int pl = tid >> 3;
  if (tid < 32){ sl[tid]=0.f; ql[tid]=0.f; }
  for (int u=tid; u<2048; u+=256) wlds[u] = wp1T[u];
  __syncthreads();
  const int b = __builtin_amdgcn_readfirstlane((int)blockIdx.x & 1);
  const int n = (((int)blockIdx.x >> 1) << 5) + pl;
  const size_t pb = (size_t)b*NN + n;
  float* mf = &mfl[pl*66];
  const float s16 = 0.0625f;

  // Phase A: ch-split gather (fp16)
  {
    int ja[16];
    const int4* ip = (const int4*)(idx + pb*16);
#pragma unroll
    for (int k4=0;k4<4;k4++){
      int4 j4 = ip[k4];
      ja[k4*4+0]=j4.x; ja[k4*4+1]=j4.y; ja[k4*4+2]=j4.z; ja[k4*4+3]=j4.w;
    }
    float af0=0.f, af1=0.f, af2=0.f, af3=0.f;
    const __half* xb = X1 + (size_t)b*NN*32 + e*4;
#pragma unroll 4
    for (int k=0;k<16;k++){
      uint2 v = *(const uint2*)(xb + (size_t)ja[k]*32);
      __half2 h0 = *(__half2*)&v.x, h1 = *(__half2*)&v.y;
      float2 f0 = __half22float2(h0), f1 = __half22float2(h1);
      af0+=f0.x; af1+=f0.y; af2+=f1.x; af3+=f1.y;
    }
    mf[32+e*4+0]=af0*s16; mf[32+e*4+1]=af1*s16;
    mf[32+e*4+2]=af2*s16; mf[32+e*4+3]=af3*s16;
  }

  // Phase B: k-split enc
  {
    int2 j2 = *(const int2*)(idx + pb*16 + e*2);
    float2 d2 = *(const float2*)(dist + pb*16 + e*2);
    const float* nb0 = coords + ((size_t)b*NN + j2.x)*3;
    const float* nb1 = coords + ((size_t)b*NN + j2.y)*3;
    const float nx0=nb0[0], ny0=nb0[1], nz0=nb0[2];
    const float nx1=nb1[0], ny1=nb1[1], nz1=nb1[2];
    const float c0=coords[pb*3], c1=coords[pb*3+1], c2=coords[pb*3+2];
    const float* wrow = w1p + (size_t)(b*32)*12;
#pragma unroll 1
    for (int cc=0;cc<4;cc++){
      float ptc[8];
#pragma unroll
      for (int q=0;q<8;q++){
        const float4* r4 = (const float4*)(wrow + (cc*8+q)*12);
        float4 ra=r4[0], rb=r4[1], rc=r4[2];
        const float t0=ra.x+rb.z, t1=ra.y+rb.w, t2=ra.z+rc.x;
        const float u0=ra.w-rb.z, u1=rb.x-rb.w, u2=rb.y-rc.x;
        const float wd=rc.y;
        float cb = rc.z;
        cb = fmaf(t0,c0,cb); cb = fmaf(t1,c1,cb); cb = fmaf(t2,c2,cb);
        float s0 = cb, s1 = cb;
        s0 = fmaf(u0,nx0,s0); s0 = fmaf(u1,ny0,s0); s0 = fmaf(u2,nz0,s0);
        s0 = fmaf(wd,d2.x,s0);
        s1 = fmaf(u0,nx1,s1); s1 = fmaf(u1,ny1,s1); s1 = fmaf(u2,nz1,s1);
        s1 = fmaf(wd,d2.y,s1);
        ptc[q] = fmaxf(s0,0.f) + fmaxf(s1,0.f);
      }
#pragma unroll
      for (int q=0;q<8;q++) ptc[q] = ecomb(ptc[q]);
      if ((e>>1)==cc){
        float v0 = (e&1) ? ptc[4] : ptc[0];
        float v1 = (e&1) ? ptc[5] : ptc[1];
        float v2 = (e&1) ? ptc[6] : ptc[2];
        float v3 = (e&1) ? ptc[7] : ptc[3];
        mf[e*4+0]=v0*s16; mf[e*4+1]=v1*s16;
        mf[e*4+2]=v2*s16; mf[e*4+3]=v3*s16;
      }
    }
  }
  __syncthreads();

  // pool1: outputs e*4 .. e*4+4 over 64 inputs (weights from LDS)
  const int o0 = e*4;
  float yac[4];
  {
    const float4 b0 = *(const float4*)(b_pool1 + o0);
    yac[0]=b0.x; yac[1]=b0.y; yac[2]=b0.z; yac[3]=b0.w;
  }
#pragma unroll 4
  for (int c=0;c<64;c++){
    const float mc = mf[c];
    const float4 w0 = *(const float4*)(wlds + c*32 + o0);
    yac[0]=fmaf(w0.x,mc,yac[0]); yac[1]=fmaf(w0.y,mc,yac[1]);
    yac[2]=fmaf(w0.z,mc,yac[2]); yac[3]=fmaf(w0.w,mc,yac[3]);
  }
  {
    __half2 h[2];
    h[0] = __floats2half2_rn(yac[0], yac[1]);
    h[1] = __floats2half2_rn(yac[2], yac[3]);
    *(uint2*)(Y1 + pb*32 + o0) = *(uint2*)h;
  }
#pragma unroll
  for (int q=0;q<4;q++){
    float s  = eredsum(yac[q]);
    float s2 = eredsum(yac[q]*yac[q]);
    if (lane < 8){ atomicAdd(&sl[o0+q], s); atomicAdd(&ql[o0+q], s2); }
  }
  __syncthreads();
  if (tid<32){ atomicAdd(&p1S[b*32+tid], sl[tid]); atomicAdd(&p1Q[b*32+tid], ql[tid]); }
}

// ---------------- K4: LSE2+pool2; fp16 gather + fused GN; LDS pool weights ----------
__global__ void __launch_bounds__(256,6) k4_lse2_pool2(
    const float* __restrict__ coords, const int* __restrict__ idx,
    const float* __restrict__ dist, const __half* __restrict__ Y1,
    const float* __restrict__ w2p, const float* __restrict__ wp2T,
    const float* __restrict__ b_pool2,
    const float* __restrict__ p1S, const float* __restrict__ p1Q,
    const float* __restrict__ g_p1, const float* __restrict__ bt_p1,
    float* __restrict__ Y2T, float* __restrict__ p2S, float* __restrict__ p2Q)
{
  __shared__ float mfl[32*66];
  __shared__ float wlds[64*64];
  __shared__ float sl[64], ql[64];
  __shared__ float al[32], dl[32];
  const int tid = threadIdx.x, lane = tid & 63;
  const int e = tid & 7;
  const int pl = tid >> 3;
  const int b = __builtin_amdgcn_readfirstlane((int)blockIdx.x & 1);
  if (tid < 64){ sl[tid]=0.f; ql[tid]=0.f; }
  if (tid >= 64 && tid < 96){
    const int c = tid - 64;
    float s = p1S[b*32+c], q = p1Q[b*32+c];
    s += __shfl_xor(s,1); q += __shfl_xor(q,1);
    const float inv = 1.f/(2.f*(float)NN);
    float mu = s*inv, e2 = q*inv, var = e2-mu*mu;
    float rstd = rsqrtf(var + GEPS);
    float a = g_p1[c]*rstd;
    al[c] = a; dl[c] = bt_p1[c] - mu*a;
  }
  for (int u=tid; u<4096; u+=256) wlds[u] = wp2T[u];
  __syncthreads();
  const int n0g = (((int)blockIdx.x >> 1) << 5);
  const int n = n0g + pl;
  const size_t pb = (size_t)b*NN + n;
  float* mf = &mfl[pl*66];
  const float s16 = 0.0625f;

  // Phase A: fp16 gather with fused pool1-GN+ReLU
  {
    const float a0g=al[e*4+0], a1g=al[e*4+1], a2g=al[e*4+2], a3g=al[e*4+3];
    const float d0g=dl[e*4+0], d1g=dl[e*4+1], d2g=dl[e*4+2], d3g=dl[e*4+3];
    int ja[16];
    const int4* ip = (const int4*)(idx + pb*16);
#pragma unroll
    for (int k4=0;k4<4;k4++){
      int4 j4 = ip[k4];
      ja[k4*4+0]=j4.x; ja[k4*4+1]=j4.y; ja[k4*4+2]=j4.z; ja[k4*4+3]=j4.w;
    }
    float af0=0.f, af1=0.f, af2=0.f, af3=0.f;
    const __half* yb = Y1 + (size_t)b*NN*32 + e*4;
#pragma unroll 4
    for (int k=0;k<16;k++){
      uint2 v = *(const uint2*)(yb + (size_t)ja[k]*32);
      __half2 h0 = *(__half2*)&v.x, h1 = *(__half2*)&v.y;
      float2 f0 = __half22float2(h0), f1 = __half22float2(h1);
      af0 += fmaxf(fmaf(f0.x, a0g, d0g), 0.f);
      af1 += fmaxf(fmaf(f0.y, a1g, d1g), 0.f);
      af2 += fmaxf(fmaf(f1.x, a2g, d2g), 0.f);
      af3 += fmaxf(fmaf(f1.y, a3g, d3g), 0.f);
    }
    mf[32+e*4+0]=af0*s16; mf[32+e*4+1]=af1*s16;
    mf[32+e*4+2]=af2*s16; mf[32+e*4+3]=af3*s16;
  }

  // Phase B: k-split enc
  {
    int2 j2 = *(const int2*)(idx + pb*16 + e*2);
    float2 d2 = *(const float2*)(dist + pb*16 + e*2);
    const float* nb0 = coords + ((size_t)b*NN + j2.x)*3;
    const float* nb1 = coords + ((size_t)b*NN + j2.y)*3;
    const float nx0=nb0[0], ny0=nb0[1], nz0=nb0[2];
    const float nx1=nb1[0], ny1=nb1[1], nz1=nb1[2];
    const float c0=coords[pb*3], c1=coords[pb*3+1], c2=coords[pb*3+2];
    const float* wrow = w2p + (size_t)(b*32)*12;
#pragma unroll 1
    for (int cc=0;cc<4;cc++){
      float ptc[8];
#pragma unroll
      for (int q=0;q<8;q++){
        const float4* r4 = (const float4*)(wrow + (cc*8+q)*12);
        float4 ra=r4[0], rb=r4[1], rc=r4[2];
        const float t0=ra.x+rb.z, t1=ra.y+rb.w, t2=ra.z+rc.x;
        const float u0=ra.w-rb.z, u1=rb.x-rb.w, u2=rb.y-rc.x;
        const float wd=rc.y;
        float cb = rc.z;
        cb = fmaf(t0,c0,cb); cb = fmaf(t1,c1,cb); cb = fmaf(t2,c2,cb);
        float s0 = cb, s1 = cb;
        s0 = fmaf(u0,nx0,s0); s0 = fmaf(u1,ny0,s0); s0 = fmaf(u2,nz0,s0);
        s0 = fmaf(wd,d2.x,s0);
        s1 = fmaf(u0,nx1,s1); s1 = fmaf(u1,ny1,s1); s1 = fmaf(u2,nz1,s1);
        s1 = fmaf(wd,d2.y,s1);
        ptc[q] = fmaxf(s0,0.f) + fmaxf(s1,0.f);
      }
#pragma unroll
      for (int q=0;q<8;q++) ptc[q] = ecomb(ptc[q]);
      if ((e>>1)==cc){
        float v0 = (e&1) ? ptc[4] : ptc[0];
        float v1 = (e&1) ? ptc[5] : ptc[1];
        float v2 = (e&1) ? ptc[6] : ptc[2];
        float v3 = (e&1) ? ptc[7] : ptc[3];
        mf[e*4+0]=v0*s16; mf[e*4+1]=v1*s16;
        mf[e*4+2]=v2*s16; mf[e*4+3]=v3*s16;
      }
    }
  }
  __syncthreads();

  // pool2: outputs e*8 .. e*8+8 over 64 inputs (weights from LDS)
  const int o0 = e*8;
  float yac[8];
  {
    const float4 b0 = *(const float4*)(b_pool2 + o0);
    const float4 b1 = *(const float4*)(b_pool2 + o0 + 4);
    yac[0]=b0.x; yac[1]=b0.y; yac[2]=b0.z; yac[3]=b0.w;
    yac[4]=b1.x; yac[5]=b1.y; yac[6]=b1.z; yac[7]=b1.w;
  }
#pragma unroll 4
  for (int c=0;c<64;c++){
    const float mc = mf[c];
    const float4 w0 = *(const float4*)(wlds + c*64 + o0);
    const float4 w1 = *(const float4*)(wlds + c*64 + o0 + 4);
    yac[0]=fmaf(w0.x,mc,yac[0]); yac[1]=fmaf(w0.y,mc,yac[1]);
    yac[2]=fmaf(w0.z,mc,yac[2]); yac[3]=fmaf(w0.w,mc,yac[3]);
    yac[4]=fmaf(w1.x,mc,yac[4]); yac[5]=fmaf(w1.y,mc,yac[5]);
    yac[6]=fmaf(w1.z,mc,yac[6]); yac[7]=fmaf(w1.w,mc,yac[7]);
  }
#pragma unroll
  for (int q=0;q<8;q++){
    float s  = eredsum(yac[q]);
    float s2 = eredsum(yac[q]*yac[q]);
    if (lane < 8){ atomicAdd(&sl[o0+q], s); atomicAdd(&ql[o0+q], s2); }
  }
  __syncthreads();
  float* ldsT = &mfl[0];
#pragma unroll
  for (int o=0;o<8;o++) ldsT[(o0+o)*33 + pl] = yac[o];
  __syncthreads();
#pragma unroll
  for (int r=0;r<8;r++){
    int u = tid + r*256;
    int ch = u >> 5, p = u & 31;
    Y2T[((size_t)(b*64+ch))*NN + n0g + p] = ldsT[ch*33 + p];
  }
  if (tid<64){ atomicAdd(&p2S[b*64+tid], sl[tid]); atomicAdd(&p2Q[b*64+tid], ql[tid]); }
}

// ---------------- F3a: per-batch GN affines (sc + pool2) ----------------------------
__global__ void f3a_affines(
    const float* __restrict__ scS, const float* __restrict__ scQ,
    const float* __restrict__ g_sc, const float* __restrict__ bt_sc,
    const float* __restrict__ b_sc, const float* __restrict__ b_mlp2,
    const float* __restrict__ p2S, const float* __restrict__ p2Q,
    const float* __restrict__ g_p2, const float* __restrict__ bt_p2,
    float* __restrict__ ascT, float* __restrict__ cstF,
    float* __restrict__ a2F, float* __restrict__ d2F)
{
  const int tid = threadIdx.x; // 384
  if (tid < 256){
    const int b = tid >> 7, c = tid & 127;
    float s = scS[b*128+c], q = scQ[b*128+c];
    s += __shfl_xor(s,1); q += __shfl_xor(q,1);
    s += __shfl_xor(s,2); q += __shfl_xor(q,2);
    s += __shfl_xor(s,4); q += __shfl_xor(q,4);
    const float inv = 1.f/(8.f*(float)NN);
    float mu = s*inv, e2 = q*inv, var = e2-mu*mu;
    float rstd = rsqrtf(var + GEPS);
    float a = g_sc[c]*rstd;
    ascT[tid] = a;
    cstF[tid] = b_mlp2[c] + a*b_sc[c] + (bt_sc[c] - mu*a);
  } else {
    const int t = tid - 256;
    const int b = t >> 6, c = t & 63;
    float s = p2S[b*64+c], q = p2Q[b*64+c];
    s += __shfl_xor(s,1); q += __shfl_xor(q,1);
    s += __shfl_xor(s,2); q += __shfl_xor(q,2);
    const float inv = 1.f/(4.f*(float)NN);
    float mu = s*inv, e2 = q*inv, var = e2-mu*mu;
    float rstd = rsqrtf(var + GEPS);
    float a = g_p2[c]*rstd;
    a2F[t] = a; d2F[t] = bt_p2[c] - mu*a;
  }
}

// ---------------- F3b: Wcomb[b] = [ w_mlp2^T (64x128) ; w_sc^T * asc[b] (72x128) ] --
__global__ void __launch_bounds__(256) f3b_wcomb(
    const float* __restrict__ w_mlp2, const float* __restrict__ w_sc,
    const float* __restrict__ ascT, float* __restrict__ Wcomb)
{
  const int t0 = blockIdx.x*256 + threadIdx.x;
  const int stride = gridDim.x*256;
  for (int u=t0; u<2*136*128; u+=stride){
    int bb = u / 17408;
    int rr = u - bb*17408;
    int i = rr >> 7, o = rr & 127;
    Wcomb[u] = (i < 64) ? w_mlp2[o*64+i]
                        : w_sc[o*72 + (i-64)] * ascT[bb*128+o];
  }
}

// ---------------- K6: outer-product reg tile; 64 pts x 128 ch; 4x8/thread ----------
__global__ void __launch_bounds__(256,4) k6_final(
    const float* __restrict__ feat, const float* __restrict__ Y2T,
    const float* __restrict__ Wcomb, const float* __restrict__ cstF,
    const float* __restrict__ a2F, const float* __restrict__ d2F,
    float* __restrict__ out)
{
  __shared__ float xl[34*64];
  __shared__ float wl[34*160];
  const int tid = threadIdx.x;
  const int tc = tid & 15;
  const int tp = tid >> 4;
  const int b  = __builtin_amdgcn_readfirstlane((int)blockIdx.x >> 9);
  const int n0 = ((int)blockIdx.x & 511) << 6;

  float acc[4][8];
#pragma unroll
  for (int q=0;q<8;q++){
    float bv = cstF[b*128 + tc*8 + q];
#pragma unroll
    for (int p=0;p<4;p++) acc[p][q] = bv;
  }

  const float* Wb = Wcomb + b*17408;
#pragma unroll 1
  for (int kk=0; kk<4; ++kk){
    __syncthreads();
    for (int u=tid; u<34*64; u+=256){
      int row = u>>6, j = u&63;
      int r = kk*34 + row;
      float v;
      if (r < 64){
        float y = Y2T[(size_t)(b*64+r)*NN + n0 + j];
        v = fmaxf(fmaf(y, a2F[b*64+r], d2F[b*64+r]), 0.f);
      } else {
        v = feat[(size_t)(b*72 + (r-64))*NN + n0 + j];
      }
      xl[u] = v;
    }
    for (int u=tid; u<34*128; u+=256){
      int row = u>>7, c = u&127;
      wl[row*160 + (c>>3)*10 + (c&7)] = Wb[(size_t)(kk*34+row)*128 + c];
    }
    __syncthreads();

#pragma unroll 2
    for (int i=0;i<34;i++){
      const float4 xa = *(const float4*)&xl[i*64 + tp*4];
      const float4 wa = *(const float4*)&wl[i*160 + tc*10];
      const float4 wb = *(const float4*)&wl[i*160 + tc*10 + 4];
      const float xs[4] = {xa.x,xa.y,xa.z,xa.w};
      const float wv[8] = {wa.x,wa.y,wa.z,wa.w,wb.x,wb.y,wb.z,wb.w};
#pragma unroll
      for (int p=0;p<4;p++)
#pragma unroll
        for (int q=0;q<8;q++)
          acc[p][q] = fmaf(wv[q], xs[p], acc[p][q]);
    }
  }

#pragma unroll
  for (int q=0;q<8;q++){
    const int ch = b*128 + tc*8 + q;
    float4 r0;
    float v;
    v = acc[0][q]; r0.x = v>0.f? v : 0.01f*v;
    v = acc[1][q]; r0.y = v>0.f? v : 0.01f*v;
    v = acc[2][q]; r0.z = v>0.f? v : 0.01f*v;
    v = acc[3][q]; r0.w = v>0.f? v : 0.01f*v;
    *(float4*)(out + (size_t)ch*NN + n0 + tp*4) = r0;
  }
}

extern "C" void kernel_launch(void* const* d_in, const int* in_sizes, int n_in,
                              void* d_out, int out_size, void* d_ws, size_t ws_size,
                              hipStream_t stream) {
  (void)in_sizes; (void)n_in; (void)out_size; (void)ws_size;
  const float* coords  = (const float*)d_in[0];
  const float* feats   = (const float*)d_in[1];
  const int*   idx     = (const int*)  d_in[2];
  const float* dist    = (const float*)d_in[3];
  const float* w_mlp1  = (const float*)d_in[4];
  const float* b_mlp1  = (const float*)d_in[5];
  const float* w_lse1  = (const float*)d_in[6];
  const float* b_lse1  = (const float*)d_in[7];
  const float* g_lse1  = (const float*)d_in[8];
  const float* bt_lse1 = (const float*)d_in[9];
  const float* w_pool1 = (const float*)d_in[10];
  const float* b_pool1 = (const float*)d_in[11];
  const float* g_pool1 = (const float*)d_in[12];
  const float* bt_pool1= (const float*)d_in[13];
  const float* w_lse2  = (const float*)d_in[14];
  const float* b_lse2  = (const float*)d_in[15];
  const float* g_lse2  = (const float*)d_in[16];
  const float* bt_lse2 = (const float*)d_in[17];
  const float* w_pool2 = (const float*)d_in[18];
  const float* b_pool2 = (const float*)d_in[19];
  const float* g_pool2 = (const float*)d_in[20];
  const float* bt_pool2= (const float*)d_in[21];
  const float* w_mlp2  = (const float*)d_in[22];
  const float* b_mlp2  = (const float*)d_in[23];
  const float* w_sc    = (const float*)d_in[24];
  const float* b_sc    = (const float*)d_in[25];
  const float* g_sc    = (const float*)d_in[26];
  const float* bt_sc   = (const float*)d_in[27];

  float* ws   = (float*)d_ws;
  float* scS  = ws;            // 256
  float* scQ  = ws + 256;      // 256
  float* vm   = ws + 512;      // 130
  float* p1S  = ws + 704;      // 64
  float* p1Q  = ws + 768;      // 64
  float* p2S  = ws + 832;      // 128
  float* p2Q  = ws + 960;      // 128
  float* w1p  = ws + 1280;     // 768
  float* w2p  = ws + 2048;     // 768
  float* wp1T = ws + 2816;     // 2048
  float* wp2T = ws + 4864;     // 4096 -> 8960
  float* ball = ws + 8960;     // 160 -> 9120
  float* cstF = ws + 9120;     // 256 -> 9376
  float* a2F  = ws + 9376;     // 128 -> 9504
  float* d2F  = ws + 9504;     // 128 -> 9632
  float* ascT = ws + 9632;     // 256 -> 9888
  float* WallT= ws + 9984;     // 11520 -> 21504
  float* Wcomb= ws + 21504;    // 34816 -> 56320
  __half* X1  = (__half*)(ws + 57344);
  __half* Y1  = (__half*)(ws + 57344 + (size_t)NN*32);
  float* Y2T  = ws + 57344 + (size_t)2*NN*32;

  hipMemsetAsync(d_ws, 0, 1088*sizeof(float), stream);

  f0_prep<<<32,256,0,stream>>>(w_mlp1,b_mlp1,w_sc,b_sc,w_pool1,w_pool2,
                               WallT,ball,wp1T,wp2T);
  k0_mlp1_scstats<<<1024,256,0,stream>>>(feats, WallT, ball, X1, scS, scQ);
  k1_vmom<<<1024,256,0,stream>>>(coords, idx, dist, vm);
  f1_fold<<<1,128,0,stream>>>(w_lse1,b_lse1,g_lse1,bt_lse1,
                              w_lse2,b_lse2,g_lse2,bt_lse2,
                              vm, w1p, w2p);
  k2_lse1_pool1<<<2048,256,0,stream>>>(coords, idx, dist, X1, w1p, wp1T, b_pool1,
                                       Y1, p1S, p1Q);
  k4_lse2_pool2<<<2048,256,0,stream>>>(coords, idx, dist, Y1, w2p, wp2T, b_pool2,
                                       p1S, p1Q, g_pool1, bt_pool1,
                                       Y2T, p2S, p2Q);
  f3a_affines<<<1,384,0,stream>>>(scS,scQ,g_sc,bt_sc,b_sc,b_mlp2,
                                  p2S,p2Q,g_pool2,bt_pool2, ascT,cstF,a2F,d2F);
  f3b_wcomb<<<64,256,0,stream>>>(w_mlp2, w_sc, ascT, Wcomb);
  k6_final<<<1024,256,0,stream>>>(feats, Y2T, Wcomb, cstF, a2F, d2F, (float*)d_out);
}

// Round 21
// 229.596 us; speedup vs baseline: 1.0846x; 1.0254x over previous
//
#include <hip/hip_runtime.h>
#include <hip/hip_fp16.h>

#define NN 32768
#define GEPS 1e-6f

typedef _Float16 f16x2 __attribute__((ext_vector_type(2)));
static __device__ __forceinline__ f16x2 as_h2(unsigned u){
  union{unsigned x; f16x2 h;} c; c.x=u; return c.h;
}
static __device__ __forceinline__ unsigned pack_h2(float a, float b){
  __half2 t = __floats2half2_rn(a,b); return *(unsigned*)&t;
}

__device__ __forceinline__ float wredsum(float v){
  v += __shfl_xor(v, 32); v += __shfl_xor(v, 16); v += __shfl_xor(v, 8);
  v += __shfl_xor(v, 4);  v += __shfl_xor(v, 2);  v += __shfl_xor(v, 1);
  return v;
}
__device__ __forceinline__ float eredsum(float v){
  v += __shfl_xor(v, 8); v += __shfl_xor(v, 16); v += __shfl_xor(v, 32);
  return v;
}
__device__ __forceinline__ float ecomb(float v){
  v += __shfl_xor(v, 1); v += __shfl_xor(v, 2); v += __shfl_xor(v, 4);
  return v;
}
__device__ __forceinline__ float hredsum(float v){
  v += __shfl_xor(v, 16); v += __shfl_xor(v, 8);
  v += __shfl_xor(v, 4);  v += __shfl_xor(v, 2);  v += __shfl_xor(v, 1);
  return v;
}

// ---------------- F0: weight transposes / concats ----------------------------------
__global__ void __launch_bounds__(256) f0_prep(
    const float* __restrict__ w_mlp1, const float* __restrict__ b_mlp1,
    const float* __restrict__ w_sc,   const float* __restrict__ b_sc,
    const float* __restrict__ w_pool1,const float* __restrict__ w_pool2,
    float* __restrict__ WallT, float* __restrict__ ball,
    float* __restrict__ wp1T,  float* __restrict__ wp2T)
{
  const int t0 = blockIdx.x*256 + threadIdx.x;
  const int stride = gridDim.x*256;
  for (int u=t0; u<72*160; u+=stride){
    int i = u/160, o = u - i*160;
    WallT[u] = (o < 128) ? w_sc[o*72+i] : w_mlp1[(o-128)*72+i];
  }
  for (int u=t0; u<160; u+=stride)
    ball[u] = (u < 128) ? b_sc[u] : b_mlp1[u-128];
  for (int u=t0; u<64*32; u+=stride){ int c=u>>5, o=u&31; wp1T[u] = w_pool1[o*64+c]; }
  for (int u=t0; u<64*64; u+=stride){ int c=u>>6, o=u&63; wp2T[u] = w_pool2[o*64+c]; }
}

// ---------------- K0: 64 pts/block; dot2 fp16 K-pairs; 3 passes {64,64,32} ch ------
// grid [b:2][tile:512] = 1024; thread (p2 = tid&31: pt pair, g8 = tid>>5: 8-ch group)
__global__ void __launch_bounds__(256,4) k0_mlp1_scstats(
    const float* __restrict__ feat, const float* __restrict__ WallT,
    const float* __restrict__ ball,
    __half* __restrict__ X1, float* __restrict__ scS, float* __restrict__ scQ)
{
  __shared__ unsigned xlu[36*64];    // 9216 B: [i2][pt] = (x[2i2], x[2i2+1])
  __shared__ unsigned wlu[36*64];    // 9216 B: [i2][c]  = (w[2i2][c], w[2i2+1][c])
  __shared__ float ssl[128], sql[128];
  const int tid = threadIdx.x;
  const int p2 = tid & 31;
  const int g8 = tid >> 5;           // per-lane (not wave-uniform)
  const int b  = __builtin_amdgcn_readfirstlane((int)blockIdx.x >> 9);
  const int n0 = ((int)blockIdx.x & 511) << 6;

  // stage x as K-pairs of fp16
  for (int u=tid; u<36*64; u+=256){
    int i2 = u>>6, pt = u&63;
    float fa = feat[(size_t)(b*72 + 2*i2    )*NN + n0 + pt];
    float fb = feat[(size_t)(b*72 + 2*i2 + 1)*NN + n0 + pt];
    xlu[u] = pack_h2(fa, fb);
  }

#pragma unroll 1
  for (int pass=0; pass<3; ++pass){
    const int cb = pass*64;
    __syncthreads();                 // xlu ready / wlu safe
    if (pass==2){
      for (int u=tid; u<36*32; u+=256){
        int i2 = u>>5, c = u&31;
        wlu[i2*64 + c] = pack_h2(WallT[(2*i2)*160 + 128 + c],
                                 WallT[(2*i2+1)*160 + 128 + c]);
      }
    } else {
      for (int u=tid; u<36*64; u+=256){
        int i2 = u>>6, c = u&63;
        wlu[i2*64 + c] = pack_h2(WallT[(2*i2)*160 + cb + c],
                                 WallT[(2*i2+1)*160 + cb + c]);
      }
    }
    __syncthreads();

    if (pass==2 && g8 >= 4){ continue; }

    const int oc = g8*8;
    float a0[8], a1[8];
#pragma unroll
    for (int q=0;q<8;q++){
      float bv = ball[cb + oc + q];
      a0[q]=bv; a1[q]=bv;
    }

#pragma unroll 4
    for (int i2=0;i2<36;i2++){
      uint2 xv = *(const uint2*)(xlu + i2*64 + 2*p2);
      f16x2 xA = as_h2(xv.x), xB = as_h2(xv.y);
      uint4 wa = *(const uint4*)(wlu + i2*64 + oc);
      uint4 wb = *(const uint4*)(wlu + i2*64 + oc + 4);
      a0[0]=__builtin_amdgcn_fdot2(as_h2(wa.x), xA, a0[0], false);
      a1[0]=__builtin_amdgcn_fdot2(as_h2(wa.x), xB, a1[0], false);
      a0[1]=__builtin_amdgcn_fdot2(as_h2(wa.y), xA, a0[1], false);
      a1[1]=__builtin_amdgcn_fdot2(as_h2(wa.y), xB, a1[1], false);
      a0[2]=__builtin_amdgcn_fdot2(as_h2(wa.z), xA, a0[2], false);
      a1[2]=__builtin_amdgcn_fdot2(as_h2(wa.z), xB, a1[2], false);
      a0[3]=__builtin_amdgcn_fdot2(as_h2(wa.w), xA, a0[3], false);
      a1[3]=__builtin_amdgcn_fdot2(as_h2(wa.w), xB, a1[3], false);
      a0[4]=__builtin_amdgcn_fdot2(as_h2(wb.x), xA, a0[4], false);
      a1[4]=__builtin_amdgcn_fdot2(as_h2(wb.x), xB, a1[4], false);
      a0[5]=__builtin_amdgcn_fdot2(as_h2(wb.y), xA, a0[5], false);
      a1[5]=__builtin_amdgcn_fdot2(as_h2(wb.y), xB, a1[5], false);
      a0[6]=__builtin_amdgcn_fdot2(as_h2(wb.z), xA, a0[6], false);
      a1[6]=__builtin_amdgcn_fdot2(as_h2(wb.z), xB, a1[6], false);
      a0[7]=__builtin_amdgcn_fdot2(as_h2(wb.w), xA, a0[7], false);
      a1[7]=__builtin_amdgcn_fdot2(as_h2(wb.w), xB, a1[7], false);
    }

    if (pass < 2){
#pragma unroll
      for (int q=0;q<8;q++){
        float s  = hredsum(a0[q]+a1[q]);
        float s2 = hredsum(a0[q]*a0[q] + a1[q]*a1[q]);
        if (p2==0){ ssl[cb+oc+q] = s; sql[cb+oc+q] = s2; }
      }
    } else {
      __half2 h0[4], h1[4];
#pragma unroll
      for (int q=0;q<4;q++){
        float v00 = a0[q*2],   v01 = a0[q*2+1];
        float v10 = a1[q*2],   v11 = a1[q*2+1];
        v00 = v00>0.f? v00 : 0.2f*v00;  v01 = v01>0.f? v01 : 0.2f*v01;
        v10 = v10>0.f? v10 : 0.2f*v10;  v11 = v11>0.f? v11 : 0.2f*v11;
        h0[q] = __floats2half2_rn(v00, v01);
        h1[q] = __floats2half2_rn(v10, v11);
      }
      // NOTE: a0 is point (n0+2*p2), a1 is point (n0+2*p2+1)
      __half* xb = X1 + ((size_t)b*NN + n0 + p2*2)*32 + g8*8;
      *(uint4*)(xb)      = *(uint4*)h0;
      *(uint4*)(xb + 32) = *(uint4*)h1;
    }
  }

  __syncthreads();
  if (tid < 128){
    atomicAdd(&scS[b*128+tid], ssl[tid]);
    atomicAdd(&scQ[b*128+tid], sql[tid]);
  }
}

// ---------------- K1: v10 moments, 4 threads per point (k-quarters) -----------------
__global__ void __launch_bounds__(256) k1_vmom(
    const float* __restrict__ coords, const int* __restrict__ idx,
    const float* __restrict__ dist, float* __restrict__ vm)
{
  __shared__ float red[4*65];
  const int tid = threadIdx.x, lane = tid & 63, wid = tid >> 6;
  const int gn = blockIdx.x*256 + tid;
  const int pt = gn >> 2, h = gn & 3;
  const int b = pt >> 15, n = pt & (NN-1);
  const size_t pb = (size_t)b*NN + n;
  const float c0 = coords[pb*3+0], c1 = coords[pb*3+1], c2 = coords[pb*3+2];

  int ja[4]; float da[4];
  {
    int4 j4 = *(const int4*)(idx + pb*16 + h*4);
    float4 d4 = *(const float4*)(dist + pb*16 + h*4);
    ja[0]=j4.x; ja[1]=j4.y; ja[2]=j4.z; ja[3]=j4.w;
    da[0]=d4.x; da[1]=d4.y; da[2]=d4.z; da[3]=d4.w;
  }

  float aS[10], aM[55];
#pragma unroll
  for (int i=0;i<10;i++) aS[i]=0.f;
#pragma unroll
  for (int i=0;i<55;i++) aM[i]=0.f;

#pragma unroll
  for (int k=0;k<4;k++){
    const float* nb = coords + ((size_t)b*NN + ja[k])*3;
    const float n0v=nb[0], n1v=nb[1], n2v=nb[2];
    const float v[10] = {c0,c1,c2,n0v,n1v,n2v,c0-n0v,c1-n1v,c2-n2v,da[k]};
#pragma unroll
    for (int i=0;i<10;i++){
      aS[i] += v[i];
#pragma unroll
      for (int j=i;j<10;j++)
        aM[i*10 - (i*(i-1))/2 + (j-i)] += v[i]*v[j];
    }
  }

#pragma unroll
  for (int i=0;i<10;i++){ float s = wredsum(aS[i]); if (lane==0) red[wid*65+i] = s; }
#pragma unroll
  for (int i=0;i<55;i++){ float s = wredsum(aM[i]); if (lane==0) red[wid*65+10+i] = s; }
  __syncthreads();
  if (tid < 65){
    float s = red[tid] + red[65+tid] + red[130+tid] + red[195+tid];
    const int bb = blockIdx.x >> 9;
    atomicAdd(&vm[bb*65+tid], s);
  }
}

// ---------------- F1: fold GN into LSE conv weights --------------------------------
__global__ void f1_fold(
    const float* __restrict__ w_lse1, const float* __restrict__ b_lse1,
    const float* __restrict__ g_lse1, const float* __restrict__ bt_lse1,
    const float* __restrict__ w_lse2, const float* __restrict__ b_lse2,
    const float* __restrict__ g_lse2, const float* __restrict__ bt_lse2,
    const float* __restrict__ vm,
    float* __restrict__ w1p, float* __restrict__ w2p)
{
  const int tid = threadIdx.x; // 128
  const int half = tid >> 6;
  const int u = tid & 63, b = u >> 5, c = u & 31;
  const float* W  = half ? w_lse2  : w_lse1;
  const float* Bv = half ? b_lse2  : b_lse1;
  const float* G  = half ? g_lse2  : g_lse1;
  const float* Bt = half ? bt_lse2 : bt_lse1;
  float wr[10];
#pragma unroll
  for (int i=0;i<10;i++) wr[i] = W[c*10+i];
  const float* S = vm + b*65;
  const float* M = vm + b*65 + 10;
  float P = 0.f;
#pragma unroll
  for (int i=0;i<10;i++) P = fmaf(wr[i], S[i], P);
  float Q = 0.f;
#pragma unroll
  for (int i=0;i<10;i++){
#pragma unroll
    for (int j=i;j<10;j++){
      float m = M[i*10 - (i*(i-1))/2 + (j-i)];
      float t = wr[i]*wr[j]*m;
      Q += (i==j) ? t : 2.f*t;
    }
  }
  const float invNK = 1.f/((float)NN*16.f);
  const float bc = Bv[c];
  float mean = P*invNK + bc;
  float ey2  = (Q + 2.f*bc*P)*invNK + bc*bc;
  float mu = 0.5f*(mean + __shfl_xor(mean,1));
  float e2 = 0.5f*(ey2  + __shfl_xor(ey2, 1));
  float var = e2 - mu*mu;
  float rstd = rsqrtf(var + GEPS);
  float a = G[c]*rstd, d = Bt[c] - mu*a;
  float* out = (half ? w2p : w1p) + (b*32+c)*12;
#pragma unroll
  for (int i=0;i<10;i++) out[i] = wr[i]*a;
  out[10] = bc*a + d;
  out[11] = 0.f;
}

// ---------------- K2: LSE1+pool1; fp16 gather; LDS pool weights --------------------
__global__ void __launch_bounds__(256,6) k2_lse1_pool1(
    const float* __restrict__ coords, const int* __restrict__ idx,
    const float* __restrict__ dist, const __half* __restrict__ X1,
    const float* __restrict__ w1p, const float* __restrict__ wp1T,
    const float* __restrict__ b_pool1,
    __half* __restrict__ Y1, float* __restrict__ p1S, float* __restrict__ p1Q)
{
  __shared__ float mfl[32*66];
  __shared__ float wlds[64*32];
  __shared__ float sl[32], ql[32];
  const int tid = threadIdx.x, lane = tid & 63;
  const int e = tid & 7;
  const int pl = tid >> 3;
  if (tid < 32){ sl[tid]=0.f; ql[tid]=0.f; }
  for (int u=tid; u<2048; u+=256) wlds[u] = wp1T[u];
  __syncthreads();
  const int b = __builtin_amdgcn_readfirstlane((int)blockIdx.x & 1);
  const int n = (((int)blockIdx.x >> 1) << 5) + pl;
  const size_t pb = (size_t)b*NN + n;
  float* mf = &mfl[pl*66];
  const float s16 = 0.0625f;

  // Phase A: ch-split gather (fp16)
  {
    int ja[16];
    const int4* ip = (const int4*)(idx + pb*16);
#pragma unroll
    for (int k4=0;k4<4;k4++){
      int4 j4 = ip[k4];
      ja[k4*4+0]=j4.x; ja[k4*4+1]=j4.y; ja[k4*4+2]=j4.z; ja[k4*4+3]=j4.w;
    }
    float af0=0.f, af1=0.f, af2=0.f, af3=0.f;
    const __half* xb = X1 + (size_t)b*NN*32 + e*4;
#pragma unroll 4
    for (int k=0;k<16;k++){
      uint2 v = *(const uint2*)(xb + (size_t)ja[k]*32);
      __half2 h0 = *(__half2*)&v.x, h1 = *(__half2*)&v.y;
      float2 f0 = __half22float2(h0), f1 = __half22float2(h1);
      af0+=f0.x; af1+=f0.y; af2+=f1.x; af3+=f1.y;
    }
    mf[32+e*4+0]=af0*s16; mf[32+e*4+1]=af1*s16;
    mf[32+e*4+2]=af2*s16; mf[32+e*4+3]=af3*s16;
  }

  // Phase B: k-split enc
  {
    int2 j2 = *(const int2*)(idx + pb*16 + e*2);
    float2 d2 = *(const float2*)(dist + pb*16 + e*2);
    const float* nb0 = coords + ((size_t)b*NN + j2.x)*3;
    const float* nb1 = coords + ((size_t)b*NN + j2.y)*3;
    const float nx0=nb0[0], ny0=nb0[1], nz0=nb0[2];
    const float nx1=nb1[0], ny1=nb1[1], nz1=nb1[2];
    const float c0=coords[pb*3], c1=coords[pb*3+1], c2=coords[pb*3+2];
    const float* wrow = w1p + (size_t)(b*32)*12;
#pragma unroll 1
    for (int cc=0;cc<4;cc++){
      float ptc[8];
#pragma unroll
      for (int q=0;q<8;q++){
        const float4* r4 = (const float4*)(wrow + (cc*8+q)*12);
        float4 ra=r4[0], rb=r4[1], rc=r4[2];
        const float t0=ra.x+rb.z, t1=ra.y+rb.w, t2=ra.z+rc.x;
        const float u0=ra.w-rb.z, u1=rb.x-rb.w, u2=rb.y-rc.x;
        const float wd=rc.y;
        float cb = rc.z;
        cb = fmaf(t0,c0,cb); cb = fmaf(t1,c1,cb); cb = fmaf(t2,c2,cb);
        float s0 = cb, s1 = cb;
        s0 = fmaf(u0,nx0,s0); s0 = fmaf(u1,ny0,s0); s0 = fmaf(u2,nz0,s0);
        s0 = fmaf(wd,d2.x,s0);
        s1 = fmaf(u0,nx1,s1); s1 = fmaf(u1,ny1,s1); s1 = fmaf(u2,nz1,s1);
        s1 = fmaf(wd,d2.y,s1);
        ptc[q] = fmaxf(s0,0.f) + fmaxf(s1,0.f);
      }
#pragma unroll
      for (int q=0;q<8;q++) ptc[q] = ecomb(ptc[q]);
      if ((e>>1)==cc){
        float v0 = (e&1) ? ptc[4] : ptc[0];
        float v1 = (e&1) ? ptc[5] : ptc[1];
        float v2 = (e&1) ? ptc[6] : ptc[2];
        float v3 = (e&1) ? ptc[7] : ptc[3];
        mf[e*4+0]=v0*s16; mf[e*4+1]=v1*s16;
        mf[e*4+2]=v2*s16; mf[e*4+3]=v3*s16;
      }
    }
  }
  __syncthreads();

  // pool1: outputs e*4 .. e*4+4 over 64 inputs (weights from LDS)
  const int o0 = e*4;
  float yac[4];
  {
    const float4 b0 = *(const float4*)(b_pool1 + o0);
    yac[0]=b0.x; yac[1]=b0.y; yac[2]=b0.z; yac[3]=b0.w;
  }
#pragma unroll 4
  for (int c=0;c<64;c++){
    const float mc = mf[c];
    const float4 w0 = *(const float4*)(wlds + c*32 + o0);
    yac[0]=fmaf(w0.x,mc,yac[0]); yac[1]=fmaf(w0.y,mc,yac[1]);
    yac[2]=fmaf(w0.z,mc,yac[2]); yac[3]=fmaf(w0.w,mc,yac[3]);
  }
  {
    __half2 h[2];
    h[0] = __floats2half2_rn(yac[0], yac[1]);
    h[1] = __floats2half2_rn(yac[2], yac[3]);
    *(uint2*)(Y1 + pb*32 + o0) = *(uint2*)h;
  }
#pragma unroll
  for (int q=0;q<4;q++){
    float s  = eredsum(yac[q]);
    float s2 = eredsum(yac[q]*yac[q]);
    if (lane < 8){ atomicAdd(&sl[o0+q], s); atomicAdd(&ql[o0+q], s2); }
  }
  __syncthreads();
  if (tid<32){ atomicAdd(&p1S[b*32+tid], sl[tid]); atomicAdd(&p1Q[b*32+tid], ql[tid]); }
}

// ---------------- K4: LSE2+pool2; fp16 gather + fused GN; LDS pool weights ----------
__global__ void __launch_bounds__(256,6) k4_lse2_pool2(
    const float* __restrict__ coords, const int* __restrict__ idx,
    const float* __restrict__ dist, const __half* __restrict__ Y1,
    const float* __restrict__ w2p, const float* __restrict__ wp2T,
    const float* __restrict__ b_pool2,
    const float* __restrict__ p1S, const float* __restrict__ p1Q,
    const float* __restrict__ g_p1, const float* __restrict__ bt_p1,
    float* __restrict__ Y2T, float* __restrict__ p2S, float* __restrict__ p2Q)
{
  __shared__ float mfl[32*66];
  __shared__ float wlds[64*64];
  __shared__ float sl[64], ql[64];
  __shared__ float al[32], dl[32];
  const int tid = threadIdx.x, lane = tid & 63;
  const int e = tid & 7;
  const int pl = tid >> 3;
  const int b = __builtin_amdgcn_readfirstlane((int)blockIdx.x & 1);
  if (tid < 64){ sl[tid]=0.f; ql[tid]=0.f; }
  if (tid >= 64 && tid < 96){
    const int c = tid - 64;
    float s = p1S[b*32+c], q = p1Q[b*32+c];
    s += __shfl_xor(s,1); q += __shfl_xor(q,1);
    const float inv = 1.f/(2.f*(float)NN);
    float mu = s*inv, e2 = q*inv, var = e2-mu*mu;
    float rstd = rsqrtf(var + GEPS);
    float a = g_p1[c]*rstd;
    al[c] = a; dl[c] = bt_p1[c] - mu*a;
  }
  for (int u=tid; u<4096; u+=256) wlds[u] = wp2T[u];
  __syncthreads();
  const int n0g = (((int)blockIdx.x >> 1) << 5);
  const int n = n0g + pl;
  const size_t pb = (size_t)b*NN + n;
  float* mf = &mfl[pl*66];
  const float s16 = 0.0625f;

  // Phase A: fp16 gather with fused pool1-GN+ReLU
  {
    const float a0g=al[e*4+0], a1g=al[e*4+1], a2g=al[e*4+2], a3g=al[e*4+3];
    const float d0g=dl[e*4+0], d1g=dl[e*4+1], d2g=dl[e*4+2], d3g=dl[e*4+3];
    int ja[16];
    const int4* ip = (const int4*)(idx + pb*16);
#pragma unroll
    for (int k4=0;k4<4;k4++){
      int4 j4 = ip[k4];
      ja[k4*4+0]=j4.x; ja[k4*4+1]=j4.y; ja[k4*4+2]=j4.z; ja[k4*4+3]=j4.w;
    }
    float af0=0.f, af1=0.f, af2=0.f, af3=0.f;
    const __half* yb = Y1 + (size_t)b*NN*32 + e*4;
#pragma unroll 4
    for (int k=0;k<16;k++){
      uint2 v = *(const uint2*)(yb + (size_t)ja[k]*32);
      __half2 h0 = *(__half2*)&v.x, h1 = *(__half2*)&v.y;
      float2 f0 = __half22float2(h0), f1 = __half22float2(h1);
      af0 += fmaxf(fmaf(f0.x, a0g, d0g), 0.f);
      af1 += fmaxf(fmaf(f0.y, a1g, d1g), 0.f);
      af2 += fmaxf(fmaf(f1.x, a2g, d2g), 0.f);
      af3 += fmaxf(fmaf(f1.y, a3g, d3g), 0.f);
    }
    mf[32+e*4+0]=af0*s16; mf[32+e*4+1]=af1*s16;
    mf[32+e*4+2]=af2*s16; mf[32+e*4+3]=af3*s16;
  }

  // Phase B: k-split enc
  {
    int2 j2 = *(const int2*)(idx + pb*16 + e*2);
    float2 d2 = *(const float2*)(dist + pb*16 + e*2);
    const float* nb0 = coords + ((size_t)b*NN + j2.x)*3;
    const float* nb1 = coords + ((size_t)b*NN + j2.y)*3;
    const float nx0=nb0[0], ny0=nb0[1], nz0=nb0[2];
    const float nx1=nb1[0], ny1=nb1[1], nz1=nb1[2];
    const float c0=coords[pb*3], c1=coords[pb*3+1], c2=coords[pb*3+2];
    const float* wrow = w2p + (size_t)(b*32)*12;
#pragma unroll 1
    for (int cc=0;cc<4;cc++){
      float ptc[8];
#pragma unroll
      for (int q=0;q<8;q++){
        const float4* r4 = (const float4*)(wrow + (cc*8+q)*12);
        float4 ra=r4[0], rb=r4[1], rc=r4[2];
        const float t0=ra.x+rb.z, t1=ra.y+rb.w, t2=ra.z+rc.x;
        const float u0=ra.w-rb.z, u1=rb.x-rb.w, u2=rb.y-rc.x;
        const float wd=rc.y;
        float cb = rc.z;
        cb = fmaf(t0,c0,cb); cb = fmaf(t1,c1,cb); cb = fmaf(t2,c2,cb);
        float s0 = cb, s1 = cb;
        s0 = fmaf(u0,nx0,s0); s0 = fmaf(u1,ny0,s0); s0 = fmaf(u2,nz0,s0);
        s0 = fmaf(wd,d2.x,s0);
        s1 = fmaf(u0,nx1,s1); s1 = fmaf(u1,ny1,s1); s1 = fmaf(u2,nz1,s1);
        s1 = fmaf(wd,d2.y,s1);
        ptc[q] = fmaxf(s0,0.f) + fmaxf(s1,0.f);
      }
#pragma unroll
      for (int q=0;q<8;q++) ptc[q] = ecomb(ptc[q]);
      if ((e>>1)==cc){
        float v0 = (e&1) ? ptc[4] : ptc[0];
        float v1 = (e&1) ? ptc[5] : ptc[1];
        float v2 = (e&1) ? ptc[6] : ptc[2];
        float v3 = (e&1) ? ptc[7] : ptc[3];
        mf[e*4+0]=v0*s16; mf[e*4+1]=v1*s16;
        mf[e*4+2]=v2*s16; mf[e*4+3]=v3*s16;
      }
    }
  }
  __syncthreads();

  // pool2: outputs e*8 .. e*8+8 over 64 inputs (weights from LDS)
  const int o0 = e*8;
  float yac[8];
  {
    const float4 b0 = *(const float4*)(b_pool2 + o0);
    const float4 b1 = *(const float4*)(b_pool2 + o0 + 4);
    yac[0]=b0.x; yac[1]=b0.y; yac[2]=b0.z; yac[3]=b0.w;
    yac[4]=b1.x; yac[5]=b1.y; yac[6]=b1.z; yac[7]=b1.w;
  }
#pragma unroll 4
  for (int c=0;c<64;c++){
    const float mc = mf[c];
    const float4 w0 = *(const float4*)(wlds + c*64 + o0);
    const float4 w1 = *(const float4*)(wlds + c*64 + o0 + 4);
    yac[0]=fmaf(w0.x,mc,yac[0]); yac[1]=fmaf(w0.y,mc,yac[1]);
    yac[2]=fmaf(w0.z,mc,yac[2]); yac[3]=fmaf(w0.w,mc,yac[3]);
    yac[4]=fmaf(w1.x,mc,yac[4]); yac[5]=fmaf(w1.y,mc,yac[5]);
    yac[6]=fmaf(w1.z,mc,yac[6]); yac[7]=fmaf(w1.w,mc,yac[7]);
  }
#pragma unroll
  for (int q=0;q<8;q++){
    float s  = eredsum(yac[q]);
    float s2 = eredsum(yac[q]*yac[q]);
    if (lane < 8){ atomicAdd(&sl[o0+q], s); atomicAdd(&ql[o0+q], s2); }
  }
  __syncthreads();
  float* ldsT = &mfl[0];
#pragma unroll
  for (int o=0;o<8;o++) ldsT[(o0+o)*33 + pl] = yac[o];
  __syncthreads();
#pragma unroll
  for (int r=0;r<8;r++){
    int u = tid + r*256;
    int ch = u >> 5, p = u & 31;
    Y2T[((size_t)(b*64+ch))*NN + n0g + p] = ldsT[ch*33 + p];
  }
  if (tid<64){ atomicAdd(&p2S[b*64+tid], sl[tid]); atomicAdd(&p2Q[b*64+tid], ql[tid]); }
}

// ---------------- F3a: per-batch GN affines (sc + pool2) ----------------------------
__global__ void f3a_affines(
    const float* __restrict__ scS, const float* __restrict__ scQ,
    const float* __restrict__ g_sc, const float* __restrict__ bt_sc,
    const float* __restrict__ b_sc, const float* __restrict__ b_mlp2,
    const float* __restrict__ p2S, const float* __restrict__ p2Q,
    const float* __restrict__ g_p2, const float* __restrict__ bt_p2,
    float* __restrict__ ascT, float* __restrict__ cstF,
    float* __restrict__ a2F, float* __restrict__ d2F)
{
  const int tid = threadIdx.x; // 384
  if (tid < 256){
    const int b = tid >> 7, c = tid & 127;
    float s = scS[b*128+c], q = scQ[b*128+c];
    s += __shfl_xor(s,1); q += __shfl_xor(q,1);
    s += __shfl_xor(s,2); q += __shfl_xor(q,2);
    s += __shfl_xor(s,4); q += __shfl_xor(q,4);
    const float inv = 1.f/(8.f*(float)NN);
    float mu = s*inv, e2 = q*inv, var = e2-mu*mu;
    float rstd = rsqrtf(var + GEPS);
    float a = g_sc[c]*rstd;
    ascT[tid] = a;
    cstF[tid] = b_mlp2[c] + a*b_sc[c] + (bt_sc[c] - mu*a);
  } else {
    const int t = tid - 256;
    const int b = t >> 6, c = t & 63;
    float s = p2S[b*64+c], q = p2Q[b*64+c];
    s += __shfl_xor(s,1); q += __shfl_xor(q,1);
    s += __shfl_xor(s,2); q += __shfl_xor(q,2);
    const float inv = 1.f/(4.f*(float)NN);
    float mu = s*inv, e2 = q*inv, var = e2-mu*mu;
    float rstd = rsqrtf(var + GEPS);
    float a = g_p2[c]*rstd;
    a2F[t] = a; d2F[t] = bt_p2[c] - mu*a;
  }
}

// ---------------- F3b: Wcomb[b] = [ w_mlp2^T (64x128) ; w_sc^T * asc[b] (72x128) ] --
__global__ void __launch_bounds__(256) f3b_wcomb(
    const float* __restrict__ w_mlp2, const float* __restrict__ w_sc,
    const float* __restrict__ ascT, float* __restrict__ Wcomb)
{
  const int t0 = blockIdx.x*256 + threadIdx.x;
  const int stride = gridDim.x*256;
  for (int u=t0; u<2*136*128; u+=stride){
    int bb = u / 17408;
    int rr = u - bb*17408;
    int i = rr >> 7, o = rr & 127;
    Wcomb[u] = (i < 64) ? w_mlp2[o*64+i]
                        : w_sc[o*72 + (i-64)] * ascT[bb*128+o];
  }
}

// ---------------- K6: outer-product reg tile; 64 pts x 128 ch; 4x8/thread ----------
__global__ void __launch_bounds__(256,4) k6_final(
    const float* __restrict__ feat, const float* __restrict__ Y2T,
    const float* __restrict__ Wcomb, const float* __restrict__ cstF,
    const float* __restrict__ a2F, const float* __restrict__ d2F,
    float* __restrict__ out)
{
  __shared__ float xl[34*64];
  __shared__ float wl[34*160];
  const int tid = threadIdx.x;
  const int tc = tid & 15;
  const int tp = tid >> 4;
  const int b  = __builtin_amdgcn_readfirstlane((int)blockIdx.x >> 9);
  const int n0 = ((int)blockIdx.x & 511) << 6;

  float acc[4][8];
#pragma unroll
  for (int q=0;q<8;q++){
    float bv = cstF[b*128 + tc*8 + q];
#pragma unroll
    for (int p=0;p<4;p++) acc[p][q] = bv;
  }

  const float* Wb = Wcomb + b*17408;
#pragma unroll 1
  for (int kk=0; kk<4; ++kk){
    __syncthreads();
    for (int u=tid; u<34*64; u+=256){
      int row = u>>6, j = u&63;
      int r = kk*34 + row;
      float v;
      if (r < 64){
        float y = Y2T[(size_t)(b*64+r)*NN + n0 + j];
        v = fmaxf(fmaf(y, a2F[b*64+r], d2F[b*64+r]), 0.f);
      } else {
        v = feat[(size_t)(b*72 + (r-64))*NN + n0 + j];
      }
      xl[u] = v;
    }
    for (int u=tid; u<34*128; u+=256){
      int row = u>>7, c = u&127;
      wl[row*160 + (c>>3)*10 + (c&7)] = Wb[(size_t)(kk*34+row)*128 + c];
    }
    __syncthreads();

#pragma unroll 2
    for (int i=0;i<34;i++){
      const float4 xa = *(const float4*)&xl[i*64 + tp*4];
      const float4 wa = *(const float4*)&wl[i*160 + tc*10];
      const float4 wb = *(const float4*)&wl[i*160 + tc*10 + 4];
      const float xs[4] = {xa.x,xa.y,xa.z,xa.w};
      const float wv[8] = {wa.x,wa.y,wa.z,wa.w,wb.x,wb.y,wb.z,wb.w};
#pragma unroll
      for (int p=0;p<4;p++)
#pragma unroll
        for (int q=0;q<8;q++)
          acc[p][q] = fmaf(wv[q], xs[p], acc[p][q]);
    }
  }

#pragma unroll
  for (int q=0;q<8;q++){
    const int ch = b*128 + tc*8 + q;
    float4 r0;
    float v;
    v = acc[0][q]; r0.x = v>0.f? v : 0.01f*v;
    v = acc[1][q]; r0.y = v>0.f? v : 0.01f*v;
    v = acc[2][q]; r0.z = v>0.f? v : 0.01f*v;
    v = acc[3][q]; r0.w = v>0.f? v : 0.01f*v;
    *(float4*)(out + (size_t)ch*NN + n0 + tp*4) = r0;
  }
}

extern "C" void kernel_launch(void* const* d_in, const int* in_sizes, int n_in,
                              void* d_out, int out_size, void* d_ws, size_t ws_size,
                              hipStream_t stream) {
  (void)in_sizes; (void)n_in; (void)out_size; (void)ws_size;
  const float* coords  = (const float*)d_in[0];
  const float* feats   = (const float*)d_in[1];
  const int*   idx     = (const int*)  d_in[2];
  const float* dist    = (const float*)d_in[3];
  const float* w_mlp1  = (const float*)d_in[4];
  const float* b_mlp1  = (const float*)d_in[5];
  const float* w_lse1  = (const float*)d_in[6];
  const float* b_lse1  = (const float*)d_in[7];
  const float* g_lse1  = (const float*)d_in[8];
  const float* bt_lse1 = (const float*)d_in[9];
  const float* w_pool1 = (const float*)d_in[10];
  const float* b_pool1 = (const float*)d_in[11];
  const float* g_pool1 = (const float*)d_in[12];
  const float* bt_pool1= (const float*)d_in[13];
  const float* w_lse2  = (const float*)d_in[14];
  const float* b_lse2  = (const float*)d_in[15];
  const float* g_lse2  = (const float*)d_in[16];
  const float* bt_lse2 = (const float*)d_in[17];
  const float* w_pool2 = (const float*)d_in[18];
  const float* b_pool2 = (const float*)d_in[19];
  const float* g_pool2 = (const float*)d_in[20];
  const float* bt_pool2= (const float*)d_in[21];
  const float* w_mlp2  = (const float*)d_in[22];
  const float* b_mlp2  = (const float*)d_in[23];
  const float* w_sc    = (const float*)d_in[24];
  const float* b_sc    = (const float*)d_in[25];
  const float* g_sc    = (const float*)d_in[26];
  const float* bt_sc   = (const float*)d_in[27];

  float* ws   = (float*)d_ws;
  float* scS  = ws;            // 256
  float* scQ  = ws + 256;      // 256
  float* vm   = ws + 512;      // 130
  float* p1S  = ws + 704;      // 64
  float* p1Q  = ws + 768;      // 64
  float* p2S  = ws + 832;      // 128
  float* p2Q  = ws + 960;      // 128
  float* w1p  = ws + 1280;     // 768
  float* w2p  = ws + 2048;     // 768
  float* wp1T = ws + 2816;     // 2048
  float* wp2T = ws + 4864;     // 4096 -> 8960
  float* ball = ws + 8960;     // 160 -> 9120
  float* cstF = ws + 9120;     // 256 -> 9376
  float* a2F  = ws + 9376;     // 128 -> 9504
  float* d2F  = ws + 9504;     // 128 -> 9632
  float* ascT = ws + 9632;     // 256 -> 9888
  float* WallT= ws + 9984;     // 11520 -> 21504
  float* Wcomb= ws + 21504;    // 34816 -> 56320
  __half* X1  = (__half*)(ws + 57344);
  __half* Y1  = (__half*)(ws + 57344 + (size_t)NN*32);
  float* Y2T  = ws + 57344 + (size_t)2*NN*32;

  hipMemsetAsync(d_ws, 0, 1088*sizeof(float), stream);

  f0_prep<<<32,256,0,stream>>>(w_mlp1,b_mlp1,w_sc,b_sc,w_pool1,w_pool2,
                               WallT,ball,wp1T,wp2T);
  k0_mlp1_scstats<<<1024,256,0,stream>>>(feats, WallT, ball, X1, scS, scQ);
  k1_vmom<<<1024,256,0,stream>>>(coords, idx, dist, vm);
  f1_fold<<<1,128,0,stream>>>(w_lse1,b_lse1,g_lse1,bt_lse1,
                              w_lse2,b_lse2,g_lse2,bt_lse2,
                              vm, w1p, w2p);
  k2_lse1_pool1<<<2048,256,0,stream>>>(coords, idx, dist, X1, w1p, wp1T, b_pool1,
                                       Y1, p1S, p1Q);
  k4_lse2_pool2<<<2048,256,0,stream>>>(coords, idx, dist, Y1, w2p, wp2T, b_pool2,
                                       p1S, p1Q, g_pool1, bt_pool1,
                                       Y2T, p2S, p2Q);
  f3a_affines<<<1,384,0,stream>>>(scS,scQ,g_sc,bt_sc,b_sc,b_mlp2,
                                  p2S,p2Q,g_pool2,bt_pool2, ascT,cstF,a2F,d2F);
  f3b_wcomb<<<64,256,0,stream>>>(w_mlp2, w_sc, ascT, Wcomb);
  k6_final<<<1024,256,0,stream>>>(feats, Y2T, Wcomb, cstF, a2F, d2F, (float*)d_out);
}

// Round 22
// 223.223 us; speedup vs baseline: 1.1156x; 1.0286x over previous
//
#include <hip/hip_runtime.h>
#include <hip/hip_fp16.h>

#define NN 32768
#define GEPS 1e-6f

typedef _Float16 f16x2 __attribute__((ext_vector_type(2)));
static __device__ __forceinline__ f16x2 as_h2(unsigned u){
  union{unsigned x; f16x2 h;} c; c.x=u; return c.h;
}
static __device__ __forceinline__ unsigned pack_h2(float a, float b){
  __half2 t = __floats2half2_rn(a,b); return *(unsigned*)&t;
}

__device__ __forceinline__ float wredsum(float v){
  v += __shfl_xor(v, 32); v += __shfl_xor(v, 16); v += __shfl_xor(v, 8);
  v += __shfl_xor(v, 4);  v += __shfl_xor(v, 2);  v += __shfl_xor(v, 1);
  return v;
}
__device__ __forceinline__ float eredsum(float v){
  v += __shfl_xor(v, 8); v += __shfl_xor(v, 16); v += __shfl_xor(v, 32);
  return v;
}
__device__ __forceinline__ float ecomb(float v){
  v += __shfl_xor(v, 1); v += __shfl_xor(v, 2); v += __shfl_xor(v, 4);
  return v;
}
__device__ __forceinline__ float hredsum(float v){
  v += __shfl_xor(v, 16); v += __shfl_xor(v, 8);
  v += __shfl_xor(v, 4);  v += __shfl_xor(v, 2);  v += __shfl_xor(v, 1);
  return v;
}

// ---------------- F0: weight transposes / concats; packed fp16 pool weights --------
__global__ void __launch_bounds__(256) f0_prep(
    const float* __restrict__ w_mlp1, const float* __restrict__ b_mlp1,
    const float* __restrict__ w_sc,   const float* __restrict__ b_sc,
    const float* __restrict__ w_pool1,const float* __restrict__ w_pool2,
    float* __restrict__ WallT, float* __restrict__ ball,
    unsigned* __restrict__ wp1H, unsigned* __restrict__ wp2H)
{
  const int t0 = blockIdx.x*256 + threadIdx.x;
  const int stride = gridDim.x*256;
  for (int u=t0; u<72*160; u+=stride){
    int i = u/160, o = u - i*160;
    WallT[u] = (o < 128) ? w_sc[o*72+i] : w_mlp1[(o-128)*72+i];
  }
  for (int u=t0; u<160; u+=stride)
    ball[u] = (u < 128) ? b_sc[u] : b_mlp1[u-128];
  // wp1H[c2*32+o] = (w_pool1[o][2c2], w_pool1[o][2c2+1])  (c2<32, o<32)
  for (int u=t0; u<32*32; u+=stride){
    int c2=u>>5, o=u&31;
    wp1H[u] = pack_h2(w_pool1[o*64 + 2*c2], w_pool1[o*64 + 2*c2 + 1]);
  }
  // wp2H[c2*64+o] = (w_pool2[o][2c2], w_pool2[o][2c2+1])  (c2<32, o<64)
  for (int u=t0; u<32*64; u+=stride){
    int c2=u>>6, o=u&63;
    wp2H[u] = pack_h2(w_pool2[o*64 + 2*c2], w_pool2[o*64 + 2*c2 + 1]);
  }
}

// ---------------- K0: 64 pts/block; dot2 fp16 K-pairs; 3 passes {64,64,32} ch ------
__global__ void __launch_bounds__(256,4) k0_mlp1_scstats(
    const float* __restrict__ feat, const float* __restrict__ WallT,
    const float* __restrict__ ball,
    __half* __restrict__ X1, float* __restrict__ scS, float* __restrict__ scQ)
{
  __shared__ unsigned xlu[36*64];
  __shared__ unsigned wlu[36*64];
  __shared__ float ssl[128], sql[128];
  const int tid = threadIdx.x;
  const int p2 = tid & 31;
  const int g8 = tid >> 5;
  const int b  = __builtin_amdgcn_readfirstlane((int)blockIdx.x >> 9);
  const int n0 = ((int)blockIdx.x & 511) << 6;

  for (int u=tid; u<36*64; u+=256){
    int i2 = u>>6, pt = u&63;
    float fa = feat[(size_t)(b*72 + 2*i2    )*NN + n0 + pt];
    float fb = feat[(size_t)(b*72 + 2*i2 + 1)*NN + n0 + pt];
    xlu[u] = pack_h2(fa, fb);
  }

#pragma unroll 1
  for (int pass=0; pass<3; ++pass){
    const int cb = pass*64;
    __syncthreads();
    if (pass==2){
      for (int u=tid; u<36*32; u+=256){
        int i2 = u>>5, c = u&31;
        wlu[i2*64 + c] = pack_h2(WallT[(2*i2)*160 + 128 + c],
                                 WallT[(2*i2+1)*160 + 128 + c]);
      }
    } else {
      for (int u=tid; u<36*64; u+=256){
        int i2 = u>>6, c = u&63;
        wlu[i2*64 + c] = pack_h2(WallT[(2*i2)*160 + cb + c],
                                 WallT[(2*i2+1)*160 + cb + c]);
      }
    }
    __syncthreads();

    if (pass==2 && g8 >= 4){ continue; }

    const int oc = g8*8;
    float a0[8], a1[8];
#pragma unroll
    for (int q=0;q<8;q++){
      float bv = ball[cb + oc + q];
      a0[q]=bv; a1[q]=bv;
    }

#pragma unroll 4
    for (int i2=0;i2<36;i2++){
      uint2 xv = *(const uint2*)(xlu + i2*64 + 2*p2);
      f16x2 xA = as_h2(xv.x), xB = as_h2(xv.y);
      uint4 wa = *(const uint4*)(wlu + i2*64 + oc);
      uint4 wb = *(const uint4*)(wlu + i2*64 + oc + 4);
      a0[0]=__builtin_amdgcn_fdot2(as_h2(wa.x), xA, a0[0], false);
      a1[0]=__builtin_amdgcn_fdot2(as_h2(wa.x), xB, a1[0], false);
      a0[1]=__builtin_amdgcn_fdot2(as_h2(wa.y), xA, a0[1], false);
      a1[1]=__builtin_amdgcn_fdot2(as_h2(wa.y), xB, a1[1], false);
      a0[2]=__builtin_amdgcn_fdot2(as_h2(wa.z), xA, a0[2], false);
      a1[2]=__builtin_amdgcn_fdot2(as_h2(wa.z), xB, a1[2], false);
      a0[3]=__builtin_amdgcn_fdot2(as_h2(wa.w), xA, a0[3], false);
      a1[3]=__builtin_amdgcn_fdot2(as_h2(wa.w), xB, a1[3], false);
      a0[4]=__builtin_amdgcn_fdot2(as_h2(wb.x), xA, a0[4], false);
      a1[4]=__builtin_amdgcn_fdot2(as_h2(wb.x), xB, a1[4], false);
      a0[5]=__builtin_amdgcn_fdot2(as_h2(wb.y), xA, a0[5], false);
      a1[5]=__builtin_amdgcn_fdot2(as_h2(wb.y), xB, a1[5], false);
      a0[6]=__builtin_amdgcn_fdot2(as_h2(wb.z), xA, a0[6], false);
      a1[6]=__builtin_amdgcn_fdot2(as_h2(wb.z), xB, a1[6], false);
      a0[7]=__builtin_amdgcn_fdot2(as_h2(wb.w), xA, a0[7], false);
      a1[7]=__builtin_amdgcn_fdot2(as_h2(wb.w), xB, a1[7], false);
    }

    if (pass < 2){
#pragma unroll
      for (int q=0;q<8;q++){
        float s  = hredsum(a0[q]+a1[q]);
        float s2 = hredsum(a0[q]*a0[q] + a1[q]*a1[q]);
        if (p2==0){ ssl[cb+oc+q] = s; sql[cb+oc+q] = s2; }
      }
    } else {
      __half2 h0[4], h1[4];
#pragma unroll
      for (int q=0;q<4;q++){
        float v00 = a0[q*2],   v01 = a0[q*2+1];
        float v10 = a1[q*2],   v11 = a1[q*2+1];
        v00 = v00>0.f? v00 : 0.2f*v00;  v01 = v01>0.f? v01 : 0.2f*v01;
        v10 = v10>0.f? v10 : 0.2f*v10;  v11 = v11>0.f? v11 : 0.2f*v11;
        h0[q] = __floats2half2_rn(v00, v01);
        h1[q] = __floats2half2_rn(v10, v11);
      }
      __half* xb = X1 + ((size_t)b*NN + n0 + p2*2)*32 + g8*8;
      *(uint4*)(xb)      = *(uint4*)h0;
      *(uint4*)(xb + 32) = *(uint4*)h1;
    }
  }

  __syncthreads();
  if (tid < 128){
    atomicAdd(&scS[b*128+tid], ssl[tid]);
    atomicAdd(&scQ[b*128+tid], sql[tid]);
  }
}

// ---------------- K1: v10 moments, 4 threads per point (k-quarters) -----------------
__global__ void __launch_bounds__(256) k1_vmom(
    const float* __restrict__ coords, const int* __restrict__ idx,
    const float* __restrict__ dist, float* __restrict__ vm)
{
  __shared__ float red[4*65];
  const int tid = threadIdx.x, lane = tid & 63, wid = tid >> 6;
  const int gn = blockIdx.x*256 + tid;
  const int pt = gn >> 2, h = gn & 3;
  const int b = pt >> 15, n = pt & (NN-1);
  const size_t pb = (size_t)b*NN + n;
  const float c0 = coords[pb*3+0], c1 = coords[pb*3+1], c2 = coords[pb*3+2];

  int ja[4]; float da[4];
  {
    int4 j4 = *(const int4*)(idx + pb*16 + h*4);
    float4 d4 = *(const float4*)(dist + pb*16 + h*4);
    ja[0]=j4.x; ja[1]=j4.y; ja[2]=j4.z; ja[3]=j4.w;
    da[0]=d4.x; da[1]=d4.y; da[2]=d4.z; da[3]=d4.w;
  }

  float aS[10], aM[55];
#pragma unroll
  for (int i=0;i<10;i++) aS[i]=0.f;
#pragma unroll
  for (int i=0;i<55;i++) aM[i]=0.f;

#pragma unroll
  for (int k=0;k<4;k++){
    const float* nb = coords + ((size_t)b*NN + ja[k])*3;
    const float n0v=nb[0], n1v=nb[1], n2v=nb[2];
    const float v[10] = {c0,c1,c2,n0v,n1v,n2v,c0-n0v,c1-n1v,c2-n2v,da[k]};
#pragma unroll
    for (int i=0;i<10;i++){
      aS[i] += v[i];
#pragma unroll
      for (int j=i;j<10;j++)
        aM[i*10 - (i*(i-1))/2 + (j-i)] += v[i]*v[j];
    }
  }

#pragma unroll
  for (int i=0;i<10;i++){ float s = wredsum(aS[i]); if (lane==0) red[wid*65+i] = s; }
#pragma unroll
  for (int i=0;i<55;i++){ float s = wredsum(aM[i]); if (lane==0) red[wid*65+10+i] = s; }
  __syncthreads();
  if (tid < 65){
    float s = red[tid] + red[65+tid] + red[130+tid] + red[195+tid];
    const int bb = blockIdx.x >> 9;
    atomicAdd(&vm[bb*65+tid], s);
  }
}

// ---------------- F1: fold GN into LSE conv weights --------------------------------
__global__ void f1_fold(
    const float* __restrict__ w_lse1, const float* __restrict__ b_lse1,
    const float* __restrict__ g_lse1, const float* __restrict__ bt_lse1,
    const float* __restrict__ w_lse2, const float* __restrict__ b_lse2,
    const float* __restrict__ g_lse2, const float* __restrict__ bt_lse2,
    const float* __restrict__ vm,
    float* __restrict__ w1p, float* __restrict__ w2p)
{
  const int tid = threadIdx.x; // 128
  const int half = tid >> 6;
  const int u = tid & 63, b = u >> 5, c = u & 31;
  const float* W  = half ? w_lse2  : w_lse1;
  const float* Bv = half ? b_lse2  : b_lse1;
  const float* G  = half ? g_lse2  : g_lse1;
  const float* Bt = half ? bt_lse2 : bt_lse1;
  float wr[10];
#pragma unroll
  for (int i=0;i<10;i++) wr[i] = W[c*10+i];
  const float* S = vm + b*65;
  const float* M = vm + b*65 + 10;
  float P = 0.f;
#pragma unroll
  for (int i=0;i<10;i++) P = fmaf(wr[i], S[i], P);
  float Q = 0.f;
#pragma unroll
  for (int i=0;i<10;i++){
#pragma unroll
    for (int j=i;j<10;j++){
      float m = M[i*10 - (i*(i-1))/2 + (j-i)];
      float t = wr[i]*wr[j]*m;
      Q += (i==j) ? t : 2.f*t;
    }
  }
  const float invNK = 1.f/((float)NN*16.f);
  const float bc = Bv[c];
  float mean = P*invNK + bc;
  float ey2  = (Q + 2.f*bc*P)*invNK + bc*bc;
  float mu = 0.5f*(mean + __shfl_xor(mean,1));
  float e2 = 0.5f*(ey2  + __shfl_xor(ey2, 1));
  float var = e2 - mu*mu;
  float rstd = rsqrtf(var + GEPS);
  float a = G[c]*rstd, d = Bt[c] - mu*a;
  float* out = (half ? w2p : w1p) + (b*32+c)*12;
#pragma unroll
  for (int i=0;i<10;i++) out[i] = wr[i]*a;
  out[10] = bc*a + d;
  out[11] = 0.f;
}

// ---------------- K2: LSE1+pool1; fp16 gather; fdot2 pool --------------------------
__global__ void __launch_bounds__(256,8) k2_lse1_pool1(
    const float* __restrict__ coords, const int* __restrict__ idx,
    const float* __restrict__ dist, const __half* __restrict__ X1,
    const float* __restrict__ w1p, const unsigned* __restrict__ wp1H,
    const float* __restrict__ b_pool1,
    __half* __restrict__ Y1, float* __restrict__ p1S, float* __restrict__ p1Q)
{
  __shared__ float mfl[32*66];
  __shared__ unsigned wlds2[32*32];   // 4096 B
  __shared__ float sl[32], ql[32];
  const int tid = threadIdx.x, lane = tid & 63;
  const int e = tid & 7;
  const int pl = tid >> 3;
  if (tid < 32){ sl[tid]=0.f; ql[tid]=0.f; }
  for (int u=tid; u<1024; u+=256) wlds2[u] = wp1H[u];
  __syncthreads();
  const int b = __builtin_amdgcn_readfirstlane((int)blockIdx.x & 1);
  const int n = (((int)blockIdx.x >> 1) << 5) + pl;
  const size_t pb = (size_t)b*NN + n;
  float* mf = &mfl[pl*66];
  const float s16 = 0.0625f;

  // Phase A: ch-split gather (fp16)
  {
    int ja[16];
    const int4* ip = (const int4*)(idx + pb*16);
#pragma unroll
    for (int k4=0;k4<4;k4++){
      int4 j4 = ip[k4];
      ja[k4*4+0]=j4.x; ja[k4*4+1]=j4.y; ja[k4*4+2]=j4.z; ja[k4*4+3]=j4.w;
    }
    float af0=0.f, af1=0.f, af2=0.f, af3=0.f;
    const __half* xb = X1 + (size_t)b*NN*32 + e*4;
#pragma unroll 4
    for (int k=0;k<16;k++){
      uint2 v = *(const uint2*)(xb + (size_t)ja[k]*32);
      __half2 h0 = *(__half2*)&v.x, h1 = *(__half2*)&v.y;
      float2 f0 = __half22float2(h0), f1 = __half22float2(h1);
      af0+=f0.x; af1+=f0.y; af2+=f1.x; af3+=f1.y;
    }
    mf[32+e*4+0]=af0*s16; mf[32+e*4+1]=af1*s16;
    mf[32+e*4+2]=af2*s16; mf[32+e*4+3]=af3*s16;
  }

  // Phase B: k-split enc
  {
    int2 j2 = *(const int2*)(idx + pb*16 + e*2);
    float2 d2 = *(const float2*)(dist + pb*16 + e*2);
    const float* nb0 = coords + ((size_t)b*NN + j2.x)*3;
    const float* nb1 = coords + ((size_t)b*NN + j2.y)*3;
    const float nx0=nb0[0], ny0=nb0[1], nz0=nb0[2];
    const float nx1=nb1[0], ny1=nb1[1], nz1=nb1[2];
    const float c0=coords[pb*3], c1=coords[pb*3+1], c2=coords[pb*3+2];
    const float* wrow = w1p + (size_t)(b*32)*12;
#pragma unroll 1
    for (int cc=0;cc<4;cc++){
      float ptc[8];
#pragma unroll
      for (int q=0;q<8;q++){
        const float4* r4 = (const float4*)(wrow + (cc*8+q)*12);
        float4 ra=r4[0], rb=r4[1], rc=r4[2];
        const float t0=ra.x+rb.z, t1=ra.y+rb.w, t2=ra.z+rc.x;
        const float u0=ra.w-rb.z, u1=rb.x-rb.w, u2=rb.y-rc.x;
        const float wd=rc.y;
        float cb = rc.z;
        cb = fmaf(t0,c0,cb); cb = fmaf(t1,c1,cb); cb = fmaf(t2,c2,cb);
        float s0 = cb, s1 = cb;
        s0 = fmaf(u0,nx0,s0); s0 = fmaf(u1,ny0,s0); s0 = fmaf(u2,nz0,s0);
        s0 = fmaf(wd,d2.x,s0);
        s1 = fmaf(u0,nx1,s1); s1 = fmaf(u1,ny1,s1); s1 = fmaf(u2,nz1,s1);
        s1 = fmaf(wd,d2.y,s1);
        ptc[q] = fmaxf(s0,0.f) + fmaxf(s1,0.f);
      }
#pragma unroll
      for (int q=0;q<8;q++) ptc[q] = ecomb(ptc[q]);
      if ((e>>1)==cc){
        float v0 = (e&1) ? ptc[4] : ptc[0];
        float v1 = (e&1) ? ptc[5] : ptc[1];
        float v2 = (e&1) ? ptc[6] : ptc[2];
        float v3 = (e&1) ? ptc[7] : ptc[3];
        mf[e*4+0]=v0*s16; mf[e*4+1]=v1*s16;
        mf[e*4+2]=v2*s16; mf[e*4+3]=v3*s16;
      }
    }
  }
  __syncthreads();

  // pool1: outputs e*4 .. e*4+4 over 32 input-pairs (fdot2)
  const int o0 = e*4;
  float yac[4];
  {
    const float4 b0 = *(const float4*)(b_pool1 + o0);
    yac[0]=b0.x; yac[1]=b0.y; yac[2]=b0.z; yac[3]=b0.w;
  }
#pragma unroll 4
  for (int c2=0;c2<32;c2++){
    float2 m2 = *(const float2*)&mf[2*c2];
    unsigned mp = pack_h2(m2.x, m2.y);
    f16x2 mh = as_h2(mp);
    uint4 w = *(const uint4*)(wlds2 + c2*32 + o0);
    yac[0]=__builtin_amdgcn_fdot2(as_h2(w.x), mh, yac[0], false);
    yac[1]=__builtin_amdgcn_fdot2(as_h2(w.y), mh, yac[1], false);
    yac[2]=__builtin_amdgcn_fdot2(as_h2(w.z), mh, yac[2], false);
    yac[3]=__builtin_amdgcn_fdot2(as_h2(w.w), mh, yac[3], false);
  }
  {
    __half2 h[2];
    h[0] = __floats2half2_rn(yac[0], yac[1]);
    h[1] = __floats2half2_rn(yac[2], yac[3]);
    *(uint2*)(Y1 + pb*32 + o0) = *(uint2*)h;
  }
#pragma unroll
  for (int q=0;q<4;q++){
    float s  = eredsum(yac[q]);
    float s2 = eredsum(yac[q]*yac[q]);
    if (lane < 8){ atomicAdd(&sl[o0+q], s); atomicAdd(&ql[o0+q], s2); }
  }
  __syncthreads();
  if (tid<32){ atomicAdd(&p1S[b*32+tid], sl[tid]); atomicAdd(&p1Q[b*32+tid], ql[tid]); }
}

// ---------------- K4: LSE2+pool2; fp16 gather + fused GN; fdot2 pool ----------------
__global__ void __launch_bounds__(256,8) k4_lse2_pool2(
    const float* __restrict__ coords, const int* __restrict__ idx,
    const float* __restrict__ dist, const __half* __restrict__ Y1,
    const float* __restrict__ w2p, const unsigned* __restrict__ wp2H,
    const float* __restrict__ b_pool2,
    const float* __restrict__ p1S, const float* __restrict__ p1Q,
    const float* __restrict__ g_p1, const float* __restrict__ bt_p1,
    float* __restrict__ Y2T, float* __restrict__ p2S, float* __restrict__ p2Q)
{
  __shared__ float mfl[32*66];
  __shared__ unsigned wlds2[32*64];   // 8192 B
  __shared__ float sl[64], ql[64];
  __shared__ float al[32], dl[32];
  const int tid = threadIdx.x, lane = tid & 63;
  const int e = tid & 7;
  const int pl = tid >> 3;
  const int b = __builtin_amdgcn_readfirstlane((int)blockIdx.x & 1);
  if (tid < 64){ sl[tid]=0.f; ql[tid]=0.f; }
  if (tid >= 64 && tid < 96){
    const int c = tid - 64;
    float s = p1S[b*32+c], q = p1Q[b*32+c];
    s += __shfl_xor(s,1); q += __shfl_xor(q,1);
    const float inv = 1.f/(2.f*(float)NN);
    float mu = s*inv, e2 = q*inv, var = e2-mu*mu;
    float rstd = rsqrtf(var + GEPS);
    float a = g_p1[c]*rstd;
    al[c] = a; dl[c] = bt_p1[c] - mu*a;
  }
  for (int u=tid; u<2048; u+=256) wlds2[u] = wp2H[u];
  __syncthreads();
  const int n0g = (((int)blockIdx.x >> 1) << 5);
  const int n = n0g + pl;
  const size_t pb = (size_t)b*NN + n;
  float* mf = &mfl[pl*66];
  const float s16 = 0.0625f;

  // Phase A: fp16 gather with fused pool1-GN+ReLU
  {
    const float a0g=al[e*4+0], a1g=al[e*4+1], a2g=al[e*4+2], a3g=al[e*4+3];
    const float d0g=dl[e*4+0], d1g=dl[e*4+1], d2g=dl[e*4+2], d3g=dl[e*4+3];
    int ja[16];
    const int4* ip = (const int4*)(idx + pb*16);
#pragma unroll
    for (int k4=0;k4<4;k4++){
      int4 j4 = ip[k4];
      ja[k4*4+0]=j4.x; ja[k4*4+1]=j4.y; ja[k4*4+2]=j4.z; ja[k4*4+3]=j4.w;
    }
    float af0=0.f, af1=0.f, af2=0.f, af3=0.f;
    const __half* yb = Y1 + (size_t)b*NN*32 + e*4;
#pragma unroll 4
    for (int k=0;k<16;k++){
      uint2 v = *(const uint2*)(yb + (size_t)ja[k]*32);
      __half2 h0 = *(__half2*)&v.x, h1 = *(__half2*)&v.y;
      float2 f0 = __half22float2(h0), f1 = __half22float2(h1);
      af0 += fmaxf(fmaf(f0.x, a0g, d0g), 0.f);
      af1 += fmaxf(fmaf(f0.y, a1g, d1g), 0.f);
      af2 += fmaxf(fmaf(f1.x, a2g, d2g), 0.f);
      af3 += fmaxf(fmaf(f1.y, a3g, d3g), 0.f);
    }
    mf[32+e*4+0]=af0*s16; mf[32+e*4+1]=af1*s16;
    mf[32+e*4+2]=af2*s16; mf[32+e*4+3]=af3*s16;
  }

  // Phase B: k-split enc
  {
    int2 j2 = *(const int2*)(idx + pb*16 + e*2);
    float2 d2 = *(const float2*)(dist + pb*16 + e*2);
    const float* nb0 = coords + ((size_t)b*NN + j2.x)*3;
    const float* nb1 = coords + ((size_t)b*NN + j2.y)*3;
    const float nx0=nb0[0], ny0=nb0[1], nz0=nb0[2];
    const float nx1=nb1[0], ny1=nb1[1], nz1=nb1[2];
    const float c0=coords[pb*3], c1=coords[pb*3+1], c2=coords[pb*3+2];
    const float* wrow = w2p + (size_t)(b*32)*12;
#pragma unroll 1
    for (int cc=0;cc<4;cc++){
      float ptc[8];
#pragma unroll
      for (int q=0;q<8;q++){
        const float4* r4 = (const float4*)(wrow + (cc*8+q)*12);
        float4 ra=r4[0], rb=r4[1], rc=r4[2];
        const float t0=ra.x+rb.z, t1=ra.y+rb.w, t2=ra.z+rc.x;
        const float u0=ra.w-rb.z, u1=rb.x-rb.w, u2=rb.y-rc.x;
        const float wd=rc.y;
        float cb = rc.z;
        cb = fmaf(t0,c0,cb); cb = fmaf(t1,c1,cb); cb = fmaf(t2,c2,cb);
        float s0 = cb, s1 = cb;
        s0 = fmaf(u0,nx0,s0); s0 = fmaf(u1,ny0,s0); s0 = fmaf(u2,nz0,s0);
        s0 = fmaf(wd,d2.x,s0);
        s1 = fmaf(u0,nx1,s1); s1 = fmaf(u1,ny1,s1); s1 = fmaf(u2,nz1,s1);
        s1 = fmaf(wd,d2.y,s1);
        ptc[q] = fmaxf(s0,0.f) + fmaxf(s1,0.f);
      }
#pragma unroll
      for (int q=0;q<8;q++) ptc[q] = ecomb(ptc[q]);
      if ((e>>1)==cc){
        float v0 = (e&1) ? ptc[4] : ptc[0];
        float v1 = (e&1) ? ptc[5] : ptc[1];
        float v2 = (e&1) ? ptc[6] : ptc[2];
        float v3 = (e&1) ? ptc[7] : ptc[3];
        mf[e*4+0]=v0*s16; mf[e*4+1]=v1*s16;
        mf[e*4+2]=v2*s16; mf[e*4+3]=v3*s16;
      }
    }
  }
  __syncthreads();

  // pool2: outputs e*8 .. e*8+8 over 32 input-pairs (fdot2)
  const int o0 = e*8;
  float yac[8];
  {
    const float4 b0 = *(const float4*)(b_pool2 + o0);
    const float4 b1 = *(const float4*)(b_pool2 + o0 + 4);
    yac[0]=b0.x; yac[1]=b0.y; yac[2]=b0.z; yac[3]=b0.w;
    yac[4]=b1.x; yac[5]=b1.y; yac[6]=b1.z; yac[7]=b1.w;
  }
#pragma unroll 4
  for (int c2=0;c2<32;c2++){
    float2 m2 = *(const float2*)&mf[2*c2];
    unsigned mp = pack_h2(m2.x, m2.y);
    f16x2 mh = as_h2(mp);
    uint4 wa = *(const uint4*)(wlds2 + c2*64 + o0);
    uint4 wb = *(const uint4*)(wlds2 + c2*64 + o0 + 4);
    yac[0]=__builtin_amdgcn_fdot2(as_h2(wa.x), mh, yac[0], false);
    yac[1]=__builtin_amdgcn_fdot2(as_h2(wa.y), mh, yac[1], false);
    yac[2]=__builtin_amdgcn_fdot2(as_h2(wa.z), mh, yac[2], false);
    yac[3]=__builtin_amdgcn_fdot2(as_h2(wa.w), mh, yac[3], false);
    yac[4]=__builtin_amdgcn_fdot2(as_h2(wb.x), mh, yac[4], false);
    yac[5]=__builtin_amdgcn_fdot2(as_h2(wb.y), mh, yac[5], false);
    yac[6]=__builtin_amdgcn_fdot2(as_h2(wb.z), mh, yac[6], false);
    yac[7]=__builtin_amdgcn_fdot2(as_h2(wb.w), mh, yac[7], false);
  }
#pragma unroll
  for (int q=0;q<8;q++){
    float s  = eredsum(yac[q]);
    float s2 = eredsum(yac[q]*yac[q]);
    if (lane < 8){ atomicAdd(&sl[o0+q], s); atomicAdd(&ql[o0+q], s2); }
  }
  __syncthreads();
  float* ldsT = &mfl[0];
#pragma unroll
  for (int o=0;o<8;o++) ldsT[(o0+o)*33 + pl] = yac[o];
  __syncthreads();
#pragma unroll
  for (int r=0;r<8;r++){
    int u = tid + r*256;
    int ch = u >> 5, p = u & 31;
    Y2T[((size_t)(b*64+ch))*NN + n0g + p] = ldsT[ch*33 + p];
  }
  if (tid<64){ atomicAdd(&p2S[b*64+tid], sl[tid]); atomicAdd(&p2Q[b*64+tid], ql[tid]); }
}

// ---------------- F3a: per-batch GN affines (sc + pool2) ----------------------------
__global__ void f3a_affines(
    const float* __restrict__ scS, const float* __restrict__ scQ,
    const float* __restrict__ g_sc, const float* __restrict__ bt_sc,
    const float* __restrict__ b_sc, const float* __restrict__ b_mlp2,
    const float* __restrict__ p2S, const float* __restrict__ p2Q,
    const float* __restrict__ g_p2, const float* __restrict__ bt_p2,
    float* __restrict__ ascT, float* __restrict__ cstF,
    float* __restrict__ a2F, float* __restrict__ d2F)
{
  const int tid = threadIdx.x; // 384
  if (tid < 256){
    const int b = tid >> 7, c = tid & 127;
    float s = scS[b*128+c], q = scQ[b*128+c];
    s += __shfl_xor(s,1); q += __shfl_xor(q,1);
    s += __shfl_xor(s,2); q += __shfl_xor(q,2);
    s += __shfl_xor(s,4); q += __shfl_xor(q,4);
    const float inv = 1.f/(8.f*(float)NN);
    float mu = s*inv, e2 = q*inv, var = e2-mu*mu;
    float rstd = rsqrtf(var + GEPS);
    float a = g_sc[c]*rstd;
    ascT[tid] = a;
    cstF[tid] = b_mlp2[c] + a*b_sc[c] + (bt_sc[c] - mu*a);
  } else {
    const int t = tid - 256;
    const int b = t >> 6, c = t & 63;
    float s = p2S[b*64+c], q = p2Q[b*64+c];
    s += __shfl_xor(s,1); q += __shfl_xor(q,1);
    s += __shfl_xor(s,2); q += __shfl_xor(q,2);
    const float inv = 1.f/(4.f*(float)NN);
    float mu = s*inv, e2 = q*inv, var = e2-mu*mu;
    float rstd = rsqrtf(var + GEPS);
    float a = g_p2[c]*rstd;
    a2F[t] = a; d2F[t] = bt_p2[c] - mu*a;
  }
}

// ---------------- F3b: Wcomb[b] = [ w_mlp2^T (64x128) ; w_sc^T * asc[b] (72x128) ] --
__global__ void __launch_bounds__(256) f3b_wcomb(
    const float* __restrict__ w_mlp2, const float* __restrict__ w_sc,
    const float* __restrict__ ascT, float* __restrict__ Wcomb)
{
  const int t0 = blockIdx.x*256 + threadIdx.x;
  const int stride = gridDim.x*256;
  for (int u=t0; u<2*136*128; u+=stride){
    int bb = u / 17408;
    int rr = u - bb*17408;
    int i = rr >> 7, o = rr & 127;
    Wcomb[u] = (i < 64) ? w_mlp2[o*64+i]
                        : w_sc[o*72 + (i-64)] * ascT[bb*128+o];
  }
}

// ---------------- K6: outer-product reg tile; 64 pts x 128 ch; 4x8/thread ----------
__global__ void __launch_bounds__(256,4) k6_final(
    const float* __restrict__ feat, const float* __restrict__ Y2T,
    const float* __restrict__ Wcomb, const float* __restrict__ cstF,
    const float* __restrict__ a2F, const float* __restrict__ d2F,
    float* __restrict__ out)
{
  __shared__ float xl[34*64];
  __shared__ float wl[34*160];
  const int tid = threadIdx.x;
  const int tc = tid & 15;
  const int tp = tid >> 4;
  const int b  = __builtin_amdgcn_readfirstlane((int)blockIdx.x >> 9);
  const int n0 = ((int)blockIdx.x & 511) << 6;

  float acc[4][8];
#pragma unroll
  for (int q=0;q<8;q++){
    float bv = cstF[b*128 + tc*8 + q];
#pragma unroll
    for (int p=0;p<4;p++) acc[p][q] = bv;
  }

  const float* Wb = Wcomb + b*17408;
#pragma unroll 1
  for (int kk=0; kk<4; ++kk){
    __syncthreads();
    for (int u=tid; u<34*64; u+=256){
      int row = u>>6, j = u&63;
      int r = kk*34 + row;
      float v;
      if (r < 64){
        float y = Y2T[(size_t)(b*64+r)*NN + n0 + j];
        v = fmaxf(fmaf(y, a2F[b*64+r], d2F[b*64+r]), 0.f);
      } else {
        v = feat[(size_t)(b*72 + (r-64))*NN + n0 + j];
      }
      xl[u] = v;
    }
    for (int u=tid; u<34*128; u+=256){
      int row = u>>7, c = u&127;
      wl[row*160 + (c>>3)*10 + (c&7)] = Wb[(size_t)(kk*34+row)*128 + c];
    }
    __syncthreads();

#pragma unroll 2
    for (int i=0;i<34;i++){
      const float4 xa = *(const float4*)&xl[i*64 + tp*4];
      const float4 wa = *(const float4*)&wl[i*160 + tc*10];
      const float4 wb = *(const float4*)&wl[i*160 + tc*10 + 4];
      const float xs[4] = {xa.x,xa.y,xa.z,xa.w};
      const float wv[8] = {wa.x,wa.y,wa.z,wa.w,wb.x,wb.y,wb.z,wb.w};
#pragma unroll
      for (int p=0;p<4;p++)
#pragma unroll
        for (int q=0;q<8;q++)
          acc[p][q] = fmaf(wv[q], xs[p], acc[p][q]);
    }
  }

#pragma unroll
  for (int q=0;q<8;q++){
    const int ch = b*128 + tc*8 + q;
    float4 r0;
    float v;
    v = acc[0][q]; r0.x = v>0.f? v : 0.01f*v;
    v = acc[1][q]; r0.y = v>0.f? v : 0.01f*v;
    v = acc[2][q]; r0.z = v>0.f? v : 0.01f*v;
    v = acc[3][q]; r0.w = v>0.f? v : 0.01f*v;
    *(float4*)(out + (size_t)ch*NN + n0 + tp*4) = r0;
  }
}

extern "C" void kernel_launch(void* const* d_in, const int* in_sizes, int n_in,
                              void* d_out, int out_size, void* d_ws, size_t ws_size,
                              hipStream_t stream) {
  (void)in_sizes; (void)n_in; (void)out_size; (void)ws_size;
  const float* coords  = (const float*)d_in[0];
  const float* feats   = (const float*)d_in[1];
  const int*   idx     = (const int*)  d_in[2];
  const float* dist    = (const float*)d_in[3];
  const float* w_mlp1  = (const float*)d_in[4];
  const float* b_mlp1  = (const float*)d_in[5];
  const float* w_lse1  = (const float*)d_in[6];
  const float* b_lse1  = (const float*)d_in[7];
  const float* g_lse1  = (const float*)d_in[8];
  const float* bt_lse1 = (const float*)d_in[9];
  const float* w_pool1 = (const float*)d_in[10];
  const float* b_pool1 = (const float*)d_in[11];
  const float* g_pool1 = (const float*)d_in[12];
  const float* bt_pool1= (const float*)d_in[13];
  const float* w_lse2  = (const float*)d_in[14];
  const float* b_lse2  = (const float*)d_in[15];
  const float* g_lse2  = (const float*)d_in[16];
  const float* bt_lse2 = (const float*)d_in[17];
  const float* w_pool2 = (const float*)d_in[18];
  const float* b_pool2 = (const float*)d_in[19];
  const float* g_pool2 = (const float*)d_in[20];
  const float* bt_pool2= (const float*)d_in[21];
  const float* w_mlp2  = (const float*)d_in[22];
  const float* b_mlp2  = (const float*)d_in[23];
  const float* w_sc    = (const float*)d_in[24];
  const float* b_sc    = (const float*)d_in[25];
  const float* g_sc    = (const float*)d_in[26];
  const float* bt_sc   = (const float*)d_in[27];

  float* ws   = (float*)d_ws;
  float* scS  = ws;            // 256
  float* scQ  = ws + 256;      // 256
  float* vm   = ws + 512;      // 130
  float* p1S  = ws + 704;      // 64
  float* p1Q  = ws + 768;      // 64
  float* p2S  = ws + 832;      // 128
  float* p2Q  = ws + 960;      // 128
  float* w1p  = ws + 1280;     // 768
  float* w2p  = ws + 2048;     // 768
  unsigned* wp1H = (unsigned*)(ws + 2816);  // 1024 u32
  unsigned* wp2H = (unsigned*)(ws + 4864);  // 2048 u32
  float* ball = ws + 8960;     // 160 -> 9120
  float* cstF = ws + 9120;     // 256 -> 9376
  float* a2F  = ws + 9376;     // 128 -> 9504
  float* d2F  = ws + 9504;     // 128 -> 9632
  float* ascT = ws + 9632;     // 256 -> 9888
  float* WallT= ws + 9984;     // 11520 -> 21504
  float* Wcomb= ws + 21504;    // 34816 -> 56320
  __half* X1  = (__half*)(ws + 57344);
  __half* Y1  = (__half*)(ws + 57344 + (size_t)NN*32);
  float* Y2T  = ws + 57344 + (size_t)2*NN*32;

  hipMemsetAsync(d_ws, 0, 1088*sizeof(float), stream);

  f0_prep<<<32,256,0,stream>>>(w_mlp1,b_mlp1,w_sc,b_sc,w_pool1,w_pool2,
                               WallT,ball,wp1H,wp2H);
  k0_mlp1_scstats<<<1024,256,0,stream>>>(feats, WallT, ball, X1, scS, scQ);
  k1_vmom<<<1024,256,0,stream>>>(coords, idx, dist, vm);
  f1_fold<<<1,128,0,stream>>>(w_lse1,b_lse1,g_lse1,bt_lse1,
                              w_lse2,b_lse2,g_lse2,bt_lse2,
                              vm, w1p, w2p);
  k2_lse1_pool1<<<2048,256,0,stream>>>(coords, idx, dist, X1, w1p, wp1H, b_pool1,
                                       Y1, p1S, p1Q);
  k4_lse2_pool2<<<2048,256,0,stream>>>(coords, idx, dist, Y1, w2p, wp2H, b_pool2,
                                       p1S, p1Q, g_pool1, bt_pool1,
                                       Y2T, p2S, p2Q);
  f3a_affines<<<1,384,0,stream>>>(scS,scQ,g_sc,bt_sc,b_sc,b_mlp2,
                                  p2S,p2Q,g_pool2,bt_pool2, ascT,cstF,a2F,d2F);
  f3b_wcomb<<<64,256,0,stream>>>(w_mlp2, w_sc, ascT, Wcomb);
  k6_final<<<1024,256,0,stream>>>(feats, Y2T, Wcomb, cstF, a2F, d2F, (float*)d_out);
}